// Round 1
// baseline (38460.132 us; speedup 1.0000x reference)
//
#include <hip/hip_runtime.h>
#include <hip/hip_bf16.h>
#include <math.h>

#define TT 256
#define BB 128
#define SS 256
#define HH 512
#define EE 512

typedef __attribute__((ext_vector_type(4))) float f32x4;
typedef __attribute__((ext_vector_type(8))) short s16x8;

__device__ __forceinline__ float b2f(short v) {
    union { unsigned u; float f; } c;
    c.u = ((unsigned)(unsigned short)v) << 16;
    return c.f;
}
__device__ __forceinline__ short f2b(float f) {
    union { float f; unsigned u; } c; c.f = f;
    unsigned u = c.u;
    unsigned r = (u + 0x7fffu + ((u >> 16) & 1u)) >> 16;
    return (short)r;
}
__device__ __forceinline__ float sigm(float x) { return 1.f / (1.f + __expf(-x)); }

// ---------------- prep kernels ----------------

__global__ void k_pack2(const float* __restrict__ Wa, int ka, const float* __restrict__ Wb, int kb,
                        short* __restrict__ dst, int n) {
    const int K = ka + kb;
    for (int i = blockIdx.x * blockDim.x + threadIdx.x; i < n; i += gridDim.x * blockDim.x) {
        int g = i / K, k = i - g * K;
        float v = (k < ka) ? Wa[(size_t)g * ka + k] : Wb[(size_t)g * kb + (k - ka)];
        dst[i] = f2b(v);
    }
}

__global__ void k_bias(const float* __restrict__ a, const float* __restrict__ b, float* __restrict__ o,
                       const float* __restrict__ a2, const float* __restrict__ b2, float* __restrict__ o2) {
    int i = blockIdx.x * blockDim.x + threadIdx.x;
    if (i < 2048) { o[i] = a[i] + b[i]; o2[i] = a2[i] + b2[i]; }
}

__global__ void k_emb(const int* __restrict__ tok, const float* __restrict__ emb, short* __restrict__ Ebf) {
    const int n = TT * BB * EE;
    for (int i = blockIdx.x * blockDim.x + threadIdx.x; i < n; i += gridDim.x * blockDim.x) {
        int tb = i >> 9, k = i & 511;
        int tkn = tok[tb];
        Ebf[i] = f2b(emb[(size_t)tkn * EE + k]);
    }
}

__global__ void k_ctx(const float* __restrict__ ctx, short* __restrict__ Ctxb) {
    const int n = BB * SS * HH;
    for (int i = blockIdx.x * blockDim.x + threadIdx.x; i < n; i += gridDim.x * blockDim.x) {
        int b = i / (SS * HH);
        int r = i - b * SS * HH;
        int s = r >> 9, h = r & 511;
        Ctxb[i] = f2b(ctx[((size_t)s * BB + b) * HH + h]);
    }
}

__global__ void k_state(const float* __restrict__ h0in, const float* __restrict__ c0in,
                        const float* __restrict__ iout,
                        short* __restrict__ H0bf, short* __restrict__ H1bf, short* __restrict__ OUTbf,
                        float* __restrict__ c0s, float* __restrict__ c1s) {
    int i = blockIdx.x * blockDim.x + threadIdx.x;
    if (i < BB * HH) {
        H0bf[i] = f2b(h0in[i]);
        H1bf[i] = f2b(h0in[BB * HH + i]);
        OUTbf[i] = f2b(iout[i]);
        c0s[i] = c0in[i];
        c1s[i] = c0in[BB * HH + i];
    }
}

// ---------------- fused GEMM ----------------
// C[b, g] = sum_k A[b,k] * W[g,k];  A = concat of up to 3 [128][512] bf16 sources.
// MODE 0: gates+LSTM cell epilogue (QUADS=4: g = q*512 + j);  MODE 1: store f32 (q);
// MODE 2: tanh -> f32 out + bf16 out.
template <int KTOT, int JSUB, int QUADS, int MODE>
__global__ __launch_bounds__(512) void gemm_k(
    const short* __restrict__ A0, const short* __restrict__ A1, const short* __restrict__ A2,
    const short* __restrict__ W, const float* __restrict__ bias,
    float* __restrict__ cstate, short* __restrict__ hbf,
    float* __restrict__ hF, float* __restrict__ cF,
    float* __restrict__ qout,
    float* __restrict__ outf, short* __restrict__ outb) {
    constexpr int JS16 = JSUB * 16;
    constexpr int WROWS = QUADS * JS16;
    __shared__ __align__(16) short lsA[128 * 40];
    __shared__ __align__(16) short lsW[WROWS * 40];
    const int tid = threadIdx.x;
    const int w = tid >> 6, l = tid & 63;
    const int j0 = blockIdx.x * JS16;
    const int lrow = l & 15, lk = (l >> 4) * 8;

    f32x4 acc[JSUB][QUADS];
    const f32x4 zero = {0.f, 0.f, 0.f, 0.f};
#pragma unroll
    for (int a = 0; a < JSUB; ++a)
#pragma unroll
        for (int q = 0; q < QUADS; ++q) acc[a][q] = zero;

    for (int k0 = 0; k0 < KTOT; k0 += 32) {
        const short* Asrc = (KTOT > 512 && k0 >= 512) ? ((KTOT > 1024 && k0 >= 1024) ? A2 : A1) : A0;
        const int koff = k0 & 511;
        __syncthreads();
        constexpr int CH = (128 + WROWS) * 4;
        for (int idx = tid; idx < CH; idx += 512) {
            const int row = idx >> 2, c4 = idx & 3;
            const short* g;
            short* d;
            if (row < 128) {
                g = Asrc + row * 512 + koff + c4 * 8;
                d = lsA + row * 40 + c4 * 8;
            } else {
                const int rr = row - 128;
                const int quad = rr / JS16, jj = rr % JS16;
                g = W + (size_t)(quad * 512 + j0 + jj) * KTOT + k0 + c4 * 8;
                d = lsW + rr * 40 + c4 * 8;
            }
            *reinterpret_cast<float4*>(d) = *reinterpret_cast<const float4*>(g);
        }
        __syncthreads();
        s16x8 af = *reinterpret_cast<const s16x8*>(lsA + (w * 16 + lrow) * 40 + lk);
#pragma unroll
        for (int js = 0; js < JSUB; ++js)
#pragma unroll
            for (int q = 0; q < QUADS; ++q) {
                s16x8 bfr = *reinterpret_cast<const s16x8*>(lsW + (q * JS16 + js * 16 + lrow) * 40 + lk);
                acc[js][q] = __builtin_amdgcn_mfma_f32_16x16x32_bf16(af, bfr, acc[js][q], 0, 0, 0);
            }
    }

    const int lg4 = l >> 4;
    if constexpr (MODE == 0) {
#pragma unroll
        for (int js = 0; js < JSUB; ++js) {
            const int j = j0 + js * 16 + lrow;
            const float bi = bias[j], bff = bias[512 + j], bgg = bias[1024 + j], boo = bias[1536 + j];
#pragma unroll
            for (int r = 0; r < 4; ++r) {
                const int bidx = w * 16 + lg4 * 4 + r;
                const int o = bidx * HH + j;
                float gi = acc[js][0][r] + bi;
                float gf = acc[js][1][r] + bff;
                float gg = acc[js][2][r] + bgg;
                float go = acc[js][3][r] + boo;
                float cold = cstate[o];
                float cn = sigm(gf) * cold + sigm(gi) * tanhf(gg);
                float hn = sigm(go) * tanhf(cn);
                cstate[o] = cn;
                cF[o] = cn;
                hF[o] = hn;
                hbf[o] = f2b(hn);
            }
        }
    } else if constexpr (MODE == 1) {
#pragma unroll
        for (int js = 0; js < JSUB; ++js) {
            const int n = j0 + js * 16 + lrow;
#pragma unroll
            for (int r = 0; r < 4; ++r) {
                const int bidx = w * 16 + lg4 * 4 + r;
                qout[bidx * HH + n] = acc[js][0][r];
            }
        }
    } else {
#pragma unroll
        for (int js = 0; js < JSUB; ++js) {
            const int n = j0 + js * 16 + lrow;
#pragma unroll
            for (int r = 0; r < 4; ++r) {
                const int bidx = w * 16 + lg4 * 4 + r;
                float tv = tanhf(acc[js][0][r]);
                outf[bidx * HH + n] = tv;
                outb[bidx * HH + n] = f2b(tv);
            }
        }
    }
}

// ---------------- attention: online softmax, one ctx pass ----------------
__global__ __launch_bounds__(256) void attn_k(const float* __restrict__ qbuf, const short* __restrict__ ctxbf,
                                              float* __restrict__ attw, short* __restrict__ wcbf) {
    const int b = blockIdx.x, tid = threadIdx.x, w = tid >> 6, l = tid & 63;
    __shared__ float ss[256];
    __shared__ float red[8];
    __shared__ float wcs[4][512];
    const short* cb = ctxbf + (size_t)b * SS * HH;
    float qr[8];
#pragma unroll
    for (int j = 0; j < 8; ++j) qr[j] = qbuf[b * HH + l * 8 + j];
    float m = -1e30f, L = 0.f;
    float wa[8];
#pragma unroll
    for (int j = 0; j < 8; ++j) wa[j] = 0.f;

    for (int si = 0; si < 64; ++si) {
        const int s = w * 64 + si;
        s16x8 v = *reinterpret_cast<const s16x8*>(cb + (size_t)s * HH + l * 8);
        float cvt[8];
        float p = 0.f;
#pragma unroll
        for (int j = 0; j < 8; ++j) { cvt[j] = b2f(v[j]); p += cvt[j] * qr[j]; }
#pragma unroll
        for (int off = 32; off; off >>= 1) p += __shfl_xor(p, off);
        if (l == 0) ss[s] = p;
        float mn = fmaxf(m, p);
        float corr = __expf(m - mn);
        float ee = __expf(p - mn);
        L = L * corr + ee;
#pragma unroll
        for (int j = 0; j < 8; ++j) wa[j] = wa[j] * corr + ee * cvt[j];
        m = mn;
    }
    if (l == 0) red[w] = m;
    __syncthreads();
    float M = fmaxf(fmaxf(red[0], red[1]), fmaxf(red[2], red[3]));
    float scale = __expf(m - M);
#pragma unroll
    for (int j = 0; j < 8; ++j) wcs[w][l * 8 + j] = wa[j] * scale;
    if (l == 0) red[4 + w] = L * scale;
    __syncthreads();
    float Ltot = red[4] + red[5] + red[6] + red[7];
    float inv = 1.f / Ltot;
    for (int h = tid; h < 512; h += 256) {
        float wc = (wcs[0][h] + wcs[1][h] + wcs[2][h] + wcs[3][h]) * inv;
        wcbf[b * HH + h] = f2b(wc);
    }
    float av = __expf(ss[tid] - M) * inv;
    attw[b * SS + tid] = av;
}

// ---------------- host ----------------

extern "C" void kernel_launch(void* const* d_in, const int* in_sizes, int n_in,
                              void* d_out, int out_size, void* d_ws, size_t ws_size,
                              hipStream_t stream) {
    const int* tokens = (const int*)d_in[0];
    const float* h0in = (const float*)d_in[1];
    const float* c0in = (const float*)d_in[2];
    const float* ctx = (const float*)d_in[3];
    const float* iout = (const float*)d_in[4];
    const float* emb = (const float*)d_in[5];
    const float* Wih0 = (const float*)d_in[6];
    const float* bih0 = (const float*)d_in[7];
    const float* Whh0 = (const float*)d_in[8];
    const float* bhh0 = (const float*)d_in[9];
    const float* Wih1 = (const float*)d_in[10];
    const float* bih1 = (const float*)d_in[11];
    const float* Whh1 = (const float*)d_in[12];
    const float* bhh1 = (const float*)d_in[13];
    const float* Win = (const float*)d_in[14];
    const float* Wout = (const float*)d_in[15];
    float* dout = (float*)d_out;

    char* p = (char*)d_ws;
    auto take = [&](size_t bytes) { char* r = p; p += (bytes + 255) & ~(size_t)255; return r; };
    short* W0cat = (short*)take((size_t)2048 * 1536 * 2);
    short* W1cat = (short*)take((size_t)2048 * 1024 * 2);
    short* Winb  = (short*)take((size_t)512 * 512 * 2);
    short* Woutb = (short*)take((size_t)512 * 1024 * 2);
    float* bias0 = (float*)take(2048 * 4);
    float* bias1 = (float*)take(2048 * 4);
    short* Ebf   = (short*)take((size_t)TT * BB * EE * 2);
    short* Ctxb  = (short*)take((size_t)BB * SS * HH * 2);
    short* H0bf  = (short*)take((size_t)2 * BB * HH * 2);
    short* H1bf  = (short*)take((size_t)2 * BB * HH * 2);
    short* OUTbf = (short*)take((size_t)BB * HH * 2);
    short* WCbf  = (short*)take((size_t)BB * HH * 2);
    float* c0s   = (float*)take((size_t)BB * HH * 4);
    float* c1s   = (float*)take((size_t)BB * HH * 4);
    float* qbuf  = (float*)take((size_t)BB * HH * 4);

    k_pack2<<<2048, 256, 0, stream>>>(Wih0, 1024, Whh0, 512, W0cat, 2048 * 1536);
    k_pack2<<<2048, 256, 0, stream>>>(Wih1, 512, Whh1, 512, W1cat, 2048 * 1024);
    k_pack2<<<1024, 256, 0, stream>>>(Win, 512, Win, 0, Winb, 512 * 512);
    k_pack2<<<1024, 256, 0, stream>>>(Wout, 1024, Wout, 0, Woutb, 512 * 1024);
    k_bias<<<8, 256, 0, stream>>>(bih0, bhh0, bias0, bih1, bhh1, bias1);
    k_emb<<<4096, 256, 0, stream>>>(tokens, emb, Ebf);
    k_ctx<<<4096, 256, 0, stream>>>(ctx, Ctxb);
    k_state<<<256, 256, 0, stream>>>(h0in, c0in, iout, H0bf, H1bf, OUTbf, c0s, c1s);

    const size_t BH = (size_t)BB * HH;                 // 65536
    const size_t OFF_HF = (size_t)TT * BB * HH;        // outputs
    const size_t OFF_CF = OFF_HF + 2 * BH;
    const size_t OFF_AT = OFF_CF + 2 * BH;

    for (int t = 0; t < TT; ++t) {
        const int pp = t & 1, pn = pp ^ 1;
        const short* Et = Ebf + (size_t)t * BB * EE;
        // layer0: A = [e_t | out_{t-1} | h0_{t-1}]
        gemm_k<1536, 2, 4, 0><<<16, 512, 0, stream>>>(
            Et, OUTbf, H0bf + pp * BH, W0cat, bias0,
            c0s, H0bf + pn * BH, dout + OFF_HF, dout + OFF_CF, nullptr, nullptr, nullptr);
        // layer1: A = [h0_t | h1_{t-1}]
        gemm_k<1024, 2, 4, 0><<<16, 512, 0, stream>>>(
            H0bf + pn * BH, H1bf + pp * BH, nullptr, W1cat, bias1,
            c1s, H1bf + pn * BH, dout + OFF_HF + BH, dout + OFF_CF + BH, nullptr, nullptr, nullptr);
        // q = h1_t @ W_in^T
        gemm_k<512, 4, 1, 1><<<8, 512, 0, stream>>>(
            H1bf + pn * BH, nullptr, nullptr, Winb, nullptr,
            nullptr, nullptr, nullptr, nullptr, qbuf, nullptr, nullptr);
        // attention (online softmax, writes attn weights + wc)
        attn_k<<<128, 256, 0, stream>>>(qbuf, Ctxb, dout + OFF_AT, WCbf);
        // out_t = tanh([wc | h1_t] @ W_out^T)
        gemm_k<1024, 4, 1, 2><<<8, 512, 0, stream>>>(
            WCbf, H1bf + pn * BH, nullptr, Woutb, nullptr,
            nullptr, nullptr, nullptr, nullptr, nullptr, dout + (size_t)t * BB * HH, OUTbf);
    }
}

// Round 3
// 25413.002 us; speedup vs baseline: 1.5134x; 1.5134x over previous
//
#include <hip/hip_runtime.h>
#include <hip/hip_bf16.h>
#include <math.h>

#define TT 256
#define BB 128
#define SS 256
#define HH 512
#define EE 512
#define NBLK 128
#define NTHR 512
#define BH (BB * HH)

typedef __attribute__((ext_vector_type(4))) float f32x4;
typedef __attribute__((ext_vector_type(8))) short s16x8;

__device__ __forceinline__ float b2f(short v) {
    union { unsigned u; float f; } c;
    c.u = ((unsigned)(unsigned short)v) << 16;
    return c.f;
}
__device__ __forceinline__ short f2b(float f) {
    union { float f; unsigned u; } c; c.f = f;
    unsigned u = c.u;
    unsigned r = (u + 0x7fffu + ((u >> 16) & 1u)) >> 16;
    return (short)r;
}
__device__ __forceinline__ float sigm(float x) { return 1.f / (1.f + __expf(-x)); }

// ---------------- prep kernels ----------------

__global__ void k_pack2(const float* __restrict__ Wa, int ka, const float* __restrict__ Wb, int kb,
                        short* __restrict__ dst, int n) {
    const int K = ka + kb;
    for (int i = blockIdx.x * blockDim.x + threadIdx.x; i < n; i += gridDim.x * blockDim.x) {
        int g = i / K, k = i - g * K;
        float v = (k < ka) ? Wa[(size_t)g * ka + k] : Wb[(size_t)g * kb + (k - ka)];
        dst[i] = f2b(v);
    }
}

__global__ void k_bias(const float* __restrict__ a, const float* __restrict__ b, float* __restrict__ o,
                       const float* __restrict__ a2, const float* __restrict__ b2, float* __restrict__ o2) {
    int i = blockIdx.x * blockDim.x + threadIdx.x;
    if (i < 2048) { o[i] = a[i] + b[i]; o2[i] = a2[i] + b2[i]; }
}

__global__ void k_ctx(const float* __restrict__ ctx, short* __restrict__ Ctxb) {
    const int n = BB * SS * HH;
    for (int i = blockIdx.x * blockDim.x + threadIdx.x; i < n; i += gridDim.x * blockDim.x) {
        int b = i / (SS * HH);
        int r = i - b * SS * HH;
        int s = r >> 9, h = r & 511;
        Ctxb[i] = f2b(ctx[((size_t)s * BB + b) * HH + h]);
    }
}

__global__ void k_state(const float* __restrict__ h0in, const float* __restrict__ iout,
                        short* __restrict__ h0bf, short* __restrict__ h1bf, short* __restrict__ outbf) {
    int i = blockIdx.x * blockDim.x + threadIdx.x;
    if (i < BH) {
        h0bf[i] = f2b(h0in[i]);
        h1bf[i] = f2b(h0in[BH + i]);
        outbf[i] = f2b(iout[i]);
    }
}

// ctxW[(b*S+s), n] = sum_k ctxb[(b*S+s), k] * Win[n, k]
__global__ __launch_bounds__(512) void k_ctxw(const short* __restrict__ ctxb, const short* __restrict__ Winb,
                                              short* __restrict__ ctxW) {
    const int tid = threadIdx.x, w = tid >> 6, l = tid & 63;
    const int m0 = blockIdx.y * 128, n0 = blockIdx.x * 64;
    const int kc8 = (l >> 4) * 8;
    const short* arow = ctxb + (size_t)(m0 + w * 16 + (l & 15)) * HH + kc8;
    f32x4 acc[4];
    const f32x4 zero = {0.f, 0.f, 0.f, 0.f};
#pragma unroll
    for (int j = 0; j < 4; ++j) acc[j] = zero;
#pragma unroll
    for (int kc = 0; kc < 16; ++kc) {
        const int k0 = kc * 32;
        s16x8 afr = *reinterpret_cast<const s16x8*>(arow + k0);
#pragma unroll
        for (int j = 0; j < 4; ++j) {
            s16x8 bfr = *reinterpret_cast<const s16x8*>(Winb + (size_t)(n0 + j * 16 + (l & 15)) * HH + k0 + kc8);
            acc[j] = __builtin_amdgcn_mfma_f32_16x16x32_bf16(afr, bfr, acc[j], 0, 0, 0);
        }
    }
#pragma unroll
    for (int j = 0; j < 4; ++j)
#pragma unroll
        for (int r = 0; r < 4; ++r)
            ctxW[(size_t)(m0 + w * 16 + (l >> 4) * 4 + r) * HH + n0 + j * 16 + (l & 15)] = f2b(acc[j][r]);
}

// ---------------- persistent cooperative kernel ----------------

struct P {
    const int* tokens;
    const float* emb;
    const float* c0in;
    const short* ctxb;
    const short* ctxW;
    const short* W0cat;
    const short* W1cat;
    const short* Woutb;
    const float* bias0;
    const float* bias1;
    short* h0bf;
    short* h1bf;
    short* outbf;
    short* wcbf;
    float* dout;
    unsigned* cnt;
};

__device__ __forceinline__ void gbar(unsigned* cnt, unsigned* eps) {
    __syncthreads();
    if (threadIdx.x == 0) {
        __threadfence();  // release (device scope)
        const unsigned target = (++(*eps)) * (unsigned)NBLK;
        __hip_atomic_fetch_add(cnt, 1u, __ATOMIC_RELAXED, __HIP_MEMORY_SCOPE_AGENT);
        while (__hip_atomic_load(cnt, __ATOMIC_RELAXED, __HIP_MEMORY_SCOPE_AGENT) < target)
            __builtin_amdgcn_s_sleep(1);
        __threadfence();  // acquire (device scope)
    }
    __syncthreads();
}

#define MFMA16(a, b, c) __builtin_amdgcn_mfma_f32_16x16x32_bf16((a), (b), (c), 0, 0, 0)

__global__ void __launch_bounds__(NTHR, 2) coop_k(P p) {
    extern __shared__ __align__(16) char smem[];
    short* W0s = (short*)smem;                  // 16 x 1544
    short* W1s = W0s + 16 * 1544;               // 16 x 1032
    float* scratch = (float*)(W1s + 16 * 1032); // 2176 floats (8 x 272)
    float* h1s = scratch + 2176;                // 512
    float* aU = h1s + 512;                      // 256
    float* red = aU + 256;                      // 16
    float* bias0s = red + 16;                   // 16
    float* bias1s = bias0s + 16;                // 16
    __shared__ unsigned eps;

    const int tid = threadIdx.x;
    const int blk = blockIdx.x;
    const int l = tid & 63;
    const int w = tid >> 6;
    const int kc8 = (l >> 4) * 8;
    const size_t OFF_HF = (size_t)TT * BH;
    const size_t OFF_CF = OFF_HF + 2 * (size_t)BH;
    const size_t OFF_AT = OFF_CF + 2 * (size_t)BH;

    // --- prologue: load resident weight slices ---
    for (int idx = tid; idx < 16 * 192; idx += NTHR) {
        int n = idx / 192, c = (idx % 192) * 8;
        int g = (n & 3) * 512 + blk * 4 + (n >> 2);
        *reinterpret_cast<s16x8*>(W0s + n * 1544 + c) =
            *reinterpret_cast<const s16x8*>(p.W0cat + (size_t)g * 1536 + c);
    }
    for (int idx = tid; idx < 16 * 128; idx += NTHR) {
        int n = idx / 128, c = (idx % 128) * 8;
        int g = (n & 3) * 512 + blk * 4 + (n >> 2);
        *reinterpret_cast<s16x8*>(W1s + n * 1032 + c) =
            *reinterpret_cast<const s16x8*>(p.W1cat + (size_t)g * 1024 + c);
    }
    if (tid < 16) {
        int g = (tid & 3) * 512 + blk * 4 + (tid >> 2);
        bias0s[tid] = p.bias0[g];
        bias1s[tid] = p.bias1[g];
    }
    if (tid == 0) eps = 0;
    __syncthreads();

    // persistent cell state in registers: lane owns (b = tid>>2, ji = tid&3)
    const int bA = tid >> 2;
    const int ji = tid & 3;
    const int jA = blk * 4 + ji;
    float c0reg = p.c0in[bA * HH + jA];
    float c1reg = p.c0in[BH + bA * HH + jA];

    for (int t = 0; t < TT; ++t) {
        const size_t pB = (size_t)(t & 1) * BH;
        const size_t pN = (size_t)((t & 1) ^ 1) * BH;

        // ---- Phase A: layer-0 gates + cell ----
        {
            const int mrow = w * 16 + (l & 15);
            const int tok = p.tokens[t * BB + mrow];
            const float* erow = p.emb + (size_t)tok * EE + kc8;
            const short* orow = p.outbf + pB + mrow * HH + kc8;
            const short* hrow = p.h0bf + pB + mrow * HH + kc8;
            const short* wrow = W0s + (l & 15) * 1544 + kc8;
            f32x4 acc = {0.f, 0.f, 0.f, 0.f};
#pragma unroll
            for (int k0 = 0; k0 < 512; k0 += 32) {
                float4 x0 = *reinterpret_cast<const float4*>(erow + k0);
                float4 x1 = *reinterpret_cast<const float4*>(erow + k0 + 4);
                s16x8 afr;
                afr[0] = f2b(x0.x); afr[1] = f2b(x0.y); afr[2] = f2b(x0.z); afr[3] = f2b(x0.w);
                afr[4] = f2b(x1.x); afr[5] = f2b(x1.y); afr[6] = f2b(x1.z); afr[7] = f2b(x1.w);
                s16x8 bfr = *reinterpret_cast<const s16x8*>(wrow + k0);
                acc = MFMA16(afr, bfr, acc);
            }
#pragma unroll
            for (int k0 = 0; k0 < 512; k0 += 32) {
                s16x8 afr = *reinterpret_cast<const s16x8*>(orow + k0);
                s16x8 bfr = *reinterpret_cast<const s16x8*>(wrow + 512 + k0);
                acc = MFMA16(afr, bfr, acc);
            }
#pragma unroll
            for (int k0 = 0; k0 < 512; k0 += 32) {
                s16x8 afr = *reinterpret_cast<const s16x8*>(hrow + k0);
                s16x8 bfr = *reinterpret_cast<const s16x8*>(wrow + 1024 + k0);
                acc = MFMA16(afr, bfr, acc);
            }
            float* scr = scratch + w * 272;
#pragma unroll
            for (int r = 0; r < 4; ++r) scr[(l & 15) * 17 + (l >> 4) * 4 + r] = acc[r];
            const int bloc = l >> 2;
            const int n0 = (l & 3) * 4;
            float gi = scr[(n0 + 0) * 17 + bloc] + bias0s[n0 + 0];
            float gf = scr[(n0 + 1) * 17 + bloc] + bias0s[n0 + 1];
            float gg = scr[(n0 + 2) * 17 + bloc] + bias0s[n0 + 2];
            float go = scr[(n0 + 3) * 17 + bloc] + bias0s[n0 + 3];
            float cn = sigm(gf) * c0reg + sigm(gi) * tanhf(gg);
            float hn = sigm(go) * tanhf(cn);
            c0reg = cn;
            p.h0bf[pN + bA * HH + jA] = f2b(hn);
            if (t == TT - 1) {
                p.dout[OFF_HF + bA * HH + jA] = hn;
                p.dout[OFF_CF + bA * HH + jA] = cn;
            }
        }
        gbar(p.cnt, &eps);

        // ---- Phase B: layer-1 gates + cell ----
        {
            const int mrow = w * 16 + (l & 15);
            const short* s0 = p.h0bf + pN + mrow * HH + kc8;
            const short* s1 = p.h1bf + pB + mrow * HH + kc8;
            const short* wrow = W1s + (l & 15) * 1032 + kc8;
            f32x4 acc = {0.f, 0.f, 0.f, 0.f};
#pragma unroll
            for (int k0 = 0; k0 < 512; k0 += 32) {
                s16x8 afr = *reinterpret_cast<const s16x8*>(s0 + k0);
                s16x8 bfr = *reinterpret_cast<const s16x8*>(wrow + k0);
                acc = MFMA16(afr, bfr, acc);
            }
#pragma unroll
            for (int k0 = 0; k0 < 512; k0 += 32) {
                s16x8 afr = *reinterpret_cast<const s16x8*>(s1 + k0);
                s16x8 bfr = *reinterpret_cast<const s16x8*>(wrow + 512 + k0);
                acc = MFMA16(afr, bfr, acc);
            }
            float* scr = scratch + w * 272;
#pragma unroll
            for (int r = 0; r < 4; ++r) scr[(l & 15) * 17 + (l >> 4) * 4 + r] = acc[r];
            const int bloc = l >> 2;
            const int n0 = (l & 3) * 4;
            float gi = scr[(n0 + 0) * 17 + bloc] + bias1s[n0 + 0];
            float gf = scr[(n0 + 1) * 17 + bloc] + bias1s[n0 + 1];
            float gg = scr[(n0 + 2) * 17 + bloc] + bias1s[n0 + 2];
            float go = scr[(n0 + 3) * 17 + bloc] + bias1s[n0 + 3];
            float cn = sigm(gf) * c1reg + sigm(gi) * tanhf(gg);
            float hn = sigm(go) * tanhf(cn);
            c1reg = cn;
            p.h1bf[pN + bA * HH + jA] = f2b(hn);
            if (t == TT - 1) {
                p.dout[OFF_HF + BH + bA * HH + jA] = hn;
                p.dout[OFF_CF + BH + bA * HH + jA] = cn;
            }
        }
        gbar(p.cnt, &eps);

        // ---- Phase C: attention for batch row b = blk ----
        {
            h1s[tid] = b2f(p.h1bf[pN + blk * HH + tid]);
            __syncthreads();
            {
                const int s = tid >> 1, hf = tid & 1;
                const short* cw = p.ctxW + ((size_t)blk * SS + s) * HH + hf * 256;
                const float* hh = h1s + hf * 256;
                float a0 = 0.f, a1 = 0.f;
#pragma unroll 4
                for (int kk = 0; kk < 256; kk += 8) {
                    s16x8 v = *reinterpret_cast<const s16x8*>(cw + kk);
                    float4 hv0 = *reinterpret_cast<const float4*>(hh + kk);
                    float4 hv1 = *reinterpret_cast<const float4*>(hh + kk + 4);
                    a0 += b2f(v[0]) * hv0.x + b2f(v[1]) * hv0.y + b2f(v[2]) * hv0.z + b2f(v[3]) * hv0.w;
                    a1 += b2f(v[4]) * hv1.x + b2f(v[5]) * hv1.y + b2f(v[6]) * hv1.z + b2f(v[7]) * hv1.w;
                }
                scratch[tid] = a0 + a1;
            }
            __syncthreads();
            float sc = -1e30f;
            if (tid < 256) sc = scratch[2 * tid] + scratch[2 * tid + 1];
            float mx = sc;
#pragma unroll
            for (int off = 32; off; off >>= 1) mx = fmaxf(mx, __shfl_xor(mx, off));
            if ((tid & 63) == 0 && tid < 256) red[tid >> 6] = mx;
            __syncthreads();
            const float M = fmaxf(fmaxf(red[0], red[1]), fmaxf(red[2], red[3]));
            float e = 0.f;
            if (tid < 256) { e = __expf(sc - M); aU[tid] = e; }
            float se = e;
#pragma unroll
            for (int off = 32; off; off >>= 1) se += __shfl_xor(se, off);
            if ((tid & 63) == 0 && tid < 256) red[8 + (tid >> 6)] = se;
            __syncthreads();
            const float inv = 1.f / (red[8] + red[9] + red[10] + red[11]);
            if (t == TT - 1 && tid < 256) p.dout[OFF_AT + blk * SS + tid] = aU[tid] * inv;
            {
                const short* cb = p.ctxb + (size_t)blk * SS * HH + tid;
                float acc = 0.f;
#pragma unroll 8
                for (int s2 = 0; s2 < 256; ++s2) acc += aU[s2] * b2f(cb[(size_t)s2 * HH]);
                p.wcbf[blk * HH + tid] = f2b(acc * inv);
            }
        }
        gbar(p.cnt, &eps);

        // ---- Phase D: out = tanh([wc|h1] @ Wout^T), 32 blocks x 16 cols ----
        if (blk < 32) {
            const int mrow = w * 16 + (l & 15);
            const short* wrow = p.Woutb + (size_t)(blk * 16 + (l & 15)) * 1024 + kc8;
            const short* s0 = p.wcbf + mrow * HH + kc8;
            const short* s1 = p.h1bf + pN + mrow * HH + kc8;
            f32x4 acc = {0.f, 0.f, 0.f, 0.f};
#pragma unroll
            for (int k0 = 0; k0 < 512; k0 += 32) {
                s16x8 afr = *reinterpret_cast<const s16x8*>(s0 + k0);
                s16x8 bfr = *reinterpret_cast<const s16x8*>(wrow + k0);
                acc = MFMA16(afr, bfr, acc);
            }
#pragma unroll
            for (int k0 = 0; k0 < 512; k0 += 32) {
                s16x8 afr = *reinterpret_cast<const s16x8*>(s1 + k0);
                s16x8 bfr = *reinterpret_cast<const s16x8*>(wrow + 512 + k0);
                acc = MFMA16(afr, bfr, acc);
            }
            const int col = blk * 16 + (l & 15);
#pragma unroll
            for (int r = 0; r < 4; ++r) {
                const int brow = w * 16 + (l >> 4) * 4 + r;
                float tv = tanhf(acc[r]);
                p.dout[(size_t)t * BH + brow * HH + col] = tv;
                p.outbf[pN + brow * HH + col] = f2b(tv);
            }
        }
        gbar(p.cnt, &eps);
    }
}

// ---------------- host ----------------

extern "C" void kernel_launch(void* const* d_in, const int* in_sizes, int n_in,
                              void* d_out, int out_size, void* d_ws, size_t ws_size,
                              hipStream_t stream) {
    const int* tokens = (const int*)d_in[0];
    const float* h0in = (const float*)d_in[1];
    const float* c0in = (const float*)d_in[2];
    const float* ctx = (const float*)d_in[3];
    const float* iout = (const float*)d_in[4];
    const float* emb = (const float*)d_in[5];
    const float* Wih0 = (const float*)d_in[6];
    const float* bih0 = (const float*)d_in[7];
    const float* Whh0 = (const float*)d_in[8];
    const float* bhh0 = (const float*)d_in[9];
    const float* Wih1 = (const float*)d_in[10];
    const float* bih1 = (const float*)d_in[11];
    const float* Whh1 = (const float*)d_in[12];
    const float* bhh1 = (const float*)d_in[13];
    const float* Win = (const float*)d_in[14];
    const float* Wout = (const float*)d_in[15];
    float* dout = (float*)d_out;

    char* pw = (char*)d_ws;
    auto take = [&](size_t bytes) { char* r = pw; pw += (bytes + 255) & ~(size_t)255; return r; };
    short* W0cat = (short*)take((size_t)2048 * 1536 * 2);
    short* W1cat = (short*)take((size_t)2048 * 1024 * 2);
    short* Winb  = (short*)take((size_t)512 * 512 * 2);
    short* Woutb = (short*)take((size_t)512 * 1024 * 2);
    float* bias0 = (float*)take(2048 * 4);
    float* bias1 = (float*)take(2048 * 4);
    short* ctxb  = (short*)take((size_t)BB * SS * HH * 2);
    short* ctxW  = (short*)take((size_t)BB * SS * HH * 2);
    short* h0bf  = (short*)take((size_t)2 * BH * 2);
    short* h1bf  = (short*)take((size_t)2 * BH * 2);
    short* outbf = (short*)take((size_t)2 * BH * 2);
    short* wcbf  = (short*)take((size_t)BH * 2);
    unsigned* cnt = (unsigned*)take(256);

    k_pack2<<<2048, 256, 0, stream>>>(Wih0, 1024, Whh0, 512, W0cat, 2048 * 1536);
    k_pack2<<<2048, 256, 0, stream>>>(Wih1, 512, Whh1, 512, W1cat, 2048 * 1024);
    k_pack2<<<1024, 256, 0, stream>>>(Win, 512, Win, 0, Winb, 512 * 512);
    k_pack2<<<1024, 256, 0, stream>>>(Wout, 1024, Wout, 0, Woutb, 512 * 1024);
    k_bias<<<8, 256, 0, stream>>>(bih0, bhh0, bias0, bih1, bhh1, bias1);
    k_ctx<<<4096, 256, 0, stream>>>(ctx, ctxb);
    k_state<<<256, 256, 0, stream>>>(h0in, iout, h0bf, h1bf, outbf);
    k_ctxw<<<dim3(8, 256), 512, 0, stream>>>(ctxb, Winb, ctxW);
    (void)hipMemsetAsync(cnt, 0, 256, stream);

    const unsigned smem_bytes = (16 * 1544 + 16 * 1032) * 2 + (2176 + 512 + 256 + 16 + 16 + 16) * 4;
    (void)hipFuncSetAttribute((const void*)coop_k, hipFuncAttributeMaxDynamicSharedMemorySize, (int)smem_bytes);

    P prm;
    prm.tokens = tokens; prm.emb = emb; prm.c0in = c0in;
    prm.ctxb = ctxb; prm.ctxW = ctxW;
    prm.W0cat = W0cat; prm.W1cat = W1cat; prm.Woutb = Woutb;
    prm.bias0 = bias0; prm.bias1 = bias1;
    prm.h0bf = h0bf; prm.h1bf = h1bf; prm.outbf = outbf; prm.wcbf = wcbf;
    prm.dout = dout; prm.cnt = cnt;
    void* args[] = {&prm};
    (void)hipLaunchCooperativeKernel((void*)coop_k, dim3(NBLK), dim3(NTHR), args, smem_bytes, stream);
}

// Round 4
// 24120.927 us; speedup vs baseline: 1.5945x; 1.0536x over previous
//
#include <hip/hip_runtime.h>
#include <hip/hip_bf16.h>
#include <math.h>

#define TT 256
#define BB 128
#define SS 256
#define HH 512
#define EE 512
#define NBLK 128
#define NTHR 512
#define BH (BB * HH)

typedef __attribute__((ext_vector_type(4))) float f32x4;
typedef __attribute__((ext_vector_type(8))) short s16x8;
typedef unsigned long long u64;

__device__ __forceinline__ float b2f(short v) {
    union { unsigned u; float f; } c;
    c.u = ((unsigned)(unsigned short)v) << 16;
    return c.f;
}
__device__ __forceinline__ short f2b(float f) {
    union { float f; unsigned u; } c; c.f = f;
    unsigned u = c.u;
    unsigned r = (u + 0x7fffu + ((u >> 16) & 1u)) >> 16;
    return (short)r;
}
__device__ __forceinline__ float sigm(float x) { return 1.f / (1.f + __expf(-x)); }

// coherent (agent-scope, L2-bypassing) exchange primitives
__device__ __forceinline__ u64 aldq(const void* p) {
    return __hip_atomic_load((const u64*)p, __ATOMIC_RELAXED, __HIP_MEMORY_SCOPE_AGENT);
}
__device__ __forceinline__ s16x8 ald8(const short* p) {
    union { u64 q[2]; s16x8 v; } c;
    c.q[0] = aldq(p);
    c.q[1] = aldq(p + 4);
    return c.v;
}
__device__ __forceinline__ void ast2(short* p, short v) {
    __hip_atomic_store(p, v, __ATOMIC_RELAXED, __HIP_MEMORY_SCOPE_AGENT);
}

// ---------------- prep kernels ----------------

__global__ void k_pack2(const float* __restrict__ Wa, int ka, const float* __restrict__ Wb, int kb,
                        short* __restrict__ dst, int n) {
    const int K = ka + kb;
    for (int i = blockIdx.x * blockDim.x + threadIdx.x; i < n; i += gridDim.x * blockDim.x) {
        int g = i / K, k = i - g * K;
        float v = (k < ka) ? Wa[(size_t)g * ka + k] : Wb[(size_t)g * kb + (k - ka)];
        dst[i] = f2b(v);
    }
}

// WoutP[m*512 + j] = pack2bf16(Wout[j][2m], Wout[j][2m+1]), m in [0,512), j in [0,512)
__global__ void k_packwout(const float* __restrict__ Wout, unsigned* __restrict__ WoutP) {
    int i = blockIdx.x * blockDim.x + threadIdx.x;
    if (i < 512 * 512) {
        int m = i >> 9, j = i & 511;
        unsigned lo = (unsigned)(unsigned short)f2b(Wout[(size_t)j * 1024 + 2 * m]);
        unsigned hi = (unsigned)(unsigned short)f2b(Wout[(size_t)j * 1024 + 2 * m + 1]);
        WoutP[i] = lo | (hi << 16);
    }
}

__global__ void k_bias(const float* __restrict__ a, const float* __restrict__ b, float* __restrict__ o,
                       const float* __restrict__ a2, const float* __restrict__ b2, float* __restrict__ o2) {
    int i = blockIdx.x * blockDim.x + threadIdx.x;
    if (i < 2048) { o[i] = a[i] + b[i]; o2[i] = a2[i] + b2[i]; }
}

__global__ void k_ctx(const float* __restrict__ ctx, short* __restrict__ Ctxb) {
    const int n = BB * SS * HH;
    for (int i = blockIdx.x * blockDim.x + threadIdx.x; i < n; i += gridDim.x * blockDim.x) {
        int b = i / (SS * HH);
        int r = i - b * SS * HH;
        int s = r >> 9, h = r & 511;
        Ctxb[i] = f2b(ctx[((size_t)s * BB + b) * HH + h]);
    }
}

__global__ void k_state(const float* __restrict__ h0in, const float* __restrict__ iout,
                        short* __restrict__ h0x, short* __restrict__ h1x, short* __restrict__ outx) {
    int i = blockIdx.x * blockDim.x + threadIdx.x;
    if (i < BH) {
        h0x[i] = f2b(h0in[i]);
        h1x[i] = f2b(h0in[BH + i]);
        outx[i] = f2b(iout[i]);
    }
}

// ctxW[(b*S+s), n] = sum_k ctxb[(b*S+s), k] * Win[n, k]
__global__ __launch_bounds__(512) void k_ctxw(const short* __restrict__ ctxb, const short* __restrict__ Winb,
                                              short* __restrict__ ctxW) {
    const int tid = threadIdx.x, w = tid >> 6, l = tid & 63;
    const int m0 = blockIdx.y * 128, n0 = blockIdx.x * 64;
    const int kc8 = (l >> 4) * 8;
    const short* arow = ctxb + (size_t)(m0 + w * 16 + (l & 15)) * HH + kc8;
    f32x4 acc[4];
    const f32x4 zero = {0.f, 0.f, 0.f, 0.f};
#pragma unroll
    for (int j = 0; j < 4; ++j) acc[j] = zero;
#pragma unroll
    for (int kc = 0; kc < 16; ++kc) {
        const int k0 = kc * 32;
        s16x8 afr = *reinterpret_cast<const s16x8*>(arow + k0);
#pragma unroll
        for (int j = 0; j < 4; ++j) {
            s16x8 bfr = *reinterpret_cast<const s16x8*>(Winb + (size_t)(n0 + j * 16 + (l & 15)) * HH + k0 + kc8);
            acc[j] = __builtin_amdgcn_mfma_f32_16x16x32_bf16(afr, bfr, acc[j], 0, 0, 0);
        }
    }
#pragma unroll
    for (int j = 0; j < 4; ++j)
#pragma unroll
        for (int r = 0; r < 4; ++r)
            ctxW[(size_t)(m0 + w * 16 + (l >> 4) * 4 + r) * HH + n0 + j * 16 + (l & 15)] = f2b(acc[j][r]);
}

// ---------------- persistent cooperative kernel ----------------

struct P {
    const int* tokens;
    const float* emb;
    const float* c0in;
    const short* ctxb;
    const short* ctxW;
    const short* W0cat;
    const short* W1cat;
    const unsigned* WoutP;
    const float* bias0;
    const float* bias1;
    short* h0x;
    short* h1x;
    short* outx;
    float* dout;
    unsigned* cnt;
};

// fence-free grid barrier: all cross-block data moves via agent-scope atomics,
// so no L2 writeback/invalidate is needed — only ordering (syncthreads drains
// vmcnt for every thread before the flag increment).
__device__ __forceinline__ void gbar(unsigned* cnt, unsigned* eps) {
    __syncthreads();
    if (threadIdx.x == 0) {
        asm volatile("s_waitcnt vmcnt(0)" ::: "memory");
        const unsigned target = (++(*eps)) * (unsigned)NBLK;
        __hip_atomic_fetch_add(cnt, 1u, __ATOMIC_RELAXED, __HIP_MEMORY_SCOPE_AGENT);
        while (__hip_atomic_load(cnt, __ATOMIC_RELAXED, __HIP_MEMORY_SCOPE_AGENT) < target)
            __builtin_amdgcn_s_sleep(1);
    }
    __syncthreads();
}

#define MFMA16(a, b, c) __builtin_amdgcn_mfma_f32_16x16x32_bf16((a), (b), (c), 0, 0, 0)

__global__ void __launch_bounds__(NTHR, 2) coop_k(P p) {
    extern __shared__ __align__(16) char smem[];
    short* W0s = (short*)smem;                  // 16 x 1544
    short* W1s = W0s + 16 * 1544;               // 16 x 1032
    float* scratch = (float*)(W1s + 16 * 1032); // 8 x 272 = 2176 floats
    float* h1s = scratch + 2176;                // 512
    float* wcf = h1s + 512;                     // 512
    float* aU = wcf + 512;                      // 256
    float* red = aU + 256;                      // 16
    float* bias0s = red + 16;                   // 16
    float* bias1s = bias0s + 16;                // 16

    const int tid = threadIdx.x;
    const int blk = blockIdx.x;
    const int l = tid & 63;
    const int w = tid >> 6;
    const int kc8 = (l >> 4) * 8;
    const size_t OFF_HF = (size_t)TT * BH;
    const size_t OFF_CF = OFF_HF + 2 * (size_t)BH;
    const size_t OFF_AT = OFF_CF + 2 * (size_t)BH;
    unsigned eps = 0;

    // --- prologue: load resident weight slices ---
    for (int idx = tid; idx < 16 * 192; idx += NTHR) {
        int n = idx / 192, c = (idx % 192) * 8;
        int g = (n & 3) * 512 + blk * 4 + (n >> 2);
        *reinterpret_cast<s16x8*>(W0s + n * 1544 + c) =
            *reinterpret_cast<const s16x8*>(p.W0cat + (size_t)g * 1536 + c);
    }
    for (int idx = tid; idx < 16 * 128; idx += NTHR) {
        int n = idx / 128, c = (idx % 128) * 8;
        int g = (n & 3) * 512 + blk * 4 + (n >> 2);
        *reinterpret_cast<s16x8*>(W1s + n * 1032 + c) =
            *reinterpret_cast<const s16x8*>(p.W1cat + (size_t)g * 1024 + c);
    }
    if (tid < 16) {
        int g = (tid & 3) * 512 + blk * 4 + (tid >> 2);
        bias0s[tid] = p.bias0[g];
        bias1s[tid] = p.bias1[g];
    }
    __syncthreads();

    // persistent cell state in registers: thread owns (bA = tid>>2, jA = blk*4 + (tid&3))
    const int bA = tid >> 2;
    const int jA = blk * 4 + (tid & 3);
    float c0reg = p.c0in[bA * HH + jA];
    float c1reg = p.c0in[BH + bA * HH + jA];

    for (int t = 0; t < TT; ++t) {
        const size_t pB = (size_t)(t & 1) * BH;
        const size_t pN = (size_t)((t & 1) ^ 1) * BH;

        // ---- Phase A: layer-0 gates + cell ----
        {
            const int mrow = w * 16 + (l & 15);
            const int tok = p.tokens[t * BB + mrow];
            const float* erow = p.emb + (size_t)tok * EE + kc8;
            const short* orow = p.outx + pB + mrow * HH + kc8;
            const short* hrow = p.h0x + pB + mrow * HH + kc8;
            const short* wrow = W0s + (l & 15) * 1544 + kc8;
            const f32x4 zero = {0.f, 0.f, 0.f, 0.f};
            f32x4 aE = zero, aO = zero, aHr = zero;
#pragma unroll
            for (int k0 = 0; k0 < 512; k0 += 32) {
                float4 x0 = *reinterpret_cast<const float4*>(erow + k0);
                float4 x1 = *reinterpret_cast<const float4*>(erow + k0 + 4);
                s16x8 afr;
                afr[0] = f2b(x0.x); afr[1] = f2b(x0.y); afr[2] = f2b(x0.z); afr[3] = f2b(x0.w);
                afr[4] = f2b(x1.x); afr[5] = f2b(x1.y); afr[6] = f2b(x1.z); afr[7] = f2b(x1.w);
                aE = MFMA16(afr, *reinterpret_cast<const s16x8*>(wrow + k0), aE);
            }
#pragma unroll
            for (int k0 = 0; k0 < 512; k0 += 32)
                aO = MFMA16(ald8(orow + k0), *reinterpret_cast<const s16x8*>(wrow + 512 + k0), aO);
#pragma unroll
            for (int k0 = 0; k0 < 512; k0 += 32)
                aHr = MFMA16(ald8(hrow + k0), *reinterpret_cast<const s16x8*>(wrow + 1024 + k0), aHr);
            f32x4 acc = aE + aO + aHr;
            float* scr = scratch + w * 272;
#pragma unroll
            for (int r = 0; r < 4; ++r) scr[(l & 15) * 17 + (l >> 4) * 4 + r] = acc[r];
            __syncthreads();
            const int bloc = l >> 2;
            const int n0 = (l & 3) * 4;
            float gi = scr[(n0 + 0) * 17 + bloc] + bias0s[n0 + 0];
            float gf = scr[(n0 + 1) * 17 + bloc] + bias0s[n0 + 1];
            float gg = scr[(n0 + 2) * 17 + bloc] + bias0s[n0 + 2];
            float go = scr[(n0 + 3) * 17 + bloc] + bias0s[n0 + 3];
            float cn = sigm(gf) * c0reg + sigm(gi) * tanhf(gg);
            float hn = sigm(go) * tanhf(cn);
            c0reg = cn;
            ast2(&p.h0x[pN + bA * HH + jA], f2b(hn));
            if (t == TT - 1) {
                p.dout[OFF_HF + bA * HH + jA] = hn;
                p.dout[OFF_CF + bA * HH + jA] = cn;
            }
        }
        gbar(p.cnt, &eps);

        // ---- Phase B: layer-1 gates + cell ----
        {
            const int mrow = w * 16 + (l & 15);
            const short* s0 = p.h0x + pN + mrow * HH + kc8;
            const short* s1 = p.h1x + pB + mrow * HH + kc8;
            const short* wrow = W1s + (l & 15) * 1032 + kc8;
            const f32x4 zero = {0.f, 0.f, 0.f, 0.f};
            f32x4 a0 = zero, a1 = zero;
#pragma unroll
            for (int k0 = 0; k0 < 512; k0 += 32)
                a0 = MFMA16(ald8(s0 + k0), *reinterpret_cast<const s16x8*>(wrow + k0), a0);
#pragma unroll
            for (int k0 = 0; k0 < 512; k0 += 32)
                a1 = MFMA16(ald8(s1 + k0), *reinterpret_cast<const s16x8*>(wrow + 512 + k0), a1);
            f32x4 acc = a0 + a1;
            float* scr = scratch + w * 272;
#pragma unroll
            for (int r = 0; r < 4; ++r) scr[(l & 15) * 17 + (l >> 4) * 4 + r] = acc[r];
            __syncthreads();
            const int bloc = l >> 2;
            const int n0 = (l & 3) * 4;
            float gi = scr[(n0 + 0) * 17 + bloc] + bias1s[n0 + 0];
            float gf = scr[(n0 + 1) * 17 + bloc] + bias1s[n0 + 1];
            float gg = scr[(n0 + 2) * 17 + bloc] + bias1s[n0 + 2];
            float go = scr[(n0 + 3) * 17 + bloc] + bias1s[n0 + 3];
            float cn = sigm(gf) * c1reg + sigm(gi) * tanhf(gg);
            float hn = sigm(go) * tanhf(cn);
            c1reg = cn;
            ast2(&p.h1x[pN + bA * HH + jA], f2b(hn));
            if (t == TT - 1) {
                p.dout[OFF_HF + BH + bA * HH + jA] = hn;
                p.dout[OFF_CF + BH + bA * HH + jA] = cn;
            }
        }
        gbar(p.cnt, &eps);

        // ---- Phase C+D: attention + output GEMV for batch row b = blk ----
        {
            if (tid < 128) {
                union { u64 q; short s[4]; } c;
                c.q = aldq(p.h1x + pN + blk * HH + tid * 4);
#pragma unroll
                for (int j = 0; j < 4; ++j) h1s[tid * 4 + j] = b2f(c.s[j]);
            }
            __syncthreads();
            {
                const int s = tid >> 1, hf = tid & 1;
                const short* cw = p.ctxW + ((size_t)blk * SS + s) * HH + hf * 256;
                const float* hh = h1s + hf * 256;
                float a0 = 0.f, a1 = 0.f;
#pragma unroll 8
                for (int kk = 0; kk < 256; kk += 8) {
                    s16x8 v = *reinterpret_cast<const s16x8*>(cw + kk);
                    float4 hv0 = *reinterpret_cast<const float4*>(hh + kk);
                    float4 hv1 = *reinterpret_cast<const float4*>(hh + kk + 4);
                    a0 += b2f(v[0]) * hv0.x + b2f(v[1]) * hv0.y + b2f(v[2]) * hv0.z + b2f(v[3]) * hv0.w;
                    a1 += b2f(v[4]) * hv1.x + b2f(v[5]) * hv1.y + b2f(v[6]) * hv1.z + b2f(v[7]) * hv1.w;
                }
                scratch[tid] = a0 + a1;
            }
            __syncthreads();
            float sc = -1e30f;
            if (tid < 256) sc = scratch[2 * tid] + scratch[2 * tid + 1];
            float mx = sc;
#pragma unroll
            for (int off = 32; off; off >>= 1) mx = fmaxf(mx, __shfl_xor(mx, off));
            if ((tid & 63) == 0 && tid < 256) red[tid >> 6] = mx;
            __syncthreads();
            const float M = fmaxf(fmaxf(red[0], red[1]), fmaxf(red[2], red[3]));
            float e = 0.f;
            if (tid < 256) { e = __expf(sc - M); aU[tid] = e; }
            float se = e;
#pragma unroll
            for (int off = 32; off; off >>= 1) se += __shfl_xor(se, off);
            if ((tid & 63) == 0 && tid < 256) red[8 + (tid >> 6)] = se;
            __syncthreads();
            const float inv = 1.f / (red[8] + red[9] + red[10] + red[11]);
            if (t == TT - 1 && tid < 256) p.dout[OFF_AT + blk * SS + tid] = aU[tid] * inv;
            {
                const short* cb = p.ctxb + (size_t)blk * SS * HH + tid;
                float acc = 0.f;
#pragma unroll 16
                for (int s2 = 0; s2 < 256; ++s2) acc += aU[s2] * b2f(cb[(size_t)s2 * HH]);
                wcf[tid] = acc * inv;
            }
            __syncthreads();
            // fused out-GEMV: out[blk, tid] = tanh(sum_k [wc|h1][k] * Wout[tid][k])
            {
                const unsigned* wp = p.WoutP + tid;
                float acc = 0.f;
#pragma unroll 16
                for (int m = 0; m < 256; ++m) {
                    unsigned wv = wp[(size_t)m * 512];
                    acc += b2f((short)(wv & 0xffff)) * wcf[2 * m] + b2f((short)(wv >> 16)) * wcf[2 * m + 1];
                }
#pragma unroll 16
                for (int m = 256; m < 512; ++m) {
                    unsigned wv = wp[(size_t)m * 512];
                    acc += b2f((short)(wv & 0xffff)) * h1s[2 * m - 512] + b2f((short)(wv >> 16)) * h1s[2 * m - 511];
                }
                float tv = tanhf(acc);
                __builtin_nontemporal_store(tv, &p.dout[(size_t)t * BH + blk * HH + tid]);
                ast2(&p.outx[pN + blk * HH + tid], f2b(tv));
            }
        }
        gbar(p.cnt, &eps);
    }
}

// ---------------- host ----------------

extern "C" void kernel_launch(void* const* d_in, const int* in_sizes, int n_in,
                              void* d_out, int out_size, void* d_ws, size_t ws_size,
                              hipStream_t stream) {
    const int* tokens = (const int*)d_in[0];
    const float* h0in = (const float*)d_in[1];
    const float* c0in = (const float*)d_in[2];
    const float* ctx = (const float*)d_in[3];
    const float* iout = (const float*)d_in[4];
    const float* emb = (const float*)d_in[5];
    const float* Wih0 = (const float*)d_in[6];
    const float* bih0 = (const float*)d_in[7];
    const float* Whh0 = (const float*)d_in[8];
    const float* bhh0 = (const float*)d_in[9];
    const float* Wih1 = (const float*)d_in[10];
    const float* bih1 = (const float*)d_in[11];
    const float* Whh1 = (const float*)d_in[12];
    const float* bhh1 = (const float*)d_in[13];
    const float* Win = (const float*)d_in[14];
    const float* Wout = (const float*)d_in[15];
    float* dout = (float*)d_out;

    char* pw = (char*)d_ws;
    auto take = [&](size_t bytes) { char* r = pw; pw += (bytes + 255) & ~(size_t)255; return r; };
    short* W0cat = (short*)take((size_t)2048 * 1536 * 2);
    short* W1cat = (short*)take((size_t)2048 * 1024 * 2);
    short* Winb  = (short*)take((size_t)512 * 512 * 2);
    unsigned* WoutP = (unsigned*)take((size_t)512 * 512 * 4);
    float* bias0 = (float*)take(2048 * 4);
    float* bias1 = (float*)take(2048 * 4);
    short* ctxb  = (short*)take((size_t)BB * SS * HH * 2);
    short* ctxW  = (short*)take((size_t)BB * SS * HH * 2);
    short* h0x   = (short*)take((size_t)2 * BH * 2);
    short* h1x   = (short*)take((size_t)2 * BH * 2);
    short* outx  = (short*)take((size_t)2 * BH * 2);
    unsigned* cnt = (unsigned*)take(256);

    k_pack2<<<2048, 256, 0, stream>>>(Wih0, 1024, Whh0, 512, W0cat, 2048 * 1536);
    k_pack2<<<2048, 256, 0, stream>>>(Wih1, 512, Whh1, 512, W1cat, 2048 * 1024);
    k_pack2<<<1024, 256, 0, stream>>>(Win, 512, Win, 0, Winb, 512 * 512);
    k_packwout<<<1024, 256, 0, stream>>>(Wout, WoutP);
    k_bias<<<8, 256, 0, stream>>>(bih0, bhh0, bias0, bih1, bhh1, bias1);
    k_ctx<<<4096, 256, 0, stream>>>(ctx, ctxb);
    k_state<<<256, 256, 0, stream>>>(h0in, iout, h0x, h1x, outx);
    k_ctxw<<<dim3(8, 256), 512, 0, stream>>>(ctxb, Winb, ctxW);
    (void)hipMemsetAsync(cnt, 0, 256, stream);

    const unsigned smem_bytes = (16 * 1544 + 16 * 1032) * 2 + (2176 + 512 + 512 + 256 + 16 + 16 + 16) * 4;
    (void)hipFuncSetAttribute((const void*)coop_k, hipFuncAttributeMaxDynamicSharedMemorySize, (int)smem_bytes);

    P prm;
    prm.tokens = tokens; prm.emb = emb; prm.c0in = c0in;
    prm.ctxb = ctxb; prm.ctxW = ctxW;
    prm.W0cat = W0cat; prm.W1cat = W1cat; prm.WoutP = WoutP;
    prm.bias0 = bias0; prm.bias1 = bias1;
    prm.h0x = h0x; prm.h1x = h1x; prm.outx = outx;
    prm.dout = dout; prm.cnt = cnt;
    void* args[] = {&prm};
    (void)hipLaunchCooperativeKernel((void*)coop_k, dim3(NBLK), dim3(NTHR), args, smem_bytes, stream);
}

// Round 5
// 21428.101 us; speedup vs baseline: 1.7948x; 1.1257x over previous
//
#include <hip/hip_runtime.h>
#include <hip/hip_bf16.h>
#include <math.h>

#define TT 256
#define BB 128
#define SS 256
#define HH 512
#define EE 512
#define NBLK 128
#define NTHR 512
#define BH (BB * HH)

typedef __attribute__((ext_vector_type(4))) float f32x4;
typedef __attribute__((ext_vector_type(8))) short s16x8;
typedef unsigned long long u64;

__device__ __forceinline__ float b2f(short v) {
    union { unsigned u; float f; } c;
    c.u = ((unsigned)(unsigned short)v) << 16;
    return c.f;
}
__device__ __forceinline__ short f2b(float f) {
    union { float f; unsigned u; } c; c.f = f;
    unsigned u = c.u;
    unsigned r = (u + 0x7fffu + ((u >> 16) & 1u)) >> 16;
    return (short)r;
}
__device__ __forceinline__ float sigm(float x) { return 1.f / (1.f + __expf(-x)); }

// L2-bypassing (agent-scope) exchange primitives: coherent at LLC, no cache flushes
__device__ __forceinline__ u64 aldq(const void* p) {
    return __hip_atomic_load((const u64*)p, __ATOMIC_RELAXED, __HIP_MEMORY_SCOPE_AGENT);
}
__device__ __forceinline__ void ast2(short* p, short v) {
    __hip_atomic_store(p, v, __ATOMIC_RELAXED, __HIP_MEMORY_SCOPE_AGENT);
}

// ---------------- prep kernels ----------------

__global__ void k_pack2(const float* __restrict__ Wa, int ka, const float* __restrict__ Wb, int kb,
                        short* __restrict__ dst, int n) {
    const int K = ka + kb;
    for (int i = blockIdx.x * blockDim.x + threadIdx.x; i < n; i += gridDim.x * blockDim.x) {
        int g = i / K, k = i - g * K;
        float v = (k < ka) ? Wa[(size_t)g * ka + k] : Wb[(size_t)g * kb + (k - ka)];
        dst[i] = f2b(v);
    }
}

__global__ void k_packwout(const float* __restrict__ Wout, unsigned* __restrict__ WoutP) {
    int i = blockIdx.x * blockDim.x + threadIdx.x;
    if (i < 512 * 512) {
        int m = i >> 9, j = i & 511;
        unsigned lo = (unsigned)(unsigned short)f2b(Wout[(size_t)j * 1024 + 2 * m]);
        unsigned hi = (unsigned)(unsigned short)f2b(Wout[(size_t)j * 1024 + 2 * m + 1]);
        WoutP[i] = lo | (hi << 16);
    }
}

__global__ void k_bias(const float* __restrict__ a, const float* __restrict__ b, float* __restrict__ o,
                       const float* __restrict__ a2, const float* __restrict__ b2, float* __restrict__ o2) {
    int i = blockIdx.x * blockDim.x + threadIdx.x;
    if (i < 2048) { o[i] = a[i] + b[i]; o2[i] = a2[i] + b2[i]; }
}

__global__ void k_ctx(const float* __restrict__ ctx, short* __restrict__ Ctxb) {
    const int n = BB * SS * HH;
    for (int i = blockIdx.x * blockDim.x + threadIdx.x; i < n; i += gridDim.x * blockDim.x) {
        int b = i / (SS * HH);
        int r = i - b * SS * HH;
        int s = r >> 9, h = r & 511;
        Ctxb[i] = f2b(ctx[((size_t)s * BB + b) * HH + h]);
    }
}

__global__ void k_state(const float* __restrict__ h0in, const float* __restrict__ iout,
                        short* __restrict__ h0x, short* __restrict__ h1x, short* __restrict__ outx) {
    int i = blockIdx.x * blockDim.x + threadIdx.x;
    if (i < BH) {
        h0x[i] = f2b(h0in[i]);
        h1x[i] = f2b(h0in[BH + i]);
        outx[i] = f2b(iout[i]);
    }
}

// ctxW[(b*S+s), n] = sum_k ctxb[(b*S+s), k] * Win[n, k]
__global__ __launch_bounds__(512) void k_ctxw(const short* __restrict__ ctxb, const short* __restrict__ Winb,
                                              short* __restrict__ ctxW) {
    const int tid = threadIdx.x, w = tid >> 6, l = tid & 63;
    const int m0 = blockIdx.y * 128, n0 = blockIdx.x * 64;
    const int kc8 = (l >> 4) * 8;
    const short* arow = ctxb + (size_t)(m0 + w * 16 + (l & 15)) * HH + kc8;
    f32x4 acc[4];
    const f32x4 zero = {0.f, 0.f, 0.f, 0.f};
#pragma unroll
    for (int j = 0; j < 4; ++j) acc[j] = zero;
#pragma unroll
    for (int kc = 0; kc < 16; ++kc) {
        const int k0 = kc * 32;
        s16x8 afr = *reinterpret_cast<const s16x8*>(arow + k0);
#pragma unroll
        for (int j = 0; j < 4; ++j) {
            s16x8 bfr = *reinterpret_cast<const s16x8*>(Winb + (size_t)(n0 + j * 16 + (l & 15)) * HH + k0 + kc8);
            acc[j] = __builtin_amdgcn_mfma_f32_16x16x32_bf16(afr, bfr, acc[j], 0, 0, 0);
        }
    }
#pragma unroll
    for (int j = 0; j < 4; ++j)
#pragma unroll
        for (int r = 0; r < 4; ++r)
            ctxW[(size_t)(m0 + w * 16 + (l >> 4) * 4 + r) * HH + n0 + j * 16 + (l & 15)] = f2b(acc[j][r]);
}

// ---------------- persistent cooperative kernel ----------------

struct P {
    const int* tokens;
    const float* emb;
    const float* c0in;
    const short* ctxb;
    const short* ctxW;
    const short* W0cat;
    const short* W1cat;
    const unsigned* WoutP;
    const float* bias0;
    const float* bias1;
    short* h0x;
    short* h1x;
    short* outx;
    float* dout;
    unsigned* flags;
};

#define MFMA16(a, b, c) __builtin_amdgcn_mfma_f32_16x16x32_bf16((a), (b), (c), 0, 0, 0)

// XOR-swizzled LDS fragment read (stride in shorts, multiple of 8; col8 = 16B chunk idx)
__device__ __forceinline__ s16x8 ldsfrag(const short* base, int stride, int row, int col8) {
    return *reinterpret_cast<const s16x8*>(base + row * stride + ((col8 ^ (row & 7)) << 3));
}

// bulk-stage 64KB (128 rows x 256 shorts) of an exchange buffer into LDS:
// batched LLC loads (all 16 in flight) then swizzled ds_writes.
__device__ __forceinline__ void stage_half(const short* __restrict__ src, short* __restrict__ stg,
                                           int tid, int khalf) {
    u64 q[16];
#pragma unroll
    for (int c = 0; c < 8; ++c) {
        const int chunk = c * 512 + tid;
        const int row = chunk >> 5, col8 = chunk & 31;
        const short* s = src + row * HH + khalf * 256 + col8 * 8;
        q[2 * c] = aldq(s);
        q[2 * c + 1] = aldq(s + 4);
    }
#pragma unroll
    for (int c = 0; c < 8; ++c) {
        const int chunk = c * 512 + tid;
        const int row = chunk >> 5, col8 = chunk & 31;
        short* d = stg + row * 256 + ((col8 ^ (row & 7)) << 3);
        *reinterpret_cast<u64*>(d) = q[2 * c];
        *reinterpret_cast<u64*>(d + 4) = q[2 * c + 1];
    }
}

// flag-array grid barrier: one sc1 store arrival per block, parallel coalesced spin
__device__ __forceinline__ void gbar(unsigned* flags, unsigned target) {
    asm volatile("s_waitcnt vmcnt(0)" ::: "memory");
    __syncthreads();
    const int tid = threadIdx.x;
    if (tid == 0)
        __hip_atomic_store(&flags[blockIdx.x], target, __ATOMIC_RELAXED, __HIP_MEMORY_SCOPE_AGENT);
    if (tid < NBLK) {
        while (__hip_atomic_load(&flags[tid], __ATOMIC_RELAXED, __HIP_MEMORY_SCOPE_AGENT) < target)
            __builtin_amdgcn_s_sleep(2);
    }
    __syncthreads();
}

__global__ void __launch_bounds__(NTHR, 1) coop_k(P p) {
    extern __shared__ __align__(16) char smem[];
    short* W0s = (short*)smem;              // 16 rows x 1536 (swizzled)
    short* W1s = W0s + 16 * 1536;           // 16 rows x 1024 (swizzled)
    short* stg = W1s + 16 * 1024;           // 128 rows x 256 (swizzled stage / scratch)
    float* biasS = (float*)(stg + 128 * 256); // 32 floats

    const int tid = threadIdx.x;
    const int blk = blockIdx.x;
    const int l = tid & 63;
    const int w = tid >> 6;
    const int mrow = w * 16 + (l & 15);
    const int kq = l >> 4;      // 0..3
    const int kc8 = kq * 8;
    const size_t OFF_HF = (size_t)TT * BH;
    const size_t OFF_CF = OFF_HF + 2 * (size_t)BH;
    const size_t OFF_AT = OFF_CF + 2 * (size_t)BH;

    // --- prologue: LDS-resident weight slices (swizzled) ---
    for (int idx = tid; idx < 16 * 192; idx += NTHR) {
        int row = idx / 192, col8 = idx % 192;
        int g = (row & 3) * 512 + blk * 4 + (row >> 2);
        *reinterpret_cast<s16x8*>(W0s + row * 1536 + ((col8 ^ (row & 7)) << 3)) =
            *reinterpret_cast<const s16x8*>(p.W0cat + (size_t)g * 1536 + col8 * 8);
    }
    for (int idx = tid; idx < 16 * 128; idx += NTHR) {
        int row = idx / 128, col8 = idx % 128;
        int g = (row & 3) * 512 + blk * 4 + (row >> 2);
        *reinterpret_cast<s16x8*>(W1s + row * 1024 + ((col8 ^ (row & 7)) << 3)) =
            *reinterpret_cast<const s16x8*>(p.W1cat + (size_t)g * 1024 + col8 * 8);
    }
    if (tid < 16) {
        int g = (tid & 3) * 512 + blk * 4 + (tid >> 2);
        biasS[tid] = p.bias0[g];
        biasS[16 + tid] = p.bias1[g];
    }
    __syncthreads();

    // persistent cell state: thread owns (bA = tid>>2, jA = blk*4 + (tid&3))
    const int bA = tid >> 2;
    const int jA = blk * 4 + (tid & 3);
    float c0reg = p.c0in[bA * HH + jA];
    float c1reg = p.c0in[BH + bA * HH + jA];
    unsigned ep = 0;
    const f32x4 fz = {0.f, 0.f, 0.f, 0.f};

    for (int t = 0; t < TT; ++t) {
        const size_t pB = (size_t)(t & 1) * BH;
        const size_t pN = (size_t)((t & 1) ^ 1) * BH;

        // ---- Phase A: layer-0 gates + cell ----
        {
            f32x4 aE = fz, aO = fz, aH = fz;
            {
                const int tok = p.tokens[t * BB + mrow];
                const float* erow = p.emb + (size_t)tok * EE + kc8;
#pragma unroll
                for (int seg = 0; seg < 16; ++seg) {
                    float4 x0 = *reinterpret_cast<const float4*>(erow + seg * 32);
                    float4 x1 = *reinterpret_cast<const float4*>(erow + seg * 32 + 4);
                    s16x8 afr;
                    afr[0] = f2b(x0.x); afr[1] = f2b(x0.y); afr[2] = f2b(x0.z); afr[3] = f2b(x0.w);
                    afr[4] = f2b(x1.x); afr[5] = f2b(x1.y); afr[6] = f2b(x1.z); afr[7] = f2b(x1.w);
                    aE = MFMA16(afr, ldsfrag(W0s, 1536, l & 15, seg * 4 + kq), aE);
                }
            }
            __syncthreads();
            stage_half(p.outx + pB, stg, tid, 0);
            __syncthreads();
#pragma unroll
            for (int seg = 0; seg < 8; ++seg)
                aO = MFMA16(ldsfrag(stg, 256, mrow, seg * 4 + kq),
                            ldsfrag(W0s, 1536, l & 15, 64 + seg * 4 + kq), aO);
            __syncthreads();
            stage_half(p.outx + pB, stg, tid, 1);
            __syncthreads();
#pragma unroll
            for (int seg = 0; seg < 8; ++seg)
                aO = MFMA16(ldsfrag(stg, 256, mrow, seg * 4 + kq),
                            ldsfrag(W0s, 1536, l & 15, 96 + seg * 4 + kq), aO);
            __syncthreads();
            stage_half(p.h0x + pB, stg, tid, 0);
            __syncthreads();
#pragma unroll
            for (int seg = 0; seg < 8; ++seg)
                aH = MFMA16(ldsfrag(stg, 256, mrow, seg * 4 + kq),
                            ldsfrag(W0s, 1536, l & 15, 128 + seg * 4 + kq), aH);
            __syncthreads();
            stage_half(p.h0x + pB, stg, tid, 1);
            __syncthreads();
#pragma unroll
            for (int seg = 0; seg < 8; ++seg)
                aH = MFMA16(ldsfrag(stg, 256, mrow, seg * 4 + kq),
                            ldsfrag(W0s, 1536, l & 15, 160 + seg * 4 + kq), aH);

            f32x4 acc = aE + aO + aH;
            __syncthreads();
            float* scr = (float*)stg + w * 272;
#pragma unroll
            for (int r = 0; r < 4; ++r) scr[(l & 15) * 17 + kq * 4 + r] = acc[r];
            __syncthreads();
            const int bloc = l >> 2;
            const int n0 = (l & 3) * 4;
            float gi = scr[(n0 + 0) * 17 + bloc] + biasS[n0 + 0];
            float gf = scr[(n0 + 1) * 17 + bloc] + biasS[n0 + 1];
            float gg = scr[(n0 + 2) * 17 + bloc] + biasS[n0 + 2];
            float go = scr[(n0 + 3) * 17 + bloc] + biasS[n0 + 3];
            float cn = sigm(gf) * c0reg + sigm(gi) * tanhf(gg);
            float hn = sigm(go) * tanhf(cn);
            c0reg = cn;
            ast2(&p.h0x[pN + bA * HH + jA], f2b(hn));
            if (t == TT - 1) {
                p.dout[OFF_HF + bA * HH + jA] = hn;
                p.dout[OFF_CF + bA * HH + jA] = cn;
            }
        }
        gbar(p.flags, ++ep);

        // ---- Phase B: layer-1 gates + cell ----
        {
            f32x4 b0 = fz, b1 = fz;
            stage_half(p.h0x + pN, stg, tid, 0);
            __syncthreads();
#pragma unroll
            for (int seg = 0; seg < 8; ++seg)
                b0 = MFMA16(ldsfrag(stg, 256, mrow, seg * 4 + kq),
                            ldsfrag(W1s, 1024, l & 15, seg * 4 + kq), b0);
            __syncthreads();
            stage_half(p.h0x + pN, stg, tid, 1);
            __syncthreads();
#pragma unroll
            for (int seg = 0; seg < 8; ++seg)
                b0 = MFMA16(ldsfrag(stg, 256, mrow, seg * 4 + kq),
                            ldsfrag(W1s, 1024, l & 15, 32 + seg * 4 + kq), b0);
            __syncthreads();
            stage_half(p.h1x + pB, stg, tid, 0);
            __syncthreads();
#pragma unroll
            for (int seg = 0; seg < 8; ++seg)
                b1 = MFMA16(ldsfrag(stg, 256, mrow, seg * 4 + kq),
                            ldsfrag(W1s, 1024, l & 15, 64 + seg * 4 + kq), b1);
            __syncthreads();
            stage_half(p.h1x + pB, stg, tid, 1);
            __syncthreads();
#pragma unroll
            for (int seg = 0; seg < 8; ++seg)
                b1 = MFMA16(ldsfrag(stg, 256, mrow, seg * 4 + kq),
                            ldsfrag(W1s, 1024, l & 15, 96 + seg * 4 + kq), b1);

            f32x4 acc = b0 + b1;
            __syncthreads();
            float* scr = (float*)stg + w * 272;
#pragma unroll
            for (int r = 0; r < 4; ++r) scr[(l & 15) * 17 + kq * 4 + r] = acc[r];
            __syncthreads();
            const int bloc = l >> 2;
            const int n0 = (l & 3) * 4;
            float gi = scr[(n0 + 0) * 17 + bloc] + biasS[16 + n0 + 0];
            float gf = scr[(n0 + 1) * 17 + bloc] + biasS[16 + n0 + 1];
            float gg = scr[(n0 + 2) * 17 + bloc] + biasS[16 + n0 + 2];
            float go = scr[(n0 + 3) * 17 + bloc] + biasS[16 + n0 + 3];
            float cn = sigm(gf) * c1reg + sigm(gi) * tanhf(gg);
            float hn = sigm(go) * tanhf(cn);
            c1reg = cn;
            ast2(&p.h1x[pN + bA * HH + jA], f2b(hn));
            if (t == TT - 1) {
                p.dout[OFF_HF + BH + bA * HH + jA] = hn;
                p.dout[OFF_CF + BH + bA * HH + jA] = cn;
            }
        }
        gbar(p.flags, ++ep);

        // ---- Phase C+D: attention + output GEMV for batch row b = blk ----
        {
            float* Sf = (float*)stg;
            float* scv = Sf;            // 512 partial scores
            float* h1f = Sf + 512;      // 512
            float* wcf = Sf + 1024;     // 512
            float* aU  = Sf + 1536;     // 256
            float* red = Sf + 1792;     // 16
            if (tid < 128) {
                union { u64 v; short s[4]; } c;
                c.v = aldq(p.h1x + pN + blk * HH + tid * 4);
#pragma unroll
                for (int j = 0; j < 4; ++j) h1f[tid * 4 + j] = b2f(c.s[j]);
            }
            __syncthreads();
            {
                const int s = tid >> 1, hf = tid & 1;
                const short* cw = p.ctxW + ((size_t)blk * SS + s) * HH + hf * 256;
                const float* hh = h1f + hf * 256;
                float a0 = 0.f, a1 = 0.f;
#pragma unroll 8
                for (int kk = 0; kk < 256; kk += 8) {
                    s16x8 v = *reinterpret_cast<const s16x8*>(cw + kk);
                    float4 hv0 = *reinterpret_cast<const float4*>(hh + kk);
                    float4 hv1 = *reinterpret_cast<const float4*>(hh + kk + 4);
                    a0 += b2f(v[0]) * hv0.x + b2f(v[1]) * hv0.y + b2f(v[2]) * hv0.z + b2f(v[3]) * hv0.w;
                    a1 += b2f(v[4]) * hv1.x + b2f(v[5]) * hv1.y + b2f(v[6]) * hv1.z + b2f(v[7]) * hv1.w;
                }
                scv[tid] = a0 + a1;
            }
            __syncthreads();
            float sc = -1e30f;
            if (tid < 256) sc = scv[2 * tid] + scv[2 * tid + 1];
            float mx = sc;
#pragma unroll
            for (int off = 32; off; off >>= 1) mx = fmaxf(mx, __shfl_xor(mx, off));
            if (l == 0 && tid < 256) red[w] = mx;
            __syncthreads();
            const float M = fmaxf(fmaxf(red[0], red[1]), fmaxf(red[2], red[3]));
            float e = 0.f;
            if (tid < 256) { e = __expf(sc - M); aU[tid] = e; }
            float se = e;
#pragma unroll
            for (int off = 32; off; off >>= 1) se += __shfl_xor(se, off);
            if (l == 0 && tid < 256) red[8 + w] = se;
            __syncthreads();
            const float inv = 1.f / (red[8] + red[9] + red[10] + red[11]);
            if (t == TT - 1 && tid < 256) p.dout[OFF_AT + blk * SS + tid] = aU[tid] * inv;
            {
                const short* cb = p.ctxb + (size_t)blk * SS * HH + tid;
                float acc2 = 0.f;
#pragma unroll 16
                for (int s2 = 0; s2 < 256; ++s2) acc2 += aU[s2] * b2f(cb[(size_t)s2 * HH]);
                wcf[tid] = acc2 * inv;
            }
            __syncthreads();
            {
                const unsigned* wp = p.WoutP + tid;
                float acc3 = 0.f;
#pragma unroll 16
                for (int m = 0; m < 256; ++m) {
                    unsigned wv = wp[(size_t)m * 512];
                    acc3 += b2f((short)(wv & 0xffff)) * wcf[2 * m] + b2f((short)(wv >> 16)) * wcf[2 * m + 1];
                }
#pragma unroll 16
                for (int m = 256; m < 512; ++m) {
                    unsigned wv = wp[(size_t)m * 512];
                    acc3 += b2f((short)(wv & 0xffff)) * h1f[2 * m - 512] + b2f((short)(wv >> 16)) * h1f[2 * m - 511];
                }
                float tv = tanhf(acc3);
                __builtin_nontemporal_store(tv, &p.dout[(size_t)t * BH + blk * HH + tid]);
                ast2(&p.outx[pN + blk * HH + tid], f2b(tv));
            }
        }
        gbar(p.flags, ++ep);
    }
}

// ---------------- host ----------------

extern "C" void kernel_launch(void* const* d_in, const int* in_sizes, int n_in,
                              void* d_out, int out_size, void* d_ws, size_t ws_size,
                              hipStream_t stream) {
    const int* tokens = (const int*)d_in[0];
    const float* h0in = (const float*)d_in[1];
    const float* c0in = (const float*)d_in[2];
    const float* ctx = (const float*)d_in[3];
    const float* iout = (const float*)d_in[4];
    const float* emb = (const float*)d_in[5];
    const float* Wih0 = (const float*)d_in[6];
    const float* bih0 = (const float*)d_in[7];
    const float* Whh0 = (const float*)d_in[8];
    const float* bhh0 = (const float*)d_in[9];
    const float* Wih1 = (const float*)d_in[10];
    const float* bih1 = (const float*)d_in[11];
    const float* Whh1 = (const float*)d_in[12];
    const float* bhh1 = (const float*)d_in[13];
    const float* Win = (const float*)d_in[14];
    const float* Wout = (const float*)d_in[15];
    float* dout = (float*)d_out;

    char* pw = (char*)d_ws;
    auto take = [&](size_t bytes) { char* r = pw; pw += (bytes + 255) & ~(size_t)255; return r; };
    short* W0cat = (short*)take((size_t)2048 * 1536 * 2);
    short* W1cat = (short*)take((size_t)2048 * 1024 * 2);
    short* Winb  = (short*)take((size_t)512 * 512 * 2);
    unsigned* WoutP = (unsigned*)take((size_t)512 * 512 * 4);
    float* bias0 = (float*)take(2048 * 4);
    float* bias1 = (float*)take(2048 * 4);
    short* ctxb  = (short*)take((size_t)BB * SS * HH * 2);
    short* ctxW  = (short*)take((size_t)BB * SS * HH * 2);
    short* h0x   = (short*)take((size_t)2 * BH * 2);
    short* h1x   = (short*)take((size_t)2 * BH * 2);
    short* outx  = (short*)take((size_t)2 * BH * 2);
    unsigned* flags = (unsigned*)take(NBLK * 4);

    k_pack2<<<2048, 256, 0, stream>>>(Wih0, 1024, Whh0, 512, W0cat, 2048 * 1536);
    k_pack2<<<2048, 256, 0, stream>>>(Wih1, 512, Whh1, 512, W1cat, 2048 * 1024);
    k_pack2<<<1024, 256, 0, stream>>>(Win, 512, Win, 0, Winb, 512 * 512);
    k_packwout<<<1024, 256, 0, stream>>>(Wout, WoutP);
    k_bias<<<8, 256, 0, stream>>>(bih0, bhh0, bias0, bih1, bhh1, bias1);
    k_ctx<<<4096, 256, 0, stream>>>(ctx, ctxb);
    k_state<<<256, 256, 0, stream>>>(h0in, iout, h0x, h1x, outx);
    k_ctxw<<<dim3(8, 256), 512, 0, stream>>>(ctxb, Winb, ctxW);
    (void)hipMemsetAsync(flags, 0, NBLK * 4, stream);

    const unsigned smem_bytes = (16 * 1536 + 16 * 1024 + 128 * 256) * 2 + 32 * 4;
    (void)hipFuncSetAttribute((const void*)coop_k, hipFuncAttributeMaxDynamicSharedMemorySize, (int)smem_bytes);

    P prm;
    prm.tokens = tokens; prm.emb = emb; prm.c0in = c0in;
    prm.ctxb = ctxb; prm.ctxW = ctxW;
    prm.W0cat = W0cat; prm.W1cat = W1cat; prm.WoutP = WoutP;
    prm.bias0 = bias0; prm.bias1 = bias1;
    prm.h0x = h0x; prm.h1x = h1x; prm.outx = outx;
    prm.dout = dout; prm.flags = flags;
    void* args[] = {&prm};
    (void)hipLaunchCooperativeKernel((void*)coop_k, dim3(NBLK), dim3(NTHR), args, smem_bytes, stream);
}

// Round 6
// 16938.953 us; speedup vs baseline: 2.2705x; 1.2650x over previous
//
#include <hip/hip_runtime.h>
#include <hip/hip_bf16.h>
#include <math.h>

#define TT 256
#define BB 128
#define SS 256
#define HH 512
#define EE 512
#define NBLK 128
#define NTHR 512
#define BH (BB * HH)

typedef __attribute__((ext_vector_type(4))) float f32x4;
typedef __attribute__((ext_vector_type(8))) short s16x8;
typedef unsigned long long u64;

__device__ __forceinline__ float b2f(short v) {
    union { unsigned u; float f; } c;
    c.u = ((unsigned)(unsigned short)v) << 16;
    return c.f;
}
__device__ __forceinline__ short f2b(float f) {
    union { float f; unsigned u; } c; c.f = f;
    unsigned u = c.u;
    unsigned r = (u + 0x7fffu + ((u >> 16) & 1u)) >> 16;
    return (short)r;
}
__device__ __forceinline__ float sigm(float x) { return 1.f / (1.f + __expf(-x)); }

// L2-bypassing (agent-scope) exchange primitives
__device__ __forceinline__ u64 aldq(const void* p) {
    return __hip_atomic_load((const u64*)p, __ATOMIC_RELAXED, __HIP_MEMORY_SCOPE_AGENT);
}
__device__ __forceinline__ void ast2(short* p, short v) {
    __hip_atomic_store(p, v, __ATOMIC_RELAXED, __HIP_MEMORY_SCOPE_AGENT);
}

// ---------------- prep kernels ----------------

__global__ void k_pack2(const float* __restrict__ Wa, int ka, const float* __restrict__ Wb, int kb,
                        short* __restrict__ dst, int n) {
    const int K = ka + kb;
    for (int i = blockIdx.x * blockDim.x + threadIdx.x; i < n; i += gridDim.x * blockDim.x) {
        int g = i / K, k = i - g * K;
        float v = (k < ka) ? Wa[(size_t)g * ka + k] : Wb[(size_t)g * kb + (k - ka)];
        dst[i] = f2b(v);
    }
}

__global__ void k_bias(const float* __restrict__ a, const float* __restrict__ b, float* __restrict__ o,
                       const float* __restrict__ a2, const float* __restrict__ b2, float* __restrict__ o2) {
    int i = blockIdx.x * blockDim.x + threadIdx.x;
    if (i < 2048) { o[i] = a[i] + b[i]; o2[i] = a2[i] + b2[i]; }
}

__global__ void k_ctx(const float* __restrict__ ctx, short* __restrict__ Ctxb) {
    const int n = BB * SS * HH;
    for (int i = blockIdx.x * blockDim.x + threadIdx.x; i < n; i += gridDim.x * blockDim.x) {
        int b = i / (SS * HH);
        int r = i - b * SS * HH;
        int s = r >> 9, h = r & 511;
        Ctxb[i] = f2b(ctx[((size_t)s * BB + b) * HH + h]);
    }
}

__global__ void k_state(const float* __restrict__ h0in, const float* __restrict__ iout,
                        short* __restrict__ h0x, short* __restrict__ h1x, short* __restrict__ outx) {
    int i = blockIdx.x * blockDim.x + threadIdx.x;
    if (i < BH) {
        h0x[i] = f2b(h0in[i]);
        h1x[i] = f2b(h0in[BH + i]);
        outx[i] = f2b(iout[i]);
    }
}

// ctxW[(b*S+s), n] = sum_k ctxb[(b*S+s), k] * Win[n, k]
__global__ __launch_bounds__(512) void k_ctxw(const short* __restrict__ ctxb, const short* __restrict__ Winb,
                                              short* __restrict__ ctxW) {
    const int tid = threadIdx.x, w = tid >> 6, l = tid & 63;
    const int m0 = blockIdx.y * 128, n0 = blockIdx.x * 64;
    const int kc8 = (l >> 4) * 8;
    const short* arow = ctxb + (size_t)(m0 + w * 16 + (l & 15)) * HH + kc8;
    f32x4 acc[4];
    const f32x4 zero = {0.f, 0.f, 0.f, 0.f};
#pragma unroll
    for (int j = 0; j < 4; ++j) acc[j] = zero;
#pragma unroll
    for (int kc = 0; kc < 16; ++kc) {
        const int k0 = kc * 32;
        s16x8 afr = *reinterpret_cast<const s16x8*>(arow + k0);
#pragma unroll
        for (int j = 0; j < 4; ++j) {
            s16x8 bfr = *reinterpret_cast<const s16x8*>(Winb + (size_t)(n0 + j * 16 + (l & 15)) * HH + k0 + kc8);
            acc[j] = __builtin_amdgcn_mfma_f32_16x16x32_bf16(afr, bfr, acc[j], 0, 0, 0);
        }
    }
#pragma unroll
    for (int j = 0; j < 4; ++j)
#pragma unroll
        for (int r = 0; r < 4; ++r)
            ctxW[(size_t)(m0 + w * 16 + (l >> 4) * 4 + r) * HH + n0 + j * 16 + (l & 15)] = f2b(acc[j][r]);
}

// ---------------- persistent cooperative kernel ----------------

struct P {
    const int* tokens;
    const float* emb;
    const float* c0in;
    const short* ctxb;
    const short* ctxW;
    const short* W0cat;
    const short* W1cat;
    const short* Woutb;
    const float* bias0;
    const float* bias1;
    short* h0x;
    short* h1x;
    short* outx;
    short* wcx;
    float* dout;
    unsigned* flags;
};

#define MFMA16(a, b, c) __builtin_amdgcn_mfma_f32_16x16x32_bf16((a), (b), (c), 0, 0, 0)

__device__ __forceinline__ s16x8 ldsfrag(const short* base, int stride, int row, int col8) {
    return *reinterpret_cast<const s16x8*>(base + row * stride + ((col8 ^ (row & 7)) << 3));
}

// issue 16B x 8 chunk loads (64KB block-wide half-tile) into regs
__device__ __forceinline__ void issue16(const short* __restrict__ src, int tid, int khalf, u64* q) {
#pragma unroll
    for (int c = 0; c < 8; ++c) {
        const int chunk = c * 512 + tid;
        const int row = chunk >> 5, col8 = chunk & 31;
        const short* s = src + row * HH + khalf * 256 + col8 * 8;
        q[2 * c] = aldq(s);
        q[2 * c + 1] = aldq(s + 4);
    }
}
__device__ __forceinline__ void write16(short* __restrict__ stg, int tid, const u64* q) {
#pragma unroll
    for (int c = 0; c < 8; ++c) {
        const int chunk = c * 512 + tid;
        const int row = chunk >> 5, col8 = chunk & 31;
        short* d = stg + row * 256 + ((col8 ^ (row & 7)) << 3);
        union { u64 qq[2]; s16x8 v; } u;
        u.qq[0] = q[2 * c];
        u.qq[1] = q[2 * c + 1];
        *reinterpret_cast<s16x8*>(d) = u.v;
    }
}

__device__ __forceinline__ f32x4 seg8(const short* stgp, const short* Ws, int wstride, int wbase,
                                      int mrow, int wrow, int kq, f32x4 acc) {
#pragma unroll
    for (int seg = 0; seg < 8; ++seg)
        acc = MFMA16(ldsfrag(stgp, 256, mrow, seg * 4 + kq),
                     ldsfrag(Ws, wstride, wrow, wbase + seg * 4 + kq), acc);
    return acc;
}

__device__ __forceinline__ f32x4 seg8m(const short* stgp, const short* Wd, int wbase,
                                       int mrow, int nn, int kq, bool valid, f32x4 acc) {
    const s16x8 zz = {0, 0, 0, 0, 0, 0, 0, 0};
#pragma unroll
    for (int seg = 0; seg < 8; ++seg) {
        s16x8 b = ldsfrag(Wd, 1024, nn & 3, wbase + seg * 4 + kq);
        if (!valid) b = zz;
        acc = MFMA16(ldsfrag(stgp, 256, mrow, seg * 4 + kq), b, acc);
    }
    return acc;
}

// flag-array grid barrier
__device__ __forceinline__ void gbar(unsigned* flags, unsigned target) {
    asm volatile("s_waitcnt vmcnt(0)" ::: "memory");
    __syncthreads();
    if (threadIdx.x == 0)
        __hip_atomic_store(&flags[blockIdx.x], target, __ATOMIC_RELAXED, __HIP_MEMORY_SCOPE_AGENT);
    if (threadIdx.x < NBLK) {
        while (__hip_atomic_load(&flags[threadIdx.x], __ATOMIC_RELAXED, __HIP_MEMORY_SCOPE_AGENT) < target)
            __builtin_amdgcn_s_sleep(1);
    }
    __syncthreads();
}

__global__ void __launch_bounds__(NTHR, 1) coop_k(P p) {
    extern __shared__ __align__(16) char smem[];
    short* W0s = (short*)smem;            // 16 x 1536 sw
    short* W1s = W0s + 16 * 1536;         // 16 x 1024 sw
    short* Wds = W1s + 16 * 1024;         // 4 x 1024 sw
    short* stg = Wds + 4 * 1024;          // 128 x 256 sw (stage / float scratch)
    float* smallf = (float*)(stg + 128 * 256);
    float* bias0s = smallf;               // 16
    float* bias1s = smallf + 16;          // 16
    float* red = smallf + 32;             // 16
    float* scv = smallf + 48;             // 256
    float* aU = smallf + 304;             // 256

    const int tid = threadIdx.x;
    const int blk = blockIdx.x;
    const int l = tid & 63;
    const int w = tid >> 6;
    const int lrow = l & 15;
    const int mrow = w * 16 + lrow;
    const int kq = l >> 4;
    const size_t OFF_HF = (size_t)TT * BH;
    const size_t OFF_CF = OFF_HF + 2 * (size_t)BH;
    const size_t OFF_AT = OFF_CF + 2 * (size_t)BH;
    const f32x4 fz = {0.f, 0.f, 0.f, 0.f};

    // --- prologue: LDS-resident weights (swizzled) ---
    for (int idx = tid; idx < 16 * 192; idx += NTHR) {
        int row = idx / 192, col8 = idx % 192;
        int g = (row & 3) * 512 + blk * 4 + (row >> 2);
        *reinterpret_cast<s16x8*>(W0s + row * 1536 + ((col8 ^ (row & 7)) << 3)) =
            *reinterpret_cast<const s16x8*>(p.W0cat + (size_t)g * 1536 + col8 * 8);
    }
    for (int idx = tid; idx < 16 * 128; idx += NTHR) {
        int row = idx / 128, col8 = idx % 128;
        int g = (row & 3) * 512 + blk * 4 + (row >> 2);
        *reinterpret_cast<s16x8*>(W1s + row * 1024 + ((col8 ^ (row & 7)) << 3)) =
            *reinterpret_cast<const s16x8*>(p.W1cat + (size_t)g * 1024 + col8 * 8);
    }
    {
        int row = tid >> 7, col8 = tid & 127;  // 512 threads = 4 rows x 128
        *reinterpret_cast<s16x8*>(Wds + row * 1024 + ((col8 ^ row) << 3)) =
            *reinterpret_cast<const s16x8*>(p.Woutb + (size_t)(blk * 4 + row) * 1024 + col8 * 8);
    }
    if (tid < 16) {
        int g = (tid & 3) * 512 + blk * 4 + (tid >> 2);
        bias0s[tid] = p.bias0[g];
        bias1s[tid] = p.bias1[g];
    }
    __syncthreads();

    const int bA = tid >> 2;
    const int jA = blk * 4 + (tid & 3);
    float c0reg = p.c0in[bA * HH + jA];
    float c1reg = p.c0in[BH + bA * HH + jA];
    unsigned ep = 0;
    u64 qa[16], qb[16];

    for (int t = 0; t < TT; ++t) {
        const size_t pB = (size_t)(t & 1) * BH;
        const size_t pN = (size_t)((t & 1) ^ 1) * BH;

        // ================= Phase A: layer-0 gates + cell =================
        {
            issue16(p.outx + pB, tid, 0, qa);
            f32x4 aE = fz, aO = fz, aH = fz;
            {
                const int tok = p.tokens[t * BB + mrow];
                const float* erow = p.emb + (size_t)tok * EE + kq * 8;
#pragma unroll
                for (int seg = 0; seg < 16; ++seg) {
                    float4 x0 = *reinterpret_cast<const float4*>(erow + seg * 32);
                    float4 x1 = *reinterpret_cast<const float4*>(erow + seg * 32 + 4);
                    s16x8 afr;
                    afr[0] = f2b(x0.x); afr[1] = f2b(x0.y); afr[2] = f2b(x0.z); afr[3] = f2b(x0.w);
                    afr[4] = f2b(x1.x); afr[5] = f2b(x1.y); afr[6] = f2b(x1.z); afr[7] = f2b(x1.w);
                    aE = MFMA16(afr, ldsfrag(W0s, 1536, lrow, seg * 4 + kq), aE);
                }
            }
            write16(stg, tid, qa);
            issue16(p.outx + pB, tid, 1, qb);
            __syncthreads();
            aO = seg8(stg, W0s, 1536, 64, mrow, lrow, kq, aO);
            __syncthreads();
            write16(stg, tid, qb);
            issue16(p.h0x + pB, tid, 0, qa);
            __syncthreads();
            aO = seg8(stg, W0s, 1536, 96, mrow, lrow, kq, aO);
            __syncthreads();
            write16(stg, tid, qa);
            issue16(p.h0x + pB, tid, 1, qb);
            __syncthreads();
            aH = seg8(stg, W0s, 1536, 128, mrow, lrow, kq, aH);
            __syncthreads();
            write16(stg, tid, qb);
            __syncthreads();
            aH = seg8(stg, W0s, 1536, 160, mrow, lrow, kq, aH);

            f32x4 acc = aE + aO + aH;
            __syncthreads();
            float* scr = (float*)stg + w * 272;
#pragma unroll
            for (int r = 0; r < 4; ++r) scr[lrow * 17 + kq * 4 + r] = acc[r];
            __syncthreads();
            const int bloc = l >> 2;
            const int n0 = (l & 3) * 4;
            float gi = scr[(n0 + 0) * 17 + bloc] + bias0s[n0 + 0];
            float gf = scr[(n0 + 1) * 17 + bloc] + bias0s[n0 + 1];
            float gg = scr[(n0 + 2) * 17 + bloc] + bias0s[n0 + 2];
            float go = scr[(n0 + 3) * 17 + bloc] + bias0s[n0 + 3];
            float cn = sigm(gf) * c0reg + sigm(gi) * tanhf(gg);
            float hn = sigm(go) * tanhf(cn);
            c0reg = cn;
            ast2(&p.h0x[pN + bA * HH + jA], f2b(hn));
            if (t == TT - 1) {
                p.dout[OFF_HF + bA * HH + jA] = hn;
                p.dout[OFF_CF + bA * HH + jA] = cn;
            }
        }
        gbar(p.flags, ++ep);

        // ================= Phase B: layer-1 gates + cell =================
        {
            issue16(p.h0x + pN, tid, 0, qa);
            f32x4 b0 = fz, b1 = fz;
            write16(stg, tid, qa);
            issue16(p.h0x + pN, tid, 1, qb);
            __syncthreads();
            b0 = seg8(stg, W1s, 1024, 0, mrow, lrow, kq, b0);
            __syncthreads();
            write16(stg, tid, qb);
            issue16(p.h1x + pB, tid, 0, qa);
            __syncthreads();
            b0 = seg8(stg, W1s, 1024, 32, mrow, lrow, kq, b0);
            __syncthreads();
            write16(stg, tid, qa);
            issue16(p.h1x + pB, tid, 1, qb);
            __syncthreads();
            b1 = seg8(stg, W1s, 1024, 64, mrow, lrow, kq, b1);
            __syncthreads();
            write16(stg, tid, qb);
            __syncthreads();
            b1 = seg8(stg, W1s, 1024, 96, mrow, lrow, kq, b1);

            f32x4 acc = b0 + b1;
            __syncthreads();
            float* scr = (float*)stg + w * 272;
#pragma unroll
            for (int r = 0; r < 4; ++r) scr[lrow * 17 + kq * 4 + r] = acc[r];
            __syncthreads();
            const int bloc = l >> 2;
            const int n0 = (l & 3) * 4;
            float gi = scr[(n0 + 0) * 17 + bloc] + bias1s[n0 + 0];
            float gf = scr[(n0 + 1) * 17 + bloc] + bias1s[n0 + 1];
            float gg = scr[(n0 + 2) * 17 + bloc] + bias1s[n0 + 2];
            float go = scr[(n0 + 3) * 17 + bloc] + bias1s[n0 + 3];
            float cn = sigm(gf) * c1reg + sigm(gi) * tanhf(gg);
            float hn = sigm(go) * tanhf(cn);
            c1reg = cn;
            ast2(&p.h1x[pN + bA * HH + jA], f2b(hn));
            if (t == TT - 1) {
                p.dout[OFF_HF + BH + bA * HH + jA] = hn;
                p.dout[OFF_CF + BH + bA * HH + jA] = cn;
            }
        }
        gbar(p.flags, ++ep);

        // ================= Phase C: attention for batch b = blk =================
        {
            float* pF = (float*)stg;        // 8 x 512 partials
            float* h1f = pF + 4096;         // 512
            if (tid < 128) {
                union { u64 v; short s[4]; } c;
                c.v = aldq(p.h1x + pN + blk * HH + tid * 4);
#pragma unroll
                for (int j = 0; j < 4; ++j) h1f[tid * 4 + j] = b2f(c.s[j]);
            }
            __syncthreads();
            float hreg[8];
#pragma unroll
            for (int j = 0; j < 8; ++j) hreg[j] = h1f[l * 8 + j];
            // score pass: wave w handles s = it*8 + w; lanes own h-chunks (1KB/wave-instr)
            const short* cwb = p.ctxW + (size_t)blk * SS * HH;
#pragma unroll 4
            for (int it = 0; it < 32; ++it) {
                const int s = it * 8 + w;
                s16x8 v = *reinterpret_cast<const s16x8*>(cwb + (size_t)s * HH + l * 8);
                float pd = 0.f;
#pragma unroll
                for (int j = 0; j < 8; ++j) pd += b2f(v[j]) * hreg[j];
#pragma unroll
                for (int off = 32; off; off >>= 1) pd += __shfl_xor(pd, off);
                if (l == 0) scv[s] = pd;
            }
            __syncthreads();
            // softmax over 256 (threads 0..255)
            float sc = -1e30f, e = 0.f;
            if (tid < 256) sc = scv[tid];
            float mx = sc;
#pragma unroll
            for (int off = 32; off; off >>= 1) mx = fmaxf(mx, __shfl_xor(mx, off));
            if (l == 0 && tid < 256) red[w] = mx;
            __syncthreads();
            const float M = fmaxf(fmaxf(red[0], red[1]), fmaxf(red[2], red[3]));
            if (tid < 256) { e = __expf(sc - M); aU[tid] = e; }
            float se = e;
#pragma unroll
            for (int off = 32; off; off >>= 1) se += __shfl_xor(se, off);
            if (l == 0 && tid < 256) red[8 + w] = se;
            __syncthreads();
            const float inv = 1.f / (red[8] + red[9] + red[10] + red[11]);
            if (t == TT - 1 && tid < 256) p.dout[OFF_AT + blk * SS + tid] = aU[tid] * inv;
            // PV pass: same wave-split, contiguous 16B loads
            const short* cbb = p.ctxb + (size_t)blk * SS * HH;
            float wa[8];
#pragma unroll
            for (int j = 0; j < 8; ++j) wa[j] = 0.f;
#pragma unroll 4
            for (int it = 0; it < 32; ++it) {
                const int s = it * 8 + w;
                const float av = aU[s];
                s16x8 v = *reinterpret_cast<const s16x8*>(cbb + (size_t)s * HH + l * 8);
#pragma unroll
                for (int j = 0; j < 8; ++j) wa[j] += av * b2f(v[j]);
            }
            {
                float4* dst = reinterpret_cast<float4*>(pF + w * 512 + l * 8);
                float4 v0 = {wa[0], wa[1], wa[2], wa[3]};
                float4 v1 = {wa[4], wa[5], wa[6], wa[7]};
                dst[0] = v0;
                dst[1] = v1;
            }
            __syncthreads();
            float s8 = 0.f;
#pragma unroll
            for (int ww = 0; ww < 8; ++ww) s8 += pF[ww * 512 + tid];
            ast2(&p.wcx[blk * HH + tid], f2b(s8 * inv));
        }
        gbar(p.flags, ++ep);

        // ================= Phase D: out = tanh([wc|h1] @ Wout^T), MFMA =================
        {
            issue16(p.wcx, tid, 0, qa);
            f32x4 acc = fz;
            const int nn = l & 15;
            const bool dv = nn < 4;
            write16(stg, tid, qa);
            issue16(p.wcx, tid, 1, qb);
            __syncthreads();
            acc = seg8m(stg, Wds, 0, mrow, nn, kq, dv, acc);
            __syncthreads();
            write16(stg, tid, qb);
            issue16(p.h1x + pN, tid, 0, qa);
            __syncthreads();
            acc = seg8m(stg, Wds, 32, mrow, nn, kq, dv, acc);
            __syncthreads();
            write16(stg, tid, qa);
            issue16(p.h1x + pN, tid, 1, qb);
            __syncthreads();
            acc = seg8m(stg, Wds, 64, mrow, nn, kq, dv, acc);
            __syncthreads();
            write16(stg, tid, qb);
            __syncthreads();
            acc = seg8m(stg, Wds, 96, mrow, nn, kq, dv, acc);
            if (dv) {
                const int col = blk * 4 + nn;
#pragma unroll
                for (int r = 0; r < 4; ++r) {
                    const int row = w * 16 + (l >> 4) * 4 + r;
                    float tv = tanhf(acc[r]);
                    __builtin_nontemporal_store(tv, &p.dout[(size_t)t * BH + row * HH + col]);
                    ast2(&p.outx[pN + row * HH + col], f2b(tv));
                }
            }
        }
        gbar(p.flags, ++ep);
    }
}

// ---------------- host ----------------

extern "C" void kernel_launch(void* const* d_in, const int* in_sizes, int n_in,
                              void* d_out, int out_size, void* d_ws, size_t ws_size,
                              hipStream_t stream) {
    const int* tokens = (const int*)d_in[0];
    const float* h0in = (const float*)d_in[1];
    const float* c0in = (const float*)d_in[2];
    const float* ctx = (const float*)d_in[3];
    const float* iout = (const float*)d_in[4];
    const float* emb = (const float*)d_in[5];
    const float* Wih0 = (const float*)d_in[6];
    const float* bih0 = (const float*)d_in[7];
    const float* Whh0 = (const float*)d_in[8];
    const float* bhh0 = (const float*)d_in[9];
    const float* Wih1 = (const float*)d_in[10];
    const float* bih1 = (const float*)d_in[11];
    const float* Whh1 = (const float*)d_in[12];
    const float* bhh1 = (const float*)d_in[13];
    const float* Win = (const float*)d_in[14];
    const float* Wout = (const float*)d_in[15];
    float* dout = (float*)d_out;

    char* pw = (char*)d_ws;
    auto take = [&](size_t bytes) { char* r = pw; pw += (bytes + 255) & ~(size_t)255; return r; };
    short* W0cat = (short*)take((size_t)2048 * 1536 * 2);
    short* W1cat = (short*)take((size_t)2048 * 1024 * 2);
    short* Winb  = (short*)take((size_t)512 * 512 * 2);
    short* Woutb = (short*)take((size_t)512 * 1024 * 2);
    float* bias0 = (float*)take(2048 * 4);
    float* bias1 = (float*)take(2048 * 4);
    short* ctxb  = (short*)take((size_t)BB * SS * HH * 2);
    short* ctxW  = (short*)take((size_t)BB * SS * HH * 2);
    short* h0x   = (short*)take((size_t)2 * BH * 2);
    short* h1x   = (short*)take((size_t)2 * BH * 2);
    short* outx  = (short*)take((size_t)2 * BH * 2);
    short* wcx   = (short*)take((size_t)BH * 2);
    unsigned* flags = (unsigned*)take(NBLK * 4);

    k_pack2<<<2048, 256, 0, stream>>>(Wih0, 1024, Whh0, 512, W0cat, 2048 * 1536);
    k_pack2<<<2048, 256, 0, stream>>>(Wih1, 512, Whh1, 512, W1cat, 2048 * 1024);
    k_pack2<<<1024, 256, 0, stream>>>(Win, 512, Win, 0, Winb, 512 * 512);
    k_pack2<<<1024, 256, 0, stream>>>(Wout, 1024, Wout, 0, Woutb, 512 * 1024);
    k_bias<<<8, 256, 0, stream>>>(bih0, bhh0, bias0, bih1, bhh1, bias1);
    k_ctx<<<4096, 256, 0, stream>>>(ctx, ctxb);
    k_state<<<256, 256, 0, stream>>>(h0in, iout, h0x, h1x, outx);
    k_ctxw<<<dim3(8, 256), 512, 0, stream>>>(ctxb, Winb, ctxW);
    (void)hipMemsetAsync(flags, 0, NBLK * 4, stream);

    const unsigned smem_bytes = (16 * 1536 + 16 * 1024 + 4 * 1024 + 128 * 256) * 2 + (16 + 16 + 16 + 256 + 256) * 4;
    (void)hipFuncSetAttribute((const void*)coop_k, hipFuncAttributeMaxDynamicSharedMemorySize, (int)smem_bytes);

    P prm;
    prm.tokens = tokens; prm.emb = emb; prm.c0in = c0in;
    prm.ctxb = ctxb; prm.ctxW = ctxW;
    prm.W0cat = W0cat; prm.W1cat = W1cat; prm.Woutb = Woutb;
    prm.bias0 = bias0; prm.bias1 = bias1;
    prm.h0x = h0x; prm.h1x = h1x; prm.outx = outx; prm.wcx = wcx;
    prm.dout = dout; prm.flags = flags;
    void* args[] = {&prm};
    (void)hipLaunchCooperativeKernel((void*)coop_k, dim3(NBLK), dim3(NTHR), args, smem_bytes, stream);
}

// Round 7
// 16592.041 us; speedup vs baseline: 2.3180x; 1.0209x over previous
//
#include <hip/hip_runtime.h>
#include <hip/hip_bf16.h>
#include <math.h>

#define TT 256
#define BB 128
#define SS 256
#define HH 512
#define EE 512
#define NBLK 128
#define NTHR 512
#define BH (BB * HH)

typedef __attribute__((ext_vector_type(4))) float f32x4;
typedef __attribute__((ext_vector_type(2))) float f32x2;
typedef __attribute__((ext_vector_type(8))) short s16x8;
typedef unsigned long long u64;

__device__ __forceinline__ float b2f(short v) {
    union { unsigned u; float f; } c;
    c.u = ((unsigned)(unsigned short)v) << 16;
    return c.f;
}
__device__ __forceinline__ short f2b(float f) {
    union { float f; unsigned u; } c; c.f = f;
    unsigned u = c.u;
    unsigned r = (u + 0x7fffu + ((u >> 16) & 1u)) >> 16;
    return (short)r;
}
__device__ __forceinline__ float sigm(float x) { return 1.f / (1.f + __expf(-x)); }

// fp8 e4m3 helpers (HW cvt, symmetric encode/decode)
__device__ __forceinline__ unsigned short f2fp8x2(float x, float y) {
    return (unsigned short)(__builtin_amdgcn_cvt_pk_fp8_f32(x, y, 0, false) & 0xffff);
}
__device__ __forceinline__ void f8x8(u64 q, float* o) {
    unsigned w0 = (unsigned)q, w1 = (unsigned)(q >> 32);
    f32x2 a = __builtin_amdgcn_cvt_pk_f32_fp8(w0, false);
    f32x2 b = __builtin_amdgcn_cvt_pk_f32_fp8(w0, true);
    f32x2 c = __builtin_amdgcn_cvt_pk_f32_fp8(w1, false);
    f32x2 d = __builtin_amdgcn_cvt_pk_f32_fp8(w1, true);
    o[0] = a[0]; o[1] = a[1]; o[2] = b[0]; o[3] = b[1];
    o[4] = c[0]; o[5] = c[1]; o[6] = d[0]; o[7] = d[1];
}

// L2-bypassing (agent-scope) exchange primitives
__device__ __forceinline__ u64 aldq(const void* p) {
    return __hip_atomic_load((const u64*)p, __ATOMIC_RELAXED, __HIP_MEMORY_SCOPE_AGENT);
}
__device__ __forceinline__ void ast2(short* p, short v) {
    __hip_atomic_store(p, v, __ATOMIC_RELAXED, __HIP_MEMORY_SCOPE_AGENT);
}

// ---------------- prep kernels ----------------

__global__ void k_pack2(const float* __restrict__ Wa, int ka, const float* __restrict__ Wb, int kb,
                        short* __restrict__ dst, int n) {
    const int K = ka + kb;
    for (int i = blockIdx.x * blockDim.x + threadIdx.x; i < n; i += gridDim.x * blockDim.x) {
        int g = i / K, k = i - g * K;
        float v = (k < ka) ? Wa[(size_t)g * ka + k] : Wb[(size_t)g * kb + (k - ka)];
        dst[i] = f2b(v);
    }
}

__global__ void k_bias(const float* __restrict__ a, const float* __restrict__ b, float* __restrict__ o,
                       const float* __restrict__ a2, const float* __restrict__ b2, float* __restrict__ o2) {
    int i = blockIdx.x * blockDim.x + threadIdx.x;
    if (i < 2048) { o[i] = a[i] + b[i]; o2[i] = a2[i] + b2[i]; }
}

// pre-gathered bf16 embedding sequence [T,B,E]
__global__ void k_emb(const int* __restrict__ tok, const float* __restrict__ emb, short* __restrict__ Ebf) {
    const int n = TT * BB * EE;
    for (int i = blockIdx.x * blockDim.x + threadIdx.x; i < n; i += gridDim.x * blockDim.x) {
        int tb = i >> 9, k = i & 511;
        int t = tok[tb];
        Ebf[i] = f2b(emb[(size_t)t * EE + k]);
    }
}

// ctx [S,B,H] f32 -> fp8 [B,S,H]
__global__ void k_ctx8(const float* __restrict__ ctx, unsigned char* __restrict__ c8) {
    const int n2 = BB * SS * (HH / 2);
    for (int i = blockIdx.x * blockDim.x + threadIdx.x; i < n2; i += gridDim.x * blockDim.x) {
        int h2 = i & 255, rest = i >> 8;
        int s = rest & 255, b = rest >> 8;
        int h = h2 * 2;
        const float* src = ctx + ((size_t)s * BB + b) * HH + h;
        *reinterpret_cast<unsigned short*>(c8 + ((size_t)b * SS + s) * HH + h) = f2fp8x2(src[0], src[1]);
    }
}

// ctxW8[(b*S+s), n] = fp8( sum_k ctx[s,b,k] * Win[n,k] )
__global__ __launch_bounds__(512) void k_ctxw8(const float* __restrict__ ctx, const short* __restrict__ Winb,
                                               unsigned char* __restrict__ ctxW8) {
    const int tid = threadIdx.x, w = tid >> 6, l = tid & 63;
    const int m0 = blockIdx.y * 128, n0 = blockIdx.x * 64;
    const int kc8 = (l >> 4) * 8;
    const int m = m0 + w * 16 + (l & 15);
    const int b = m >> 8, s = m & 255;
    const float* arow = ctx + ((size_t)s * BB + b) * HH + kc8;
    f32x4 acc[4];
    const f32x4 zero = {0.f, 0.f, 0.f, 0.f};
#pragma unroll
    for (int j = 0; j < 4; ++j) acc[j] = zero;
#pragma unroll
    for (int kc = 0; kc < 16; ++kc) {
        const int k0 = kc * 32;
        float4 x0 = *reinterpret_cast<const float4*>(arow + k0);
        float4 x1 = *reinterpret_cast<const float4*>(arow + k0 + 4);
        s16x8 afr;
        afr[0] = f2b(x0.x); afr[1] = f2b(x0.y); afr[2] = f2b(x0.z); afr[3] = f2b(x0.w);
        afr[4] = f2b(x1.x); afr[5] = f2b(x1.y); afr[6] = f2b(x1.z); afr[7] = f2b(x1.w);
#pragma unroll
        for (int j = 0; j < 4; ++j) {
            s16x8 bfr = *reinterpret_cast<const s16x8*>(Winb + (size_t)(n0 + j * 16 + (l & 15)) * HH + k0 + kc8);
            acc[j] = __builtin_amdgcn_mfma_f32_16x16x32_bf16(afr, bfr, acc[j], 0, 0, 0);
        }
    }
#pragma unroll
    for (int j = 0; j < 4; ++j)
#pragma unroll
        for (int r = 0; r < 4; ++r)
            ctxW8[(size_t)(m0 + w * 16 + (l >> 4) * 4 + r) * HH + (n0 + j * 16 + (l & 15))] =
                (unsigned char)(__builtin_amdgcn_cvt_pk_fp8_f32(acc[j][r], 0.f, 0, false) & 0xff);
}

__global__ void k_state(const float* __restrict__ h0in, const float* __restrict__ iout,
                        short* __restrict__ h0x, short* __restrict__ h1x, short* __restrict__ outx) {
    int i = blockIdx.x * blockDim.x + threadIdx.x;
    if (i < BH) {
        h0x[i] = f2b(h0in[i]);
        h1x[i] = f2b(h0in[BH + i]);
        outx[i] = f2b(iout[i]);
    }
}

// ---------------- persistent cooperative kernel ----------------

struct P {
    const short* Ebf;
    const float* c0in;
    const unsigned char* ctxb8;
    const unsigned char* ctxW8;
    const short* W0cat;
    const short* W1cat;
    const short* Woutb;
    const float* bias0;
    const float* bias1;
    short* h0x;
    short* h1x;
    short* outx;
    short* wcx;
    float* dout;
    unsigned* flags;
};

#define MFMA16(a, b, c) __builtin_amdgcn_mfma_f32_16x16x32_bf16((a), (b), (c), 0, 0, 0)

__device__ __forceinline__ s16x8 ldsfrag(const short* base, int stride, int row, int col8) {
    return *reinterpret_cast<const s16x8*>(base + row * stride + ((col8 ^ (row & 7)) << 3));
}

__device__ __forceinline__ void issue16(const short* __restrict__ src, int tid, int khalf, u64* q) {
#pragma unroll
    for (int c = 0; c < 8; ++c) {
        const int chunk = c * 512 + tid;
        const int row = chunk >> 5, col8 = chunk & 31;
        const short* s = src + row * HH + khalf * 256 + col8 * 8;
        q[2 * c] = aldq(s);
        q[2 * c + 1] = aldq(s + 4);
    }
}
__device__ __forceinline__ void write16(short* __restrict__ stg, int tid, const u64* q) {
#pragma unroll
    for (int c = 0; c < 8; ++c) {
        const int chunk = c * 512 + tid;
        const int row = chunk >> 5, col8 = chunk & 31;
        short* d = stg + row * 256 + ((col8 ^ (row & 7)) << 3);
        union { u64 qq[2]; s16x8 v; } u;
        u.qq[0] = q[2 * c];
        u.qq[1] = q[2 * c + 1];
        *reinterpret_cast<s16x8*>(d) = u.v;
    }
}

__device__ __forceinline__ f32x4 seg8(const short* stgp, const short* Ws, int wstride, int wbase,
                                      int mrow, int wrow, int kq, f32x4 acc) {
#pragma unroll
    for (int seg = 0; seg < 8; ++seg)
        acc = MFMA16(ldsfrag(stgp, 256, mrow, seg * 4 + kq),
                     ldsfrag(Ws, wstride, wrow, wbase + seg * 4 + kq), acc);
    return acc;
}

__device__ __forceinline__ f32x4 seg8m(const short* stgp, const short* Wd, int wbase,
                                       int mrow, int nn, int kq, bool valid, f32x4 acc) {
    const s16x8 zz = {0, 0, 0, 0, 0, 0, 0, 0};
#pragma unroll
    for (int seg = 0; seg < 8; ++seg) {
        s16x8 b = ldsfrag(Wd, 1024, nn & 3, wbase + seg * 4 + kq);
        if (!valid) b = zz;
        acc = MFMA16(ldsfrag(stgp, 256, mrow, seg * 4 + kq), b, acc);
    }
    return acc;
}

// flag-array grid barrier
__device__ __forceinline__ void gbar(unsigned* flags, unsigned target) {
    asm volatile("s_waitcnt vmcnt(0)" ::: "memory");
    __syncthreads();
    if (threadIdx.x == 0)
        __hip_atomic_store(&flags[blockIdx.x], target, __ATOMIC_RELAXED, __HIP_MEMORY_SCOPE_AGENT);
    if (threadIdx.x < NBLK) {
        while (__hip_atomic_load(&flags[threadIdx.x], __ATOMIC_RELAXED, __HIP_MEMORY_SCOPE_AGENT) < target)
            __builtin_amdgcn_s_sleep(1);
    }
    __syncthreads();
}

__global__ void __launch_bounds__(NTHR, 1) coop_k(P p) {
    extern __shared__ __align__(16) char smem[];
    short* W0s = (short*)smem;            // 16 x 1536 sw
    short* W1s = W0s + 16 * 1536;         // 16 x 1024 sw
    short* Wds = W1s + 16 * 1024;         // 4 x 1024 sw
    short* stg = Wds + 4 * 1024;          // 128 x 256 sw (stage / float scratch)
    float* smallf = (float*)(stg + 128 * 256);
    float* bias0s = smallf;               // 16
    float* bias1s = smallf + 16;          // 16
    float* red = smallf + 32;             // 16
    float* scv = smallf + 48;             // 256
    float* aU = smallf + 304;             // 256

    const int tid = threadIdx.x;
    const int blk = blockIdx.x;
    const int l = tid & 63;
    const int w = tid >> 6;
    const int lrow = l & 15;
    const int mrow = w * 16 + lrow;
    const int kq = l >> 4;
    const size_t OFF_HF = (size_t)TT * BH;
    const size_t OFF_CF = OFF_HF + 2 * (size_t)BH;
    const size_t OFF_AT = OFF_CF + 2 * (size_t)BH;
    const f32x4 fz = {0.f, 0.f, 0.f, 0.f};

    // --- prologue: LDS-resident weights (swizzled) ---
    for (int idx = tid; idx < 16 * 192; idx += NTHR) {
        int row = idx / 192, col8 = idx % 192;
        int g = (row & 3) * 512 + blk * 4 + (row >> 2);
        *reinterpret_cast<s16x8*>(W0s + row * 1536 + ((col8 ^ (row & 7)) << 3)) =
            *reinterpret_cast<const s16x8*>(p.W0cat + (size_t)g * 1536 + col8 * 8);
    }
    for (int idx = tid; idx < 16 * 128; idx += NTHR) {
        int row = idx / 128, col8 = idx % 128;
        int g = (row & 3) * 512 + blk * 4 + (row >> 2);
        *reinterpret_cast<s16x8*>(W1s + row * 1024 + ((col8 ^ (row & 7)) << 3)) =
            *reinterpret_cast<const s16x8*>(p.W1cat + (size_t)g * 1024 + col8 * 8);
    }
    {
        int row = tid >> 7, col8 = tid & 127;
        *reinterpret_cast<s16x8*>(Wds + row * 1024 + ((col8 ^ row) << 3)) =
            *reinterpret_cast<const s16x8*>(p.Woutb + (size_t)(blk * 4 + row) * 1024 + col8 * 8);
    }
    if (tid < 16) {
        int g = (tid & 3) * 512 + blk * 4 + (tid >> 2);
        bias0s[tid] = p.bias0[g];
        bias1s[tid] = p.bias1[g];
    }
    __syncthreads();

    const int bA = tid >> 2;
    const int jA = blk * 4 + (tid & 3);
    float c0reg = p.c0in[bA * HH + jA];
    float c1reg = p.c0in[BH + bA * HH + jA];
    unsigned ep = 0;
    u64 qa[16], qb[16];

    for (int t = 0; t < TT; ++t) {
        const size_t pB = (size_t)(t & 1) * BH;
        const size_t pN = (size_t)((t & 1) ^ 1) * BH;

        // ================= Phase A: layer-0 gates + cell =================
        {
            issue16(p.outx + pB, tid, 0, qa);
            f32x4 aE = fz, aO = fz, aH = fz;
            {
                const short* erow = p.Ebf + ((size_t)t * BB + mrow) * EE + kq * 8;
#pragma unroll
                for (int seg = 0; seg < 16; ++seg) {
                    s16x8 afr = *reinterpret_cast<const s16x8*>(erow + seg * 32);
                    aE = MFMA16(afr, ldsfrag(W0s, 1536, lrow, seg * 4 + kq), aE);
                }
            }
            write16(stg, tid, qa);
            issue16(p.outx + pB, tid, 1, qb);
            __syncthreads();
            aO = seg8(stg, W0s, 1536, 64, mrow, lrow, kq, aO);
            __syncthreads();
            write16(stg, tid, qb);
            issue16(p.h0x + pB, tid, 0, qa);
            __syncthreads();
            aO = seg8(stg, W0s, 1536, 96, mrow, lrow, kq, aO);
            __syncthreads();
            write16(stg, tid, qa);
            issue16(p.h0x + pB, tid, 1, qb);
            __syncthreads();
            aH = seg8(stg, W0s, 1536, 128, mrow, lrow, kq, aH);
            __syncthreads();
            write16(stg, tid, qb);
            __syncthreads();
            aH = seg8(stg, W0s, 1536, 160, mrow, lrow, kq, aH);

            f32x4 acc = aE + aO + aH;
            __syncthreads();
            float* scr = (float*)stg + w * 272;
#pragma unroll
            for (int r = 0; r < 4; ++r) scr[lrow * 17 + kq * 4 + r] = acc[r];
            __syncthreads();
            const int bloc = l >> 2;
            const int n0 = (l & 3) * 4;
            float gi = scr[(n0 + 0) * 17 + bloc] + bias0s[n0 + 0];
            float gf = scr[(n0 + 1) * 17 + bloc] + bias0s[n0 + 1];
            float gg = scr[(n0 + 2) * 17 + bloc] + bias0s[n0 + 2];
            float go = scr[(n0 + 3) * 17 + bloc] + bias0s[n0 + 3];
            float cn = sigm(gf) * c0reg + sigm(gi) * tanhf(gg);
            float hn = sigm(go) * tanhf(cn);
            c0reg = cn;
            ast2(&p.h0x[pN + bA * HH + jA], f2b(hn));
            if (t == TT - 1) {
                p.dout[OFF_HF + bA * HH + jA] = hn;
                p.dout[OFF_CF + bA * HH + jA] = cn;
            }
        }
        gbar(p.flags, ++ep);

        // ================= Phase B: layer-1 gates + cell =================
        {
            issue16(p.h0x + pN, tid, 0, qa);
            f32x4 b0 = fz, b1 = fz;
            write16(stg, tid, qa);
            issue16(p.h0x + pN, tid, 1, qb);
            __syncthreads();
            b0 = seg8(stg, W1s, 1024, 0, mrow, lrow, kq, b0);
            __syncthreads();
            write16(stg, tid, qb);
            issue16(p.h1x + pB, tid, 0, qa);
            __syncthreads();
            b0 = seg8(stg, W1s, 1024, 32, mrow, lrow, kq, b0);
            __syncthreads();
            write16(stg, tid, qa);
            issue16(p.h1x + pB, tid, 1, qb);
            __syncthreads();
            b1 = seg8(stg, W1s, 1024, 64, mrow, lrow, kq, b1);
            __syncthreads();
            write16(stg, tid, qb);
            __syncthreads();
            b1 = seg8(stg, W1s, 1024, 96, mrow, lrow, kq, b1);

            f32x4 acc = b0 + b1;
            __syncthreads();
            float* scr = (float*)stg + w * 272;
#pragma unroll
            for (int r = 0; r < 4; ++r) scr[lrow * 17 + kq * 4 + r] = acc[r];
            __syncthreads();
            const int bloc = l >> 2;
            const int n0 = (l & 3) * 4;
            float gi = scr[(n0 + 0) * 17 + bloc] + bias1s[n0 + 0];
            float gf = scr[(n0 + 1) * 17 + bloc] + bias1s[n0 + 1];
            float gg = scr[(n0 + 2) * 17 + bloc] + bias1s[n0 + 2];
            float go = scr[(n0 + 3) * 17 + bloc] + bias1s[n0 + 3];
            float cn = sigm(gf) * c1reg + sigm(gi) * tanhf(gg);
            float hn = sigm(go) * tanhf(cn);
            c1reg = cn;
            ast2(&p.h1x[pN + bA * HH + jA], f2b(hn));
            if (t == TT - 1) {
                p.dout[OFF_HF + BH + bA * HH + jA] = hn;
                p.dout[OFF_CF + BH + bA * HH + jA] = cn;
            }
        }
        gbar(p.flags, ++ep);

        // ================= Phase C: attention for batch b = blk (fp8 ctx, L2-resident) =================
        {
            float* pF = (float*)stg;        // 8 x 512 partials
            float* h1f = pF + 4096;         // 512
            if (tid < 128) {
                union { u64 v; short s[4]; } c;
                c.v = aldq(p.h1x + pN + blk * HH + tid * 4);
#pragma unroll
                for (int j = 0; j < 4; ++j) h1f[tid * 4 + j] = b2f(c.s[j]);
            }
            __syncthreads();
            float hreg[8];
#pragma unroll
            for (int j = 0; j < 8; ++j) hreg[j] = h1f[l * 8 + j];
            // score pass: wave w handles s = it*8 + w; lane owns 8 h-cols (8B fp8 load)
            const unsigned char* cwb = p.ctxW8 + (size_t)blk * SS * HH;
#pragma unroll 4
            for (int it = 0; it < 32; ++it) {
                const int s = it * 8 + w;
                u64 q = *reinterpret_cast<const u64*>(cwb + (size_t)s * HH + l * 8);
                float o[8];
                f8x8(q, o);
                float pd = 0.f;
#pragma unroll
                for (int j = 0; j < 8; ++j) pd += o[j] * hreg[j];
#pragma unroll
                for (int off = 32; off; off >>= 1) pd += __shfl_xor(pd, off);
                if (l == 0) scv[s] = pd;
            }
            __syncthreads();
            float sc = -1e30f, e = 0.f;
            if (tid < 256) sc = scv[tid];
            float mx = sc;
#pragma unroll
            for (int off = 32; off; off >>= 1) mx = fmaxf(mx, __shfl_xor(mx, off));
            if (l == 0 && tid < 256) red[w] = mx;
            __syncthreads();
            const float M = fmaxf(fmaxf(red[0], red[1]), fmaxf(red[2], red[3]));
            if (tid < 256) { e = __expf(sc - M); aU[tid] = e; }
            float se = e;
#pragma unroll
            for (int off = 32; off; off >>= 1) se += __shfl_xor(se, off);
            if (l == 0 && tid < 256) red[8 + w] = se;
            __syncthreads();
            const float inv = 1.f / (red[8] + red[9] + red[10] + red[11]);
            if (t == TT - 1 && tid < 256) p.dout[OFF_AT + blk * SS + tid] = aU[tid] * inv;
            // PV pass
            const unsigned char* cbb = p.ctxb8 + (size_t)blk * SS * HH;
            float wa[8];
#pragma unroll
            for (int j = 0; j < 8; ++j) wa[j] = 0.f;
#pragma unroll 4
            for (int it = 0; it < 32; ++it) {
                const int s = it * 8 + w;
                const float av = aU[s];
                u64 q = *reinterpret_cast<const u64*>(cbb + (size_t)s * HH + l * 8);
                float o[8];
                f8x8(q, o);
#pragma unroll
                for (int j = 0; j < 8; ++j) wa[j] += av * o[j];
            }
            {
                float4* dst = reinterpret_cast<float4*>(pF + w * 512 + l * 8);
                float4 v0 = {wa[0], wa[1], wa[2], wa[3]};
                float4 v1 = {wa[4], wa[5], wa[6], wa[7]};
                dst[0] = v0;
                dst[1] = v1;
            }
            __syncthreads();
            float s8 = 0.f;
#pragma unroll
            for (int ww = 0; ww < 8; ++ww) s8 += pF[ww * 512 + tid];
            ast2(&p.wcx[blk * HH + tid], f2b(s8 * inv));
        }
        gbar(p.flags, ++ep);

        // ================= Phase D: out = tanh([wc|h1] @ Wout^T), MFMA =================
        {
            issue16(p.wcx, tid, 0, qa);
            f32x4 acc = fz;
            const int nn = l & 15;
            const bool dv = nn < 4;
            write16(stg, tid, qa);
            issue16(p.wcx, tid, 1, qb);
            __syncthreads();
            acc = seg8m(stg, Wds, 0, mrow, nn, kq, dv, acc);
            __syncthreads();
            write16(stg, tid, qb);
            issue16(p.h1x + pN, tid, 0, qa);
            __syncthreads();
            acc = seg8m(stg, Wds, 32, mrow, nn, kq, dv, acc);
            __syncthreads();
            write16(stg, tid, qa);
            issue16(p.h1x + pN, tid, 1, qb);
            __syncthreads();
            acc = seg8m(stg, Wds, 64, mrow, nn, kq, dv, acc);
            __syncthreads();
            write16(stg, tid, qb);
            __syncthreads();
            acc = seg8m(stg, Wds, 96, mrow, nn, kq, dv, acc);
            if (dv) {
                const int col = blk * 4 + nn;
#pragma unroll
                for (int r = 0; r < 4; ++r) {
                    const int row = w * 16 + (l >> 4) * 4 + r;
                    float tv = tanhf(acc[r]);
                    __builtin_nontemporal_store(tv, &p.dout[(size_t)t * BH + row * HH + col]);
                    ast2(&p.outx[pN + row * HH + col], f2b(tv));
                }
            }
        }
        gbar(p.flags, ++ep);
    }
}

// ---------------- host ----------------

extern "C" void kernel_launch(void* const* d_in, const int* in_sizes, int n_in,
                              void* d_out, int out_size, void* d_ws, size_t ws_size,
                              hipStream_t stream) {
    const int* tokens = (const int*)d_in[0];
    const float* h0in = (const float*)d_in[1];
    const float* c0in = (const float*)d_in[2];
    const float* ctx = (const float*)d_in[3];
    const float* iout = (const float*)d_in[4];
    const float* emb = (const float*)d_in[5];
    const float* Wih0 = (const float*)d_in[6];
    const float* bih0 = (const float*)d_in[7];
    const float* Whh0 = (const float*)d_in[8];
    const float* bhh0 = (const float*)d_in[9];
    const float* Wih1 = (const float*)d_in[10];
    const float* bih1 = (const float*)d_in[11];
    const float* Whh1 = (const float*)d_in[12];
    const float* bhh1 = (const float*)d_in[13];
    const float* Win = (const float*)d_in[14];
    const float* Wout = (const float*)d_in[15];
    float* dout = (float*)d_out;

    char* pw = (char*)d_ws;
    auto take = [&](size_t bytes) { char* r = pw; pw += (bytes + 255) & ~(size_t)255; return r; };
    short* W0cat = (short*)take((size_t)2048 * 1536 * 2);
    short* W1cat = (short*)take((size_t)2048 * 1024 * 2);
    short* Winb  = (short*)take((size_t)512 * 512 * 2);
    short* Woutb = (short*)take((size_t)512 * 1024 * 2);
    float* bias0 = (float*)take(2048 * 4);
    float* bias1 = (float*)take(2048 * 4);
    short* Ebf   = (short*)take((size_t)TT * BB * EE * 2);
    unsigned char* ctxb8 = (unsigned char*)take((size_t)BB * SS * HH);
    unsigned char* ctxW8 = (unsigned char*)take((size_t)BB * SS * HH);
    short* h0x   = (short*)take((size_t)2 * BH * 2);
    short* h1x   = (short*)take((size_t)2 * BH * 2);
    short* outx  = (short*)take((size_t)2 * BH * 2);
    short* wcx   = (short*)take((size_t)BH * 2);
    unsigned* flags = (unsigned*)take(NBLK * 4);

    k_pack2<<<2048, 256, 0, stream>>>(Wih0, 1024, Whh0, 512, W0cat, 2048 * 1536);
    k_pack2<<<2048, 256, 0, stream>>>(Wih1, 512, Whh1, 512, W1cat, 2048 * 1024);
    k_pack2<<<1024, 256, 0, stream>>>(Win, 512, Win, 0, Winb, 512 * 512);
    k_pack2<<<1024, 256, 0, stream>>>(Wout, 1024, Wout, 0, Woutb, 512 * 1024);
    k_bias<<<8, 256, 0, stream>>>(bih0, bhh0, bias0, bih1, bhh1, bias1);
    k_emb<<<4096, 256, 0, stream>>>(tokens, emb, Ebf);
    k_ctx8<<<4096, 256, 0, stream>>>(ctx, ctxb8);
    k_state<<<256, 256, 0, stream>>>(h0in, iout, h0x, h1x, outx);
    k_ctxw8<<<dim3(8, 256), 512, 0, stream>>>(ctx, Winb, ctxW8);
    (void)hipMemsetAsync(flags, 0, NBLK * 4, stream);

    const unsigned smem_bytes = (16 * 1536 + 16 * 1024 + 4 * 1024 + 128 * 256) * 2 + (16 + 16 + 16 + 256 + 256) * 4;
    (void)hipFuncSetAttribute((const void*)coop_k, hipFuncAttributeMaxDynamicSharedMemorySize, (int)smem_bytes);

    P prm;
    prm.Ebf = Ebf; prm.c0in = c0in;
    prm.ctxb8 = ctxb8; prm.ctxW8 = ctxW8;
    prm.W0cat = W0cat; prm.W1cat = W1cat; prm.Woutb = Woutb;
    prm.bias0 = bias0; prm.bias1 = bias1;
    prm.h0x = h0x; prm.h1x = h1x; prm.outx = outx; prm.wcx = wcx;
    prm.dout = dout; prm.flags = flags;
    void* args[] = {&prm};
    (void)hipLaunchCooperativeKernel((void*)coop_k, dim3(NBLK), dim3(NTHR), args, smem_bytes, stream);
}

// Round 8
// 15081.061 us; speedup vs baseline: 2.5502x; 1.1002x over previous
//
#include <hip/hip_runtime.h>
#include <hip/hip_bf16.h>
#include <math.h>

#define TT 256
#define BB 128
#define SS 256
#define HH 512
#define EE 512
#define NBLK 128
#define NTHR 512
#define BH (BB * HH)

typedef __attribute__((ext_vector_type(4))) float f32x4;
typedef __attribute__((ext_vector_type(2))) float f32x2;
typedef __attribute__((ext_vector_type(8))) short s16x8;
typedef unsigned long long u64;

__device__ __forceinline__ float b2f(short v) {
    union { unsigned u; float f; } c;
    c.u = ((unsigned)(unsigned short)v) << 16;
    return c.f;
}
__device__ __forceinline__ short f2b(float f) {
    union { float f; unsigned u; } c; c.f = f;
    unsigned u = c.u;
    unsigned r = (u + 0x7fffu + ((u >> 16) & 1u)) >> 16;
    return (short)r;
}
__device__ __forceinline__ float sigm(float x) { return 1.f / (1.f + __expf(-x)); }

// fp8 e4m3 helpers (HW cvt)
__device__ __forceinline__ unsigned short f2fp8x2(float x, float y) {
    return (unsigned short)(__builtin_amdgcn_cvt_pk_fp8_f32(x, y, 0, false) & 0xffff);
}
__device__ __forceinline__ void f8x8(u64 q, float* o) {
    unsigned w0 = (unsigned)q, w1 = (unsigned)(q >> 32);
    f32x2 a = __builtin_amdgcn_cvt_pk_f32_fp8(w0, false);
    f32x2 b = __builtin_amdgcn_cvt_pk_f32_fp8(w0, true);
    f32x2 c = __builtin_amdgcn_cvt_pk_f32_fp8(w1, false);
    f32x2 d = __builtin_amdgcn_cvt_pk_f32_fp8(w1, true);
    o[0] = a[0]; o[1] = a[1]; o[2] = b[0]; o[3] = b[1];
    o[4] = c[0]; o[5] = c[1]; o[6] = d[0]; o[7] = d[1];
}

// L2-bypassing (agent-scope) exchange primitives
__device__ __forceinline__ u64 aldq(const void* p) {
    return __hip_atomic_load((const u64*)p, __ATOMIC_RELAXED, __HIP_MEMORY_SCOPE_AGENT);
}
__device__ __forceinline__ void ast2(short* p, short v) {
    __hip_atomic_store(p, v, __ATOMIC_RELAXED, __HIP_MEMORY_SCOPE_AGENT);
}
// 16B uncached (LLC-coherent) load — compiler has no 16B atomic; inline asm.
// MUST be followed by an explicit s_waitcnt vmcnt(0) before the result is used.
__device__ __forceinline__ s16x8 ald16(const void* p) {
    s16x8 r;
    asm volatile("global_load_dwordx4 %0, %1, off sc0 sc1" : "=v"(r) : "v"(p) : "memory");
    return r;
}

// ---------------- prep kernels ----------------

__global__ void k_pack2(const float* __restrict__ Wa, int ka, const float* __restrict__ Wb, int kb,
                        short* __restrict__ dst, int n) {
    const int K = ka + kb;
    for (int i = blockIdx.x * blockDim.x + threadIdx.x; i < n; i += gridDim.x * blockDim.x) {
        int g = i / K, k = i - g * K;
        float v = (k < ka) ? Wa[(size_t)g * ka + k] : Wb[(size_t)g * kb + (k - ka)];
        dst[i] = f2b(v);
    }
}

__global__ void k_bias(const float* __restrict__ a, const float* __restrict__ b, float* __restrict__ o,
                       const float* __restrict__ a2, const float* __restrict__ b2, float* __restrict__ o2) {
    int i = blockIdx.x * blockDim.x + threadIdx.x;
    if (i < 2048) { o[i] = a[i] + b[i]; o2[i] = a2[i] + b2[i]; }
}

__global__ void k_emb(const int* __restrict__ tok, const float* __restrict__ emb, short* __restrict__ Ebf) {
    const int n = TT * BB * EE;
    for (int i = blockIdx.x * blockDim.x + threadIdx.x; i < n; i += gridDim.x * blockDim.x) {
        int tb = i >> 9, k = i & 511;
        int t = tok[tb];
        Ebf[i] = f2b(emb[(size_t)t * EE + k]);
    }
}

__global__ void k_ctx8(const float* __restrict__ ctx, unsigned char* __restrict__ c8) {
    const int n2 = BB * SS * (HH / 2);
    for (int i = blockIdx.x * blockDim.x + threadIdx.x; i < n2; i += gridDim.x * blockDim.x) {
        int h2 = i & 255, rest = i >> 8;
        int s = rest & 255, b = rest >> 8;
        int h = h2 * 2;
        const float* src = ctx + ((size_t)s * BB + b) * HH + h;
        *reinterpret_cast<unsigned short*>(c8 + ((size_t)b * SS + s) * HH + h) = f2fp8x2(src[0], src[1]);
    }
}

__global__ __launch_bounds__(512) void k_ctxw8(const float* __restrict__ ctx, const short* __restrict__ Winb,
                                               unsigned char* __restrict__ ctxW8) {
    const int tid = threadIdx.x, w = tid >> 6, l = tid & 63;
    const int m0 = blockIdx.y * 128, n0 = blockIdx.x * 64;
    const int kc8 = (l >> 4) * 8;
    const int m = m0 + w * 16 + (l & 15);
    const int b = m >> 8, s = m & 255;
    const float* arow = ctx + ((size_t)s * BB + b) * HH + kc8;
    f32x4 acc[4];
    const f32x4 zero = {0.f, 0.f, 0.f, 0.f};
#pragma unroll
    for (int j = 0; j < 4; ++j) acc[j] = zero;
#pragma unroll
    for (int kc = 0; kc < 16; ++kc) {
        const int k0 = kc * 32;
        float4 x0 = *reinterpret_cast<const float4*>(arow + k0);
        float4 x1 = *reinterpret_cast<const float4*>(arow + k0 + 4);
        s16x8 afr;
        afr[0] = f2b(x0.x); afr[1] = f2b(x0.y); afr[2] = f2b(x0.z); afr[3] = f2b(x0.w);
        afr[4] = f2b(x1.x); afr[5] = f2b(x1.y); afr[6] = f2b(x1.z); afr[7] = f2b(x1.w);
#pragma unroll
        for (int j = 0; j < 4; ++j) {
            s16x8 bfr = *reinterpret_cast<const s16x8*>(Winb + (size_t)(n0 + j * 16 + (l & 15)) * HH + k0 + kc8);
            acc[j] = __builtin_amdgcn_mfma_f32_16x16x32_bf16(afr, bfr, acc[j], 0, 0, 0);
        }
    }
#pragma unroll
    for (int j = 0; j < 4; ++j)
#pragma unroll
        for (int r = 0; r < 4; ++r)
            ctxW8[(size_t)(m0 + w * 16 + (l >> 4) * 4 + r) * HH + (n0 + j * 16 + (l & 15))] =
                (unsigned char)(__builtin_amdgcn_cvt_pk_fp8_f32(acc[j][r], 0.f, 0, false) & 0xff);
}

__global__ void k_state(const float* __restrict__ h0in, const float* __restrict__ iout,
                        short* __restrict__ h0x, short* __restrict__ h1x, short* __restrict__ outx) {
    int i = blockIdx.x * blockDim.x + threadIdx.x;
    if (i < BH) {
        h0x[i] = f2b(h0in[i]);
        h1x[i] = f2b(h0in[BH + i]);
        outx[i] = f2b(iout[i]);
    }
}

// ---------------- persistent cooperative kernel ----------------

struct P {
    const short* Ebf;
    const float* c0in;
    const unsigned char* ctxb8;
    const unsigned char* ctxW8;
    const short* W0cat;
    const short* W1cat;
    const short* Woutb;
    const float* bias0;
    const float* bias1;
    short* h0x;
    short* h1x;
    short* outx;
    short* wcx;
    float* dout;
    unsigned* flags;
};

#define MFMA16(a, b, c) __builtin_amdgcn_mfma_f32_16x16x32_bf16((a), (b), (c), 0, 0, 0)

__device__ __forceinline__ s16x8 ldsfrag(const short* base, int stride, int row, int col8) {
    return *reinterpret_cast<const s16x8*>(base + row * stride + ((col8 ^ (row & 7)) << 3));
}

// issue 8 x 16B uncached loads (block-wide 64KB half-tile) into regs
__device__ __forceinline__ void issue8(const short* __restrict__ src, int tid, int khalf, s16x8* q) {
#pragma unroll
    for (int c = 0; c < 8; ++c) {
        const int chunk = c * 512 + tid;
        const int row = chunk >> 5, col8 = chunk & 31;
        q[c] = ald16(src + row * HH + khalf * 256 + col8 * 8);
    }
}
// drain asm loads, then swizzled ds_write_b128
__device__ __forceinline__ void write8(short* __restrict__ stg, int tid, const s16x8* q) {
    asm volatile("s_waitcnt vmcnt(0)" ::: "memory");
#pragma unroll
    for (int c = 0; c < 8; ++c) {
        const int chunk = c * 512 + tid;
        const int row = chunk >> 5, col8 = chunk & 31;
        *reinterpret_cast<s16x8*>(stg + row * 256 + ((col8 ^ (row & 7)) << 3)) = q[c];
    }
}

__device__ __forceinline__ f32x4 seg8(const short* stgp, const short* Ws, int wstride, int wbase,
                                      int mrow, int wrow, int kq, f32x4 acc) {
#pragma unroll
    for (int seg = 0; seg < 8; ++seg)
        acc = MFMA16(ldsfrag(stgp, 256, mrow, seg * 4 + kq),
                     ldsfrag(Ws, wstride, wrow, wbase + seg * 4 + kq), acc);
    return acc;
}

__device__ __forceinline__ f32x4 seg8m(const short* stgp, const short* Wd, int wbase,
                                       int mrow, int nn, int kq, bool valid, f32x4 acc) {
    const s16x8 zz = {0, 0, 0, 0, 0, 0, 0, 0};
#pragma unroll
    for (int seg = 0; seg < 8; ++seg) {
        s16x8 b = ldsfrag(Wd, 1024, nn & 3, wbase + seg * 4 + kq);
        if (!valid) b = zz;
        acc = MFMA16(ldsfrag(stgp, 256, mrow, seg * 4 + kq), b, acc);
    }
    return acc;
}

// flag-array grid barrier
__device__ __forceinline__ void gbar(unsigned* flags, unsigned target) {
    asm volatile("s_waitcnt vmcnt(0)" ::: "memory");
    __syncthreads();
    if (threadIdx.x == 0)
        __hip_atomic_store(&flags[blockIdx.x], target, __ATOMIC_RELAXED, __HIP_MEMORY_SCOPE_AGENT);
    if (threadIdx.x < NBLK) {
        while (__hip_atomic_load(&flags[threadIdx.x], __ATOMIC_RELAXED, __HIP_MEMORY_SCOPE_AGENT) < target)
            __builtin_amdgcn_s_sleep(1);
    }
    __syncthreads();
}

__global__ void __launch_bounds__(NTHR, 1) coop_k(P p) {
    extern __shared__ __align__(16) char smem[];
    short* W0s = (short*)smem;            // 16 x 1536 sw
    short* W1s = W0s + 16 * 1536;         // 16 x 1024 sw
    short* Wds = W1s + 16 * 1024;         // 4 x 1024 sw
    short* stg = Wds + 4 * 1024;          // 128 x 256 sw (stage / float scratch)
    float* smallf = (float*)(stg + 128 * 256);
    float* bias0s = smallf;               // 16
    float* bias1s = smallf + 16;          // 16
    float* red = smallf + 32;             // 16
    float* scv = smallf + 48;             // 256
    float* aU = smallf + 304;             // 256

    const int tid = threadIdx.x;
    const int blk = blockIdx.x;
    const int l = tid & 63;
    const int w = tid >> 6;
    const int lrow = l & 15;
    const int mrow = w * 16 + lrow;
    const int kq = l >> 4;
    const size_t OFF_HF = (size_t)TT * BH;
    const size_t OFF_CF = OFF_HF + 2 * (size_t)BH;
    const size_t OFF_AT = OFF_CF + 2 * (size_t)BH;
    const f32x4 fz = {0.f, 0.f, 0.f, 0.f};

    // --- prologue: LDS-resident weights (swizzled) ---
    for (int idx = tid; idx < 16 * 192; idx += NTHR) {
        int row = idx / 192, col8 = idx % 192;
        int g = (row & 3) * 512 + blk * 4 + (row >> 2);
        *reinterpret_cast<s16x8*>(W0s + row * 1536 + ((col8 ^ (row & 7)) << 3)) =
            *reinterpret_cast<const s16x8*>(p.W0cat + (size_t)g * 1536 + col8 * 8);
    }
    for (int idx = tid; idx < 16 * 128; idx += NTHR) {
        int row = idx / 128, col8 = idx % 128;
        int g = (row & 3) * 512 + blk * 4 + (row >> 2);
        *reinterpret_cast<s16x8*>(W1s + row * 1024 + ((col8 ^ (row & 7)) << 3)) =
            *reinterpret_cast<const s16x8*>(p.W1cat + (size_t)g * 1024 + col8 * 8);
    }
    {
        int row = tid >> 7, col8 = tid & 127;
        *reinterpret_cast<s16x8*>(Wds + row * 1024 + ((col8 ^ row) << 3)) =
            *reinterpret_cast<const s16x8*>(p.Woutb + (size_t)(blk * 4 + row) * 1024 + col8 * 8);
    }
    if (tid < 16) {
        int g = (tid & 3) * 512 + blk * 4 + (tid >> 2);
        bias0s[tid] = p.bias0[g];
        bias1s[tid] = p.bias1[g];
    }
    __syncthreads();

    const int bA = tid >> 2;
    const int jA = blk * 4 + (tid & 3);
    float c0reg = p.c0in[bA * HH + jA];
    float c1reg = p.c0in[BH + bA * HH + jA];
    unsigned ep = 0;
    s16x8 qa[8], qb[8];

    for (int t = 0; t < TT; ++t) {
        const size_t pB = (size_t)(t & 1) * BH;
        const size_t pN = (size_t)((t & 1) ^ 1) * BH;

        // ================= Phase A: layer-0 gates + cell =================
        {
            issue8(p.outx + pB, tid, 0, qa);
            f32x4 aE = fz, aO = fz, aH = fz;
            {
                const short* erow = p.Ebf + ((size_t)t * BB + mrow) * EE + kq * 8;
#pragma unroll
                for (int seg = 0; seg < 16; ++seg) {
                    s16x8 afr = *reinterpret_cast<const s16x8*>(erow + seg * 32);
                    aE = MFMA16(afr, ldsfrag(W0s, 1536, lrow, seg * 4 + kq), aE);
                }
            }
            write8(stg, tid, qa);
            issue8(p.outx + pB, tid, 1, qb);
            __syncthreads();
            aO = seg8(stg, W0s, 1536, 64, mrow, lrow, kq, aO);
            __syncthreads();
            write8(stg, tid, qb);
            issue8(p.h0x + pB, tid, 0, qa);
            __syncthreads();
            aO = seg8(stg, W0s, 1536, 96, mrow, lrow, kq, aO);
            __syncthreads();
            write8(stg, tid, qa);
            issue8(p.h0x + pB, tid, 1, qb);
            __syncthreads();
            aH = seg8(stg, W0s, 1536, 128, mrow, lrow, kq, aH);
            __syncthreads();
            write8(stg, tid, qb);
            __syncthreads();
            aH = seg8(stg, W0s, 1536, 160, mrow, lrow, kq, aH);

            f32x4 acc = aE + aO + aH;
            __syncthreads();
            float* scr = (float*)stg + w * 272;
#pragma unroll
            for (int r = 0; r < 4; ++r) scr[lrow * 17 + kq * 4 + r] = acc[r];
            __syncthreads();
            const int bloc = l >> 2;
            const int n0 = (l & 3) * 4;
            float gi = scr[(n0 + 0) * 17 + bloc] + bias0s[n0 + 0];
            float gf = scr[(n0 + 1) * 17 + bloc] + bias0s[n0 + 1];
            float gg = scr[(n0 + 2) * 17 + bloc] + bias0s[n0 + 2];
            float go = scr[(n0 + 3) * 17 + bloc] + bias0s[n0 + 3];
            float cn = sigm(gf) * c0reg + sigm(gi) * tanhf(gg);
            float hn = sigm(go) * tanhf(cn);
            c0reg = cn;
            ast2(&p.h0x[pN + bA * HH + jA], f2b(hn));
            if (t == TT - 1) {
                p.dout[OFF_HF + bA * HH + jA] = hn;
                p.dout[OFF_CF + bA * HH + jA] = cn;
            }
        }
        gbar(p.flags, ++ep);

        // ================= Phase B: layer-1 gates + cell =================
        {
            issue8(p.h0x + pN, tid, 0, qa);
            f32x4 b0 = fz, b1 = fz;
            write8(stg, tid, qa);
            issue8(p.h0x + pN, tid, 1, qb);
            __syncthreads();
            b0 = seg8(stg, W1s, 1024, 0, mrow, lrow, kq, b0);
            __syncthreads();
            write8(stg, tid, qb);
            issue8(p.h1x + pB, tid, 0, qa);
            __syncthreads();
            b0 = seg8(stg, W1s, 1024, 32, mrow, lrow, kq, b0);
            __syncthreads();
            write8(stg, tid, qa);
            issue8(p.h1x + pB, tid, 1, qb);
            __syncthreads();
            b1 = seg8(stg, W1s, 1024, 64, mrow, lrow, kq, b1);
            __syncthreads();
            write8(stg, tid, qb);
            __syncthreads();
            b1 = seg8(stg, W1s, 1024, 96, mrow, lrow, kq, b1);

            f32x4 acc = b0 + b1;
            __syncthreads();
            float* scr = (float*)stg + w * 272;
#pragma unroll
            for (int r = 0; r < 4; ++r) scr[lrow * 17 + kq * 4 + r] = acc[r];
            __syncthreads();
            const int bloc = l >> 2;
            const int n0 = (l & 3) * 4;
            float gi = scr[(n0 + 0) * 17 + bloc] + bias1s[n0 + 0];
            float gf = scr[(n0 + 1) * 17 + bloc] + bias1s[n0 + 1];
            float gg = scr[(n0 + 2) * 17 + bloc] + bias1s[n0 + 2];
            float go = scr[(n0 + 3) * 17 + bloc] + bias1s[n0 + 3];
            float cn = sigm(gf) * c1reg + sigm(gi) * tanhf(gg);
            float hn = sigm(go) * tanhf(cn);
            c1reg = cn;
            ast2(&p.h1x[pN + bA * HH + jA], f2b(hn));
            if (t == TT - 1) {
                p.dout[OFF_HF + BH + bA * HH + jA] = hn;
                p.dout[OFF_CF + BH + bA * HH + jA] = cn;
            }
        }
        gbar(p.flags, ++ep);

        // ================= Phase C: attention for batch b = blk (fp8 ctx, L2-resident) =================
        {
            float* pF = (float*)stg;        // 8 x 512 partials
            float* h1f = pF + 4096;         // 512
            if (tid < 128) {
                union { u64 v; short s[4]; } c;
                c.v = aldq(p.h1x + pN + blk * HH + tid * 4);
#pragma unroll
                for (int j = 0; j < 4; ++j) h1f[tid * 4 + j] = b2f(c.s[j]);
            }
            __syncthreads();
            float hreg[8];
#pragma unroll
            for (int j = 0; j < 8; ++j) hreg[j] = h1f[l * 8 + j];
            const unsigned char* cwb = p.ctxW8 + (size_t)blk * SS * HH;
#pragma unroll 4
            for (int it = 0; it < 32; ++it) {
                const int s = it * 8 + w;
                u64 q = *reinterpret_cast<const u64*>(cwb + (size_t)s * HH + l * 8);
                float o[8];
                f8x8(q, o);
                float pd = 0.f;
#pragma unroll
                for (int j = 0; j < 8; ++j) pd += o[j] * hreg[j];
#pragma unroll
                for (int off = 32; off; off >>= 1) pd += __shfl_xor(pd, off);
                if (l == 0) scv[s] = pd;
            }
            __syncthreads();
            float sc = -1e30f, e = 0.f;
            if (tid < 256) sc = scv[tid];
            float mx = sc;
#pragma unroll
            for (int off = 32; off; off >>= 1) mx = fmaxf(mx, __shfl_xor(mx, off));
            if (l == 0 && tid < 256) red[w] = mx;
            __syncthreads();
            const float M = fmaxf(fmaxf(red[0], red[1]), fmaxf(red[2], red[3]));
            if (tid < 256) { e = __expf(sc - M); aU[tid] = e; }
            float se = e;
#pragma unroll
            for (int off = 32; off; off >>= 1) se += __shfl_xor(se, off);
            if (l == 0 && tid < 256) red[8 + w] = se;
            __syncthreads();
            const float inv = 1.f / (red[8] + red[9] + red[10] + red[11]);
            if (t == TT - 1 && tid < 256) p.dout[OFF_AT + blk * SS + tid] = aU[tid] * inv;
            const unsigned char* cbb = p.ctxb8 + (size_t)blk * SS * HH;
            float wa[8];
#pragma unroll
            for (int j = 0; j < 8; ++j) wa[j] = 0.f;
#pragma unroll 4
            for (int it = 0; it < 32; ++it) {
                const int s = it * 8 + w;
                const float av = aU[s];
                u64 q = *reinterpret_cast<const u64*>(cbb + (size_t)s * HH + l * 8);
                float o[8];
                f8x8(q, o);
#pragma unroll
                for (int j = 0; j < 8; ++j) wa[j] += av * o[j];
            }
            {
                float4* dst = reinterpret_cast<float4*>(pF + w * 512 + l * 8);
                float4 v0 = {wa[0], wa[1], wa[2], wa[3]};
                float4 v1 = {wa[4], wa[5], wa[6], wa[7]};
                dst[0] = v0;
                dst[1] = v1;
            }
            __syncthreads();
            float s8 = 0.f;
#pragma unroll
            for (int ww = 0; ww < 8; ++ww) s8 += pF[ww * 512 + tid];
            ast2(&p.wcx[blk * HH + tid], f2b(s8 * inv));
        }
        gbar(p.flags, ++ep);

        // ================= Phase D: out = tanh([wc|h1] @ Wout^T), MFMA =================
        {
            issue8(p.wcx, tid, 0, qa);
            f32x4 acc = fz;
            const int nn = l & 15;
            const bool dv = nn < 4;
            write8(stg, tid, qa);
            issue8(p.wcx, tid, 1, qb);
            __syncthreads();
            acc = seg8m(stg, Wds, 0, mrow, nn, kq, dv, acc);
            __syncthreads();
            write8(stg, tid, qb);
            issue8(p.h1x + pN, tid, 0, qa);
            __syncthreads();
            acc = seg8m(stg, Wds, 32, mrow, nn, kq, dv, acc);
            __syncthreads();
            write8(stg, tid, qa);
            issue8(p.h1x + pN, tid, 1, qb);
            __syncthreads();
            acc = seg8m(stg, Wds, 64, mrow, nn, kq, dv, acc);
            __syncthreads();
            write8(stg, tid, qb);
            __syncthreads();
            acc = seg8m(stg, Wds, 96, mrow, nn, kq, dv, acc);
            if (dv) {
                const int col = blk * 4 + nn;
#pragma unroll
                for (int r = 0; r < 4; ++r) {
                    const int row = w * 16 + (l >> 4) * 4 + r;
                    float tv = tanhf(acc[r]);
                    __builtin_nontemporal_store(tv, &p.dout[(size_t)t * BH + row * HH + col]);
                    ast2(&p.outx[pN + row * HH + col], f2b(tv));
                }
            }
        }
        gbar(p.flags, ++ep);
    }
}

// ---------------- host ----------------

extern "C" void kernel_launch(void* const* d_in, const int* in_sizes, int n_in,
                              void* d_out, int out_size, void* d_ws, size_t ws_size,
                              hipStream_t stream) {
    const int* tokens = (const int*)d_in[0];
    const float* h0in = (const float*)d_in[1];
    const float* c0in = (const float*)d_in[2];
    const float* ctx = (const float*)d_in[3];
    const float* iout = (const float*)d_in[4];
    const float* emb = (const float*)d_in[5];
    const float* Wih0 = (const float*)d_in[6];
    const float* bih0 = (const float*)d_in[7];
    const float* Whh0 = (const float*)d_in[8];
    const float* bhh0 = (const float*)d_in[9];
    const float* Wih1 = (const float*)d_in[10];
    const float* bih1 = (const float*)d_in[11];
    const float* Whh1 = (const float*)d_in[12];
    const float* bhh1 = (const float*)d_in[13];
    const float* Win = (const float*)d_in[14];
    const float* Wout = (const float*)d_in[15];
    float* dout = (float*)d_out;

    char* pw = (char*)d_ws;
    auto take = [&](size_t bytes) { char* r = pw; pw += (bytes + 255) & ~(size_t)255; return r; };
    short* W0cat = (short*)take((size_t)2048 * 1536 * 2);
    short* W1cat = (short*)take((size_t)2048 * 1024 * 2);
    short* Winb  = (short*)take((size_t)512 * 512 * 2);
    short* Woutb = (short*)take((size_t)512 * 1024 * 2);
    float* bias0 = (float*)take(2048 * 4);
    float* bias1 = (float*)take(2048 * 4);
    short* Ebf   = (short*)take((size_t)TT * BB * EE * 2);
    unsigned char* ctxb8 = (unsigned char*)take((size_t)BB * SS * HH);
    unsigned char* ctxW8 = (unsigned char*)take((size_t)BB * SS * HH);
    short* h0x   = (short*)take((size_t)2 * BH * 2);
    short* h1x   = (short*)take((size_t)2 * BH * 2);
    short* outx  = (short*)take((size_t)2 * BH * 2);
    short* wcx   = (short*)take((size_t)BH * 2);
    unsigned* flags = (unsigned*)take(NBLK * 4);

    k_pack2<<<2048, 256, 0, stream>>>(Wih0, 1024, Whh0, 512, W0cat, 2048 * 1536);
    k_pack2<<<2048, 256, 0, stream>>>(Wih1, 512, Whh1, 512, W1cat, 2048 * 1024);
    k_pack2<<<1024, 256, 0, stream>>>(Win, 512, Win, 0, Winb, 512 * 512);
    k_pack2<<<1024, 256, 0, stream>>>(Wout, 1024, Wout, 0, Woutb, 512 * 1024);
    k_bias<<<8, 256, 0, stream>>>(bih0, bhh0, bias0, bih1, bhh1, bias1);
    k_emb<<<4096, 256, 0, stream>>>(tokens, emb, Ebf);
    k_ctx8<<<4096, 256, 0, stream>>>(ctx, ctxb8);
    k_state<<<256, 256, 0, stream>>>(h0in, iout, h0x, h1x, outx);
    k_ctxw8<<<dim3(8, 256), 512, 0, stream>>>(ctx, Winb, ctxW8);
    (void)hipMemsetAsync(flags, 0, NBLK * 4, stream);

    const unsigned smem_bytes = (16 * 1536 + 16 * 1024 + 4 * 1024 + 128 * 256) * 2 + (16 + 16 + 16 + 256 + 256) * 4;
    (void)hipFuncSetAttribute((const void*)coop_k, hipFuncAttributeMaxDynamicSharedMemorySize, (int)smem_bytes);

    P prm;
    prm.Ebf = Ebf; prm.c0in = c0in;
    prm.ctxb8 = ctxb8; prm.ctxW8 = ctxW8;
    prm.W0cat = W0cat; prm.W1cat = W1cat; prm.Woutb = Woutb;
    prm.bias0 = bias0; prm.bias1 = bias1;
    prm.h0x = h0x; prm.h1x = h1x; prm.outx = outx; prm.wcx = wcx;
    prm.dout = dout; prm.flags = flags;
    void* args[] = {&prm};
    (void)hipLaunchCooperativeKernel((void*)coop_k, dim3(NBLK), dim3(NTHR), args, smem_bytes, stream);
}

// Round 9
// 14798.639 us; speedup vs baseline: 2.5989x; 1.0191x over previous
//
#include <hip/hip_runtime.h>
#include <hip/hip_bf16.h>
#include <math.h>

#define TT 256
#define BB 128
#define SS 256
#define HH 512
#define EE 512
#define NBLK 128
#define NTHR 512
#define BH (BB * HH)

typedef __attribute__((ext_vector_type(4))) float f32x4;
typedef __attribute__((ext_vector_type(2))) float f32x2;
typedef __attribute__((ext_vector_type(8))) short s16x8;
typedef unsigned long long u64;

__device__ __forceinline__ float b2f(short v) {
    union { unsigned u; float f; } c;
    c.u = ((unsigned)(unsigned short)v) << 16;
    return c.f;
}
__device__ __forceinline__ short f2b(float f) {
    union { float f; unsigned u; } c; c.f = f;
    unsigned u = c.u;
    unsigned r = (u + 0x7fffu + ((u >> 16) & 1u)) >> 16;
    return (short)r;
}
__device__ __forceinline__ float sigm(float x) { return 1.f / (1.f + __expf(-x)); }

__device__ __forceinline__ unsigned short f2fp8x2(float x, float y) {
    return (unsigned short)(__builtin_amdgcn_cvt_pk_fp8_f32(x, y, 0, false) & 0xffff);
}
__device__ __forceinline__ void f8x8(u64 q, float* o) {
    unsigned w0 = (unsigned)q, w1 = (unsigned)(q >> 32);
    f32x2 a = __builtin_amdgcn_cvt_pk_f32_fp8(w0, false);
    f32x2 b = __builtin_amdgcn_cvt_pk_f32_fp8(w0, true);
    f32x2 c = __builtin_amdgcn_cvt_pk_f32_fp8(w1, false);
    f32x2 d = __builtin_amdgcn_cvt_pk_f32_fp8(w1, true);
    o[0] = a[0]; o[1] = a[1]; o[2] = b[0]; o[3] = b[1];
    o[4] = c[0]; o[5] = c[1]; o[6] = d[0]; o[7] = d[1];
}

// agent-scope (LLC-coherent, cache-bypassing) exchange primitives
__device__ __forceinline__ u64 aldq(const void* p) {
    return __hip_atomic_load((const u64*)p, __ATOMIC_RELAXED, __HIP_MEMORY_SCOPE_AGENT);
}
__device__ __forceinline__ void ast2(short* p, short v) {
    __hip_atomic_store(p, v, __ATOMIC_RELAXED, __HIP_MEMORY_SCOPE_AGENT);
}
__device__ __forceinline__ s16x8 ald16(const void* p) {
    s16x8 r;
    asm volatile("global_load_dwordx4 %0, %1, off sc0 sc1" : "=v"(r) : "v"(p) : "memory");
    return r;
}

// LDS-only barrier: does NOT drain vmcnt (raw s_barrier; __syncthreads would
// emit s_waitcnt vmcnt(0) and flush the staging pipeline).
__device__ __forceinline__ void lbar() {
    asm volatile("s_waitcnt lgkmcnt(0)" ::: "memory");
    __builtin_amdgcn_s_barrier();
}

// ---------------- prep kernels ----------------

__global__ void k_pack2(const float* __restrict__ Wa, int ka, const float* __restrict__ Wb, int kb,
                        short* __restrict__ dst, int n) {
    const int K = ka + kb;
    for (int i = blockIdx.x * blockDim.x + threadIdx.x; i < n; i += gridDim.x * blockDim.x) {
        int g = i / K, k = i - g * K;
        float v = (k < ka) ? Wa[(size_t)g * ka + k] : Wb[(size_t)g * kb + (k - ka)];
        dst[i] = f2b(v);
    }
}

__global__ void k_bias(const float* __restrict__ a, const float* __restrict__ b, float* __restrict__ o,
                       const float* __restrict__ a2, const float* __restrict__ b2, float* __restrict__ o2) {
    int i = blockIdx.x * blockDim.x + threadIdx.x;
    if (i < 2048) { o[i] = a[i] + b[i]; o2[i] = a2[i] + b2[i]; }
}

__global__ void k_emb(const int* __restrict__ tok, const float* __restrict__ emb, short* __restrict__ Ebf) {
    const int n = TT * BB * EE;
    for (int i = blockIdx.x * blockDim.x + threadIdx.x; i < n; i += gridDim.x * blockDim.x) {
        int tb = i >> 9, k = i & 511;
        int t = tok[tb];
        Ebf[i] = f2b(emb[(size_t)t * EE + k]);
    }
}

// WRP[m*512 + j] = pack2bf16(Wout[j][512+2m], Wout[j][512+2m+1])   (h1 half of Wout)
__global__ void k_packwr(const float* __restrict__ Wout, unsigned* __restrict__ WRP) {
    int i = blockIdx.x * blockDim.x + threadIdx.x;
    if (i < 256 * 512) {
        int m = i >> 9, j = i & 511;
        unsigned lo = (unsigned)(unsigned short)f2b(Wout[(size_t)j * 1024 + 512 + 2 * m]);
        unsigned hi = (unsigned)(unsigned short)f2b(Wout[(size_t)j * 1024 + 512 + 2 * m + 1]);
        WRP[i] = lo | (hi << 16);
    }
}

// out8[(b*S+s), n] = fp8( sum_k ctx[s,b,k] * Wb[n, k] ), Wb row-stride = wstride
__global__ __launch_bounds__(512) void k_cvt8(const float* __restrict__ ctx, const short* __restrict__ Wb,
                                              int wstride, unsigned char* __restrict__ out8) {
    const int tid = threadIdx.x, w = tid >> 6, l = tid & 63;
    const int m0 = blockIdx.y * 128, n0 = blockIdx.x * 64;
    const int kc8 = (l >> 4) * 8;
    const int m = m0 + w * 16 + (l & 15);
    const int b = m >> 8, s = m & 255;
    const float* arow = ctx + ((size_t)s * BB + b) * HH + kc8;
    f32x4 acc[4];
    const f32x4 zero = {0.f, 0.f, 0.f, 0.f};
#pragma unroll
    for (int j = 0; j < 4; ++j) acc[j] = zero;
#pragma unroll
    for (int kc = 0; kc < 16; ++kc) {
        const int k0 = kc * 32;
        float4 x0 = *reinterpret_cast<const float4*>(arow + k0);
        float4 x1 = *reinterpret_cast<const float4*>(arow + k0 + 4);
        s16x8 afr;
        afr[0] = f2b(x0.x); afr[1] = f2b(x0.y); afr[2] = f2b(x0.z); afr[3] = f2b(x0.w);
        afr[4] = f2b(x1.x); afr[5] = f2b(x1.y); afr[6] = f2b(x1.z); afr[7] = f2b(x1.w);
#pragma unroll
        for (int j = 0; j < 4; ++j) {
            s16x8 bfr = *reinterpret_cast<const s16x8*>(Wb + (size_t)(n0 + j * 16 + (l & 15)) * wstride + k0 + kc8);
            acc[j] = __builtin_amdgcn_mfma_f32_16x16x32_bf16(afr, bfr, acc[j], 0, 0, 0);
        }
    }
#pragma unroll
    for (int j = 0; j < 4; ++j)
#pragma unroll
        for (int r = 0; r < 4; ++r)
            out8[(size_t)(m0 + w * 16 + (l >> 4) * 4 + r) * HH + (n0 + j * 16 + (l & 15))] =
                (unsigned char)(__builtin_amdgcn_cvt_pk_fp8_f32(acc[j][r], 0.f, 0, false) & 0xff);
}

__global__ void k_state(const float* __restrict__ h0in, const float* __restrict__ iout,
                        short* __restrict__ h0x, short* __restrict__ h1x, short* __restrict__ outx) {
    int i = blockIdx.x * blockDim.x + threadIdx.x;
    if (i < BH) {
        h0x[i] = f2b(h0in[i]);
        h1x[i] = f2b(h0in[BH + i]);
        outx[i] = f2b(iout[i]);
    }
}

// ---------------- persistent cooperative kernel ----------------

struct P {
    const short* Ebf;
    const float* c0in;
    const unsigned char* ctxW8;   // scores source
    const unsigned char* ctxO8;   // PV-in-output-space source (ctx @ WoutL^T)
    const unsigned* WRP;          // packed Wout right half, [256m][512j]
    const short* W0cat;
    const short* W1cat;
    const float* bias0;
    const float* bias1;
    short* h0x;
    short* h1x;
    short* outx;
    float* dout;
    unsigned* flags;
};

#define MFMA16(a, b, c) __builtin_amdgcn_mfma_f32_16x16x32_bf16((a), (b), (c), 0, 0, 0)

__device__ __forceinline__ s16x8 ldsfrag(const short* base, int stride, int row, int col8) {
    return *reinterpret_cast<const s16x8*>(base + row * stride + ((col8 ^ (row & 7)) << 3));
}

__device__ __forceinline__ void issue8(const short* __restrict__ src, int tid, int khalf, s16x8* q) {
#pragma unroll
    for (int c = 0; c < 8; ++c) {
        const int chunk = c * 512 + tid;
        const int row = chunk >> 5, col8 = chunk & 31;
        q[c] = ald16(src + row * HH + khalf * 256 + col8 * 8);
    }
}
// counted-vmcnt staged write: waits only until <=N of *our* asm loads remain
template <int N>
__device__ __forceinline__ void write8n(short* __restrict__ stg, int tid, const s16x8* q) {
    asm volatile("s_waitcnt vmcnt(%0)" ::"i"(N) : "memory");
#pragma unroll
    for (int c = 0; c < 8; ++c) {
        const int chunk = c * 512 + tid;
        const int row = chunk >> 5, col8 = chunk & 31;
        *reinterpret_cast<s16x8*>(stg + row * 256 + ((col8 ^ (row & 7)) << 3)) = q[c];
    }
}

__device__ __forceinline__ f32x4 seg8(const short* stgp, const short* Ws, int wstride, int wbase,
                                      int mrow, int wrow, int kq, f32x4 acc) {
#pragma unroll
    for (int seg = 0; seg < 8; ++seg)
        acc = MFMA16(ldsfrag(stgp, 256, mrow, seg * 4 + kq),
                     ldsfrag(Ws, wstride, wrow, wbase + seg * 4 + kq), acc);
    return acc;
}

// full grid barrier (drains vmcnt — exchange stores must be LLC-visible)
__device__ __forceinline__ void gbar(unsigned* flags, unsigned target) {
    asm volatile("s_waitcnt vmcnt(0)" ::: "memory");
    __syncthreads();
    if (threadIdx.x == 0)
        __hip_atomic_store(&flags[blockIdx.x], target, __ATOMIC_RELAXED, __HIP_MEMORY_SCOPE_AGENT);
    if (threadIdx.x < NBLK) {
        while (__hip_atomic_load(&flags[threadIdx.x], __ATOMIC_RELAXED, __HIP_MEMORY_SCOPE_AGENT) < target)
            __builtin_amdgcn_s_sleep(1);
    }
    __syncthreads();
}

__global__ void __launch_bounds__(NTHR, 1) coop_k(P p) {
    extern __shared__ __align__(16) char smem[];
    short* W0s = (short*)smem;            // 16 x 1536 sw
    short* W1s = W0s + 16 * 1536;         // 16 x 1024 sw
    short* stg = W1s + 16 * 1024;         // 128 x 256 sw stage / scratch
    float* smallf = (float*)(stg + 128 * 256);
    float* bias0s = smallf;               // 16
    float* bias1s = smallf + 16;          // 16
    float* red = smallf + 32;             // 16
    float* scv = smallf + 48;             // 256
    float* aU = smallf + 304;             // 256
    float* h1f = smallf + 560;            // 512

    const int tid = threadIdx.x;
    const int blk = blockIdx.x;
    const int l = tid & 63;
    const int w = tid >> 6;
    const int lrow = l & 15;
    const int mrow = w * 16 + lrow;
    const int kq = l >> 4;
    const size_t OFF_HF = (size_t)TT * BH;
    const size_t OFF_CF = OFF_HF + 2 * (size_t)BH;
    const size_t OFF_AT = OFF_CF + 2 * (size_t)BH;
    const f32x4 fz = {0.f, 0.f, 0.f, 0.f};

    // --- prologue ---
    for (int idx = tid; idx < 16 * 192; idx += NTHR) {
        int row = idx / 192, col8 = idx % 192;
        int g = (row & 3) * 512 + blk * 4 + (row >> 2);
        *reinterpret_cast<s16x8*>(W0s + row * 1536 + ((col8 ^ (row & 7)) << 3)) =
            *reinterpret_cast<const s16x8*>(p.W0cat + (size_t)g * 1536 + col8 * 8);
    }
    for (int idx = tid; idx < 16 * 128; idx += NTHR) {
        int row = idx / 128, col8 = idx % 128;
        int g = (row & 3) * 512 + blk * 4 + (row >> 2);
        *reinterpret_cast<s16x8*>(W1s + row * 1024 + ((col8 ^ (row & 7)) << 3)) =
            *reinterpret_cast<const s16x8*>(p.W1cat + (size_t)g * 1024 + col8 * 8);
    }
    if (tid < 16) {
        int g = (tid & 3) * 512 + blk * 4 + (tid >> 2);
        bias0s[tid] = p.bias0[g];
        bias1s[tid] = p.bias1[g];
    }
    __syncthreads();

    const int bA = tid >> 2;
    const int jA = blk * 4 + (tid & 3);
    float c0reg = p.c0in[bA * HH + jA];
    float c1reg = p.c0in[BH + bA * HH + jA];
    unsigned ep = 0;
    s16x8 qa[8], qb[8], qc[8], qd[8];

    for (int t = 0; t < TT; ++t) {
        const size_t pB = (size_t)(t & 1) * BH;
        const size_t pN = (size_t)((t & 1) ^ 1) * BH;

        // ================= Phase A: layer-0 gates + cell =================
        {
            issue8(p.outx + pB, tid, 0, qa);
            issue8(p.outx + pB, tid, 1, qb);
            f32x4 aE = fz, aO = fz, aH = fz;
            {
                const short* erow = p.Ebf + ((size_t)t * BB + mrow) * EE + kq * 8;
#pragma unroll
                for (int seg = 0; seg < 16; ++seg) {
                    s16x8 afr = *reinterpret_cast<const s16x8*>(erow + seg * 32);
                    aE = MFMA16(afr, ldsfrag(W0s, 1536, lrow, seg * 4 + kq), aE);
                }
            }
            write8n<8>(stg, tid, qa);
            issue8(p.h0x + pB, tid, 0, qc);
            lbar();
            aO = seg8(stg, W0s, 1536, 64, mrow, lrow, kq, aO);
            lbar();
            write8n<8>(stg, tid, qb);
            issue8(p.h0x + pB, tid, 1, qd);
            lbar();
            aO = seg8(stg, W0s, 1536, 96, mrow, lrow, kq, aO);
            lbar();
            write8n<8>(stg, tid, qc);
            lbar();
            aH = seg8(stg, W0s, 1536, 128, mrow, lrow, kq, aH);
            lbar();
            write8n<0>(stg, tid, qd);
            lbar();
            aH = seg8(stg, W0s, 1536, 160, mrow, lrow, kq, aH);

            f32x4 acc = aE + aO + aH;
            lbar();
            float* scr = (float*)stg + w * 272;
#pragma unroll
            for (int r = 0; r < 4; ++r) scr[lrow * 17 + kq * 4 + r] = acc[r];
            const int bloc = l >> 2;
            const int n0 = (l & 3) * 4;
            float gi = scr[(n0 + 0) * 17 + bloc] + bias0s[n0 + 0];
            float gf = scr[(n0 + 1) * 17 + bloc] + bias0s[n0 + 1];
            float gg = scr[(n0 + 2) * 17 + bloc] + bias0s[n0 + 2];
            float go = scr[(n0 + 3) * 17 + bloc] + bias0s[n0 + 3];
            float cn = sigm(gf) * c0reg + sigm(gi) * tanhf(gg);
            float hn = sigm(go) * tanhf(cn);
            c0reg = cn;
            ast2(&p.h0x[pN + bA * HH + jA], f2b(hn));
            if (t == TT - 1) {
                p.dout[OFF_HF + bA * HH + jA] = hn;
                p.dout[OFF_CF + bA * HH + jA] = cn;
            }
        }
        gbar(p.flags, ++ep);

        // ================= Phase B: layer-1 gates + cell =================
        {
            issue8(p.h0x + pN, tid, 0, qa);
            issue8(p.h0x + pN, tid, 1, qb);
            f32x4 b0 = fz, b1 = fz;
            write8n<8>(stg, tid, qa);
            issue8(p.h1x + pB, tid, 0, qc);
            lbar();
            b0 = seg8(stg, W1s, 1024, 0, mrow, lrow, kq, b0);
            lbar();
            write8n<8>(stg, tid, qb);
            issue8(p.h1x + pB, tid, 1, qd);
            lbar();
            b0 = seg8(stg, W1s, 1024, 32, mrow, lrow, kq, b0);
            lbar();
            write8n<8>(stg, tid, qc);
            lbar();
            b1 = seg8(stg, W1s, 1024, 64, mrow, lrow, kq, b1);
            lbar();
            write8n<0>(stg, tid, qd);
            lbar();
            b1 = seg8(stg, W1s, 1024, 96, mrow, lrow, kq, b1);

            f32x4 acc = b0 + b1;
            lbar();
            float* scr = (float*)stg + w * 272;
#pragma unroll
            for (int r = 0; r < 4; ++r) scr[lrow * 17 + kq * 4 + r] = acc[r];
            const int bloc = l >> 2;
            const int n0 = (l & 3) * 4;
            float gi = scr[(n0 + 0) * 17 + bloc] + bias1s[n0 + 0];
            float gf = scr[(n0 + 1) * 17 + bloc] + bias1s[n0 + 1];
            float gg = scr[(n0 + 2) * 17 + bloc] + bias1s[n0 + 2];
            float go = scr[(n0 + 3) * 17 + bloc] + bias1s[n0 + 3];
            float cn = sigm(gf) * c1reg + sigm(gi) * tanhf(gg);
            float hn = sigm(go) * tanhf(cn);
            c1reg = cn;
            ast2(&p.h1x[pN + bA * HH + jA], f2b(hn));
            if (t == TT - 1) {
                p.dout[OFF_HF + BH + bA * HH + jA] = hn;
                p.dout[OFF_CF + BH + bA * HH + jA] = cn;
            }
        }
        gbar(p.flags, ++ep);

        // ===== Phase C: attention + fused output row for batch b = blk =====
        {
            float* pF = (float*)stg;        // 8 x 512 f32 partials (16KB)
            if (tid < 128) {
                union { u64 v; short s[4]; } c;
                c.v = aldq(p.h1x + pN + blk * HH + tid * 4);
#pragma unroll
                for (int j = 0; j < 4; ++j) h1f[tid * 4 + j] = b2f(c.s[j]);
            }
            lbar();
            float hreg[8];
#pragma unroll
            for (int j = 0; j < 8; ++j) hreg[j] = h1f[l * 8 + j];
            // scores
            const unsigned char* cwb = p.ctxW8 + (size_t)blk * SS * HH;
#pragma unroll 4
            for (int it = 0; it < 32; ++it) {
                const int s = it * 8 + w;
                u64 q = *reinterpret_cast<const u64*>(cwb + (size_t)s * HH + l * 8);
                float o[8];
                f8x8(q, o);
                float pd = 0.f;
#pragma unroll
                for (int j = 0; j < 8; ++j) pd += o[j] * hreg[j];
#pragma unroll
                for (int off = 32; off; off >>= 1) pd += __shfl_xor(pd, off);
                if (l == 0) scv[s] = pd;
            }
            lbar();
            float sc = -1e30f, e = 0.f;
            if (tid < 256) sc = scv[tid];
            float mx = sc;
#pragma unroll
            for (int off = 32; off; off >>= 1) mx = fmaxf(mx, __shfl_xor(mx, off));
            if (l == 0 && tid < 256) red[w] = mx;
            lbar();
            const float M = fmaxf(fmaxf(red[0], red[1]), fmaxf(red[2], red[3]));
            if (tid < 256) { e = __expf(sc - M); aU[tid] = e; }
            float se = e;
#pragma unroll
            for (int off = 32; off; off >>= 1) se += __shfl_xor(se, off);
            if (l == 0 && tid < 256) red[8 + w] = se;
            lbar();
            const float inv = 1.f / (red[8] + red[9] + red[10] + red[11]);
            if (t == TT - 1 && tid < 256) p.dout[OFF_AT + blk * SS + tid] = aU[tid] * inv;
            // PV in output space: opre = sum_s a_s * ctxO[b,s,:]
            const unsigned char* cob = p.ctxO8 + (size_t)blk * SS * HH;
            float wa[8];
#pragma unroll
            for (int j = 0; j < 8; ++j) wa[j] = 0.f;
#pragma unroll 4
            for (int it = 0; it < 32; ++it) {
                const int s = it * 8 + w;
                const float av = aU[s];
                u64 q = *reinterpret_cast<const u64*>(cob + (size_t)s * HH + l * 8);
                float o[8];
                f8x8(q, o);
#pragma unroll
                for (int j = 0; j < 8; ++j) wa[j] += av * o[j];
            }
            {
                float4* dst = reinterpret_cast<float4*>(pF + w * 512 + l * 8);
                float4 v0 = {wa[0], wa[1], wa[2], wa[3]};
                float4 v1 = {wa[4], wa[5], wa[6], wa[7]};
                dst[0] = v0;
                dst[1] = v1;
            }
            lbar();
            // combine: out[blk, tid] = tanh( PV*inv + h1 . WoutR[tid] )
            {
                float opv = 0.f;
#pragma unroll
                for (int ww = 0; ww < 8; ++ww) opv += pF[ww * 512 + tid];
                opv *= inv;
                const unsigned* wp = p.WRP + tid;
                float g = 0.f;
#pragma unroll 8
                for (int m = 0; m < 256; ++m) {
                    unsigned wv = wp[(size_t)m * 512];
                    g += b2f((short)(wv & 0xffff)) * h1f[2 * m] + b2f((short)(wv >> 16)) * h1f[2 * m + 1];
                }
                float tv = tanhf(opv + g);
                __builtin_nontemporal_store(tv, &p.dout[(size_t)t * BH + blk * HH + tid]);
                ast2(&p.outx[pN + blk * HH + tid], f2b(tv));
            }
        }
        gbar(p.flags, ++ep);
    }
}

// ---------------- host ----------------

extern "C" void kernel_launch(void* const* d_in, const int* in_sizes, int n_in,
                              void* d_out, int out_size, void* d_ws, size_t ws_size,
                              hipStream_t stream) {
    const int* tokens = (const int*)d_in[0];
    const float* h0in = (const float*)d_in[1];
    const float* c0in = (const float*)d_in[2];
    const float* ctx = (const float*)d_in[3];
    const float* iout = (const float*)d_in[4];
    const float* emb = (const float*)d_in[5];
    const float* Wih0 = (const float*)d_in[6];
    const float* bih0 = (const float*)d_in[7];
    const float* Whh0 = (const float*)d_in[8];
    const float* bhh0 = (const float*)d_in[9];
    const float* Wih1 = (const float*)d_in[10];
    const float* bih1 = (const float*)d_in[11];
    const float* Whh1 = (const float*)d_in[12];
    const float* bhh1 = (const float*)d_in[13];
    const float* Win = (const float*)d_in[14];
    const float* Wout = (const float*)d_in[15];
    float* dout = (float*)d_out;

    char* pw = (char*)d_ws;
    auto take = [&](size_t bytes) { char* r = pw; pw += (bytes + 255) & ~(size_t)255; return r; };
    short* W0cat = (short*)take((size_t)2048 * 1536 * 2);
    short* W1cat = (short*)take((size_t)2048 * 1024 * 2);
    short* Winb  = (short*)take((size_t)512 * 512 * 2);
    short* Woutb = (short*)take((size_t)512 * 1024 * 2);
    unsigned* WRP = (unsigned*)take((size_t)256 * 512 * 4);
    float* bias0 = (float*)take(2048 * 4);
    float* bias1 = (float*)take(2048 * 4);
    short* Ebf   = (short*)take((size_t)TT * BB * EE * 2);
    unsigned char* ctxW8 = (unsigned char*)take((size_t)BB * SS * HH);
    unsigned char* ctxO8 = (unsigned char*)take((size_t)BB * SS * HH);
    short* h0x   = (short*)take((size_t)2 * BH * 2);
    short* h1x   = (short*)take((size_t)2 * BH * 2);
    short* outx  = (short*)take((size_t)2 * BH * 2);
    unsigned* flags = (unsigned*)take(NBLK * 4);

    k_pack2<<<2048, 256, 0, stream>>>(Wih0, 1024, Whh0, 512, W0cat, 2048 * 1536);
    k_pack2<<<2048, 256, 0, stream>>>(Wih1, 512, Whh1, 512, W1cat, 2048 * 1024);
    k_pack2<<<1024, 256, 0, stream>>>(Win, 512, Win, 0, Winb, 512 * 512);
    k_pack2<<<1024, 256, 0, stream>>>(Wout, 1024, Wout, 0, Woutb, 512 * 1024);
    k_packwr<<<512, 256, 0, stream>>>(Wout, WRP);
    k_bias<<<8, 256, 0, stream>>>(bih0, bhh0, bias0, bih1, bhh1, bias1);
    k_emb<<<4096, 256, 0, stream>>>(tokens, emb, Ebf);
    k_state<<<256, 256, 0, stream>>>(h0in, iout, h0x, h1x, outx);
    k_cvt8<<<dim3(8, 256), 512, 0, stream>>>(ctx, Winb, 512, ctxW8);
    k_cvt8<<<dim3(8, 256), 512, 0, stream>>>(ctx, Woutb, 1024, ctxO8);
    (void)hipMemsetAsync(flags, 0, NBLK * 4, stream);

    const unsigned smem_bytes = (16 * 1536 + 16 * 1024 + 128 * 256) * 2 + (16 + 16 + 16 + 256 + 256 + 512) * 4;
    (void)hipFuncSetAttribute((const void*)coop_k, hipFuncAttributeMaxDynamicSharedMemorySize, (int)smem_bytes);

    P prm;
    prm.Ebf = Ebf; prm.c0in = c0in;
    prm.ctxW8 = ctxW8; prm.ctxO8 = ctxO8; prm.WRP = WRP;
    prm.W0cat = W0cat; prm.W1cat = W1cat;
    prm.bias0 = bias0; prm.bias1 = bias1;
    prm.h0x = h0x; prm.h1x = h1x; prm.outx = outx;
    prm.dout = dout; prm.flags = flags;
    void* args[] = {&prm};
    (void)hipLaunchCooperativeKernel((void*)coop_k, dim3(NBLK), dim3(NTHR), args, smem_bytes, stream);
}

// Round 10
// 14583.870 us; speedup vs baseline: 2.6372x; 1.0147x over previous
//
#include <hip/hip_runtime.h>
#include <hip/hip_bf16.h>
#include <math.h>

#define TT 256
#define BB 128
#define SS 256
#define HH 512
#define EE 512
#define NBLK 128
#define NTHR 512
#define BH (BB * HH)

typedef __attribute__((ext_vector_type(4))) float f32x4;
typedef __attribute__((ext_vector_type(8))) short s16x8;
typedef unsigned long long u64;

__device__ __forceinline__ float b2f(short v) {
    union { unsigned u; float f; } c;
    c.u = ((unsigned)(unsigned short)v) << 16;
    return c.f;
}
__device__ __forceinline__ short f2b(float f) {
    union { float f; unsigned u; } c; c.f = f;
    unsigned u = c.u;
    unsigned r = (u + 0x7fffu + ((u >> 16) & 1u)) >> 16;
    return (short)r;
}
__device__ __forceinline__ float sigm(float x) { return 1.f / (1.f + __expf(-x)); }

// agent-scope (LLC-coherent, cache-bypassing) exchange primitives
__device__ __forceinline__ u64 aldq(const void* p) {
    return __hip_atomic_load((const u64*)p, __ATOMIC_RELAXED, __HIP_MEMORY_SCOPE_AGENT);
}
__device__ __forceinline__ void ast2(short* p, short v) {
    __hip_atomic_store(p, v, __ATOMIC_RELAXED, __HIP_MEMORY_SCOPE_AGENT);
}
__device__ __forceinline__ s16x8 ald16(const void* p) {
    s16x8 r;
    asm volatile("global_load_dwordx4 %0, %1, off sc0 sc1" : "=v"(r) : "v"(p) : "memory");
    return r;
}

// LDS-only barrier: does NOT drain vmcnt
__device__ __forceinline__ void lbar() {
    asm volatile("s_waitcnt lgkmcnt(0)" ::: "memory");
    __builtin_amdgcn_s_barrier();
}

// ---------------- prep kernels ----------------

__global__ void k_pack2(const float* __restrict__ Wa, int ka, const float* __restrict__ Wb, int kb,
                        short* __restrict__ dst, int n) {
    const int K = ka + kb;
    for (int i = blockIdx.x * blockDim.x + threadIdx.x; i < n; i += gridDim.x * blockDim.x) {
        int g = i / K, k = i - g * K;
        float v = (k < ka) ? Wa[(size_t)g * ka + k] : Wb[(size_t)g * kb + (k - ka)];
        dst[i] = f2b(v);
    }
}

__global__ void k_bias(const float* __restrict__ a, const float* __restrict__ b, float* __restrict__ o,
                       const float* __restrict__ a2, const float* __restrict__ b2, float* __restrict__ o2) {
    int i = blockIdx.x * blockDim.x + threadIdx.x;
    if (i < 2048) { o[i] = a[i] + b[i]; o2[i] = a2[i] + b2[i]; }
}

__global__ void k_emb(const int* __restrict__ tok, const float* __restrict__ emb, short* __restrict__ Ebf) {
    const int n = TT * BB * EE;
    for (int i = blockIdx.x * blockDim.x + threadIdx.x; i < n; i += gridDim.x * blockDim.x) {
        int tb = i >> 9, k = i & 511;
        int t = tok[tb];
        Ebf[i] = f2b(emb[(size_t)t * EE + k]);
    }
}

// out8 = fp8( ctx[s,b,:] @ Wb[n,:]^T );  transpose=0: [(b,s), n];  transpose=1: [(b,n), s]
__global__ __launch_bounds__(512) void k_cvt8(const float* __restrict__ ctx, const short* __restrict__ Wb,
                                              int wstride, int transpose, unsigned char* __restrict__ out8) {
    const int tid = threadIdx.x, w = tid >> 6, l = tid & 63;
    const int m0 = blockIdx.y * 128, n0 = blockIdx.x * 64;
    const int kc8 = (l >> 4) * 8;
    const int m = m0 + w * 16 + (l & 15);
    const int b = m >> 8, s = m & 255;
    const float* arow = ctx + ((size_t)s * BB + b) * HH + kc8;
    f32x4 acc[4];
    const f32x4 zero = {0.f, 0.f, 0.f, 0.f};
#pragma unroll
    for (int j = 0; j < 4; ++j) acc[j] = zero;
#pragma unroll
    for (int kc = 0; kc < 16; ++kc) {
        const int k0 = kc * 32;
        float4 x0 = *reinterpret_cast<const float4*>(arow + k0);
        float4 x1 = *reinterpret_cast<const float4*>(arow + k0 + 4);
        s16x8 afr;
        afr[0] = f2b(x0.x); afr[1] = f2b(x0.y); afr[2] = f2b(x0.z); afr[3] = f2b(x0.w);
        afr[4] = f2b(x1.x); afr[5] = f2b(x1.y); afr[6] = f2b(x1.z); afr[7] = f2b(x1.w);
#pragma unroll
        for (int j = 0; j < 4; ++j) {
            s16x8 bfr = *reinterpret_cast<const s16x8*>(Wb + (size_t)(n0 + j * 16 + (l & 15)) * wstride + k0 + kc8);
            acc[j] = __builtin_amdgcn_mfma_f32_16x16x32_bf16(afr, bfr, acc[j], 0, 0, 0);
        }
    }
#pragma unroll
    for (int j = 0; j < 4; ++j)
#pragma unroll
        for (int r = 0; r < 4; ++r) {
            const int mm = m0 + w * 16 + (l >> 4) * 4 + r;
            const int nn = n0 + j * 16 + (l & 15);
            unsigned char v8 = (unsigned char)(__builtin_amdgcn_cvt_pk_fp8_f32(acc[j][r], 0.f, 0, false) & 0xff);
            if (transpose) {
                const int bb = mm >> 8, ss = mm & 255;
                out8[((size_t)bb * HH + nn) * SS + ss] = v8;
            } else {
                out8[(size_t)mm * HH + nn] = v8;
            }
        }
}

__global__ void k_state(const float* __restrict__ h0in, const float* __restrict__ iout,
                        short* __restrict__ h0x, short* __restrict__ h1x, short* __restrict__ outx) {
    int i = blockIdx.x * blockDim.x + threadIdx.x;
    if (i < BH) {
        h0x[i] = f2b(h0in[i]);
        h1x[i] = f2b(h0in[BH + i]);
        outx[i] = f2b(iout[i]);
    }
}

// ---------------- persistent cooperative kernel ----------------

struct P {
    const short* Ebf;
    const float* c0in;
    const unsigned char* ctxW8;   // [(b,s), n] fp8: scores source
    const unsigned char* ctxO8T;  // [(b,h'), s] fp8: PV-in-output-space, transposed
    const short* Woutb;           // bf16 [j][1024]
    const short* W0cat;
    const short* W1cat;
    const float* bias0;
    const float* bias1;
    short* h0x;
    short* h1x;
    short* outx;
    float* dout;
    unsigned* flags;
};

#define MFMA16(a, b, c) __builtin_amdgcn_mfma_f32_16x16x32_bf16((a), (b), (c), 0, 0, 0)
#define MFMA8(a, b, c) __builtin_amdgcn_mfma_f32_16x16x32_fp8_fp8((a), (b), (c), 0, 0, 0)

__device__ __forceinline__ s16x8 ldsfrag(const short* base, int stride, int row, int col8) {
    return *reinterpret_cast<const s16x8*>(base + row * stride + ((col8 ^ (row & 7)) << 3));
}

__device__ __forceinline__ void issue8(const short* __restrict__ src, int tid, int khalf, s16x8* q) {
#pragma unroll
    for (int c = 0; c < 8; ++c) {
        const int chunk = c * 512 + tid;
        const int row = chunk >> 5, col8 = chunk & 31;
        q[c] = ald16(src + row * HH + khalf * 256 + col8 * 8);
    }
}
template <int N>
__device__ __forceinline__ void write8n(short* __restrict__ stg, int tid, const s16x8* q) {
    asm volatile("s_waitcnt vmcnt(%0)" ::"i"(N) : "memory");
#pragma unroll
    for (int c = 0; c < 8; ++c) {
        const int chunk = c * 512 + tid;
        const int row = chunk >> 5, col8 = chunk & 31;
        *reinterpret_cast<s16x8*>(stg + row * 256 + ((col8 ^ (row & 7)) << 3)) = q[c];
    }
}

__device__ __forceinline__ f32x4 seg8(const short* stgp, const short* Ws, int wstride, int wbase,
                                      int mrow, int wrow, int kq, f32x4 acc) {
#pragma unroll
    for (int seg = 0; seg < 8; ++seg)
        acc = MFMA16(ldsfrag(stgp, 256, mrow, seg * 4 + kq),
                     ldsfrag(Ws, wstride, wrow, wbase + seg * 4 + kq), acc);
    return acc;
}

// full grid barrier (drains vmcnt — exchange stores must be LLC-visible)
__device__ __forceinline__ void gbar(unsigned* flags, unsigned target) {
    asm volatile("s_waitcnt vmcnt(0)" ::: "memory");
    __syncthreads();
    if (threadIdx.x == 0)
        __hip_atomic_store(&flags[blockIdx.x], target, __ATOMIC_RELAXED, __HIP_MEMORY_SCOPE_AGENT);
    if (threadIdx.x < NBLK) {
        while (__hip_atomic_load(&flags[threadIdx.x], __ATOMIC_RELAXED, __HIP_MEMORY_SCOPE_AGENT) < target)
            __builtin_amdgcn_s_sleep(1);
    }
    __syncthreads();
}

__global__ void __launch_bounds__(NTHR, 1) coop_k(P p) {
    extern __shared__ __align__(16) char smem[];
    short* W0s = (short*)smem;            // 16 x 1536 sw
    short* W1s = W0s + 16 * 1536;         // 16 x 1024 sw
    short* stg = W1s + 16 * 1024;         // 128 x 256 sw stage / scratch
    float* smallf = (float*)(stg + 128 * 256);
    float* bias0s = smallf;               // 16
    float* bias1s = smallf + 16;          // 16
    float* red = smallf + 32;             // 16
    float* scv = smallf + 48;             // 256
    float* aU = smallf + 304;             // 256
    short* h1b = (short*)(smallf + 560);  // 512 bf16
    unsigned* h18u = (unsigned*)(smallf + 816);  // 512 fp8 (128 u32, 8B aligned)
    unsigned* a32 = (unsigned*)(smallf + 944);   // 256 fp8 (64 u32, 8B aligned)

    const int tid = threadIdx.x;
    const int blk = blockIdx.x;
    const int l = tid & 63;
    const int w = tid >> 6;
    const int lrow = l & 15;
    const int mrow = w * 16 + lrow;
    const int kq = l >> 4;
    const size_t OFF_HF = (size_t)TT * BH;
    const size_t OFF_CF = OFF_HF + 2 * (size_t)BH;
    const size_t OFF_AT = OFF_CF + 2 * (size_t)BH;
    const f32x4 fz = {0.f, 0.f, 0.f, 0.f};

    // --- prologue ---
    for (int idx = tid; idx < 16 * 192; idx += NTHR) {
        int row = idx / 192, col8 = idx % 192;
        int g = (row & 3) * 512 + blk * 4 + (row >> 2);
        *reinterpret_cast<s16x8*>(W0s + row * 1536 + ((col8 ^ (row & 7)) << 3)) =
            *reinterpret_cast<const s16x8*>(p.W0cat + (size_t)g * 1536 + col8 * 8);
    }
    for (int idx = tid; idx < 16 * 128; idx += NTHR) {
        int row = idx / 128, col8 = idx % 128;
        int g = (row & 3) * 512 + blk * 4 + (row >> 2);
        *reinterpret_cast<s16x8*>(W1s + row * 1024 + ((col8 ^ (row & 7)) << 3)) =
            *reinterpret_cast<const s16x8*>(p.W1cat + (size_t)g * 1024 + col8 * 8);
    }
    if (tid < 16) {
        int g = (tid & 3) * 512 + blk * 4 + (tid >> 2);
        bias0s[tid] = p.bias0[g];
        bias1s[tid] = p.bias1[g];
    }
    __syncthreads();

    const int bA = tid >> 2;
    const int jA = blk * 4 + (tid & 3);
    float c0reg = p.c0in[bA * HH + jA];
    float c1reg = p.c0in[BH + bA * HH + jA];
    unsigned ep = 0;
    s16x8 qa[8], qb[8], qc[8], qd[8];

    for (int t = 0; t < TT; ++t) {
        const size_t pB = (size_t)(t & 1) * BH;
        const size_t pN = (size_t)((t & 1) ^ 1) * BH;

        // ================= Phase A: layer-0 gates + cell =================
        {
            issue8(p.outx + pB, tid, 0, qa);
            issue8(p.outx + pB, tid, 1, qb);
            f32x4 aE = fz, aO = fz, aH = fz;
            {
                const short* erow = p.Ebf + ((size_t)t * BB + mrow) * EE + kq * 8;
#pragma unroll
                for (int seg = 0; seg < 16; ++seg) {
                    s16x8 afr = *reinterpret_cast<const s16x8*>(erow + seg * 32);
                    aE = MFMA16(afr, ldsfrag(W0s, 1536, lrow, seg * 4 + kq), aE);
                }
            }
            write8n<8>(stg, tid, qa);
            issue8(p.h0x + pB, tid, 0, qc);
            lbar();
            aO = seg8(stg, W0s, 1536, 64, mrow, lrow, kq, aO);
            lbar();
            write8n<8>(stg, tid, qb);
            issue8(p.h0x + pB, tid, 1, qd);
            lbar();
            aO = seg8(stg, W0s, 1536, 96, mrow, lrow, kq, aO);
            lbar();
            write8n<8>(stg, tid, qc);
            lbar();
            aH = seg8(stg, W0s, 1536, 128, mrow, lrow, kq, aH);
            lbar();
            write8n<0>(stg, tid, qd);
            lbar();
            aH = seg8(stg, W0s, 1536, 160, mrow, lrow, kq, aH);

            f32x4 acc = aE + aO + aH;
            lbar();
            float* scr = (float*)stg + w * 272;
#pragma unroll
            for (int r = 0; r < 4; ++r) scr[lrow * 17 + kq * 4 + r] = acc[r];
            const int bloc = l >> 2;
            const int n0 = (l & 3) * 4;
            float gi = scr[(n0 + 0) * 17 + bloc] + bias0s[n0 + 0];
            float gf = scr[(n0 + 1) * 17 + bloc] + bias0s[n0 + 1];
            float gg = scr[(n0 + 2) * 17 + bloc] + bias0s[n0 + 2];
            float go = scr[(n0 + 3) * 17 + bloc] + bias0s[n0 + 3];
            float cn = sigm(gf) * c0reg + sigm(gi) * tanhf(gg);
            float hn = sigm(go) * tanhf(cn);
            c0reg = cn;
            ast2(&p.h0x[pN + bA * HH + jA], f2b(hn));
            if (t == TT - 1) {
                p.dout[OFF_HF + bA * HH + jA] = hn;
                p.dout[OFF_CF + bA * HH + jA] = cn;
            }
        }
        gbar(p.flags, ++ep);

        // ================= Phase B: layer-1 gates + cell =================
        {
            issue8(p.h0x + pN, tid, 0, qa);
            issue8(p.h0x + pN, tid, 1, qb);
            f32x4 b0 = fz, b1 = fz;
            write8n<8>(stg, tid, qa);
            issue8(p.h1x + pB, tid, 0, qc);
            lbar();
            b0 = seg8(stg, W1s, 1024, 0, mrow, lrow, kq, b0);
            lbar();
            write8n<8>(stg, tid, qb);
            issue8(p.h1x + pB, tid, 1, qd);
            lbar();
            b0 = seg8(stg, W1s, 1024, 32, mrow, lrow, kq, b0);
            lbar();
            write8n<8>(stg, tid, qc);
            lbar();
            b1 = seg8(stg, W1s, 1024, 64, mrow, lrow, kq, b1);
            lbar();
            write8n<0>(stg, tid, qd);
            lbar();
            b1 = seg8(stg, W1s, 1024, 96, mrow, lrow, kq, b1);

            f32x4 acc = b0 + b1;
            lbar();
            float* scr = (float*)stg + w * 272;
#pragma unroll
            for (int r = 0; r < 4; ++r) scr[lrow * 17 + kq * 4 + r] = acc[r];
            const int bloc = l >> 2;
            const int n0 = (l & 3) * 4;
            float gi = scr[(n0 + 0) * 17 + bloc] + bias1s[n0 + 0];
            float gf = scr[(n0 + 1) * 17 + bloc] + bias1s[n0 + 1];
            float gg = scr[(n0 + 2) * 17 + bloc] + bias1s[n0 + 2];
            float go = scr[(n0 + 3) * 17 + bloc] + bias1s[n0 + 3];
            float cn = sigm(gf) * c1reg + sigm(gi) * tanhf(gg);
            float hn = sigm(go) * tanhf(cn);
            c1reg = cn;
            ast2(&p.h1x[pN + bA * HH + jA], f2b(hn));
            if (t == TT - 1) {
                p.dout[OFF_HF + BH + bA * HH + jA] = hn;
                p.dout[OFF_CF + BH + bA * HH + jA] = cn;
            }
        }
        gbar(p.flags, ++ep);

        // ===== Phase C: attention + fused output row for batch b = blk (all-MFMA) =====
        {
            float* pFh = (float*)stg;   // 512 floats: PV result in output space
            // stage h1 row -> bf16 LDS copy + fp8 LDS copy
            if (tid < 128) {
                union { u64 v; short s[4]; } c;
                c.v = aldq(p.h1x + pN + blk * HH + tid * 4);
#pragma unroll
                for (int j = 0; j < 4; ++j) h1b[tid * 4 + j] = c.s[j];
                float f0 = b2f(c.s[0]), f1 = b2f(c.s[1]), f2 = b2f(c.s[2]), f3 = b2f(c.s[3]);
                unsigned lo = __builtin_amdgcn_cvt_pk_fp8_f32(f0, f1, 0, false) & 0xffffu;
                unsigned hi = __builtin_amdgcn_cvt_pk_fp8_f32(f2, f3, 0, false) & 0xffffu;
                h18u[tid] = lo | (hi << 16);
            }
            lbar();
            // scores via fp8 MFMA: B = ctxW8 rows (16 s/tile), A = h1 fp8 broadcast
            {
                const unsigned char* cwb = p.ctxW8 + (size_t)blk * SS * HH;
                const u64* h18q = (const u64*)h18u;
#pragma unroll
                for (int i = 0; i < 2; ++i) {
                    const int s0 = (w * 2 + i) * 16;
                    f32x4 acc = fz;
#pragma unroll
                    for (int kc = 0; kc < 16; ++kc) {
                        const int k0 = kc * 32;
                        long long av = (long long)h18q[(k0 >> 3) + kq];
                        long long bv = *reinterpret_cast<const long long*>(cwb + (size_t)(s0 + lrow) * HH + k0 + kq * 8);
                        acc = MFMA8(av, bv, acc);
                    }
                    if (l < 16) scv[s0 + l] = acc[0];
                }
            }
            lbar();
            // softmax over 256 (threads 0..255)
            float sc = -1e30f, e = 0.f;
            if (tid < 256) sc = scv[tid];
            float mx = sc;
#pragma unroll
            for (int off = 32; off; off >>= 1) mx = fmaxf(mx, __shfl_xor(mx, off));
            if (l == 0 && tid < 256) red[w] = mx;
            lbar();
            const float M = fmaxf(fmaxf(red[0], red[1]), fmaxf(red[2], red[3]));
            if (tid < 256) { e = __expf(sc - M); aU[tid] = e; }
            float se = e;
#pragma unroll
            for (int off = 32; off; off >>= 1) se += __shfl_xor(se, off);
            if (l == 0 && tid < 256) red[8 + w] = se;
            lbar();
            const float inv = 1.f / (red[8] + red[9] + red[10] + red[11]);
            if (t == TT - 1 && tid < 256) p.dout[OFF_AT + blk * SS + tid] = aU[tid] * inv;
            // pack softmax weights (unnormalized) to fp8
            if (tid < 64) {
                unsigned lo = __builtin_amdgcn_cvt_pk_fp8_f32(aU[tid * 4], aU[tid * 4 + 1], 0, false) & 0xffffu;
                unsigned hi = __builtin_amdgcn_cvt_pk_fp8_f32(aU[tid * 4 + 2], aU[tid * 4 + 3], 0, false) & 0xffffu;
                a32[tid] = lo | (hi << 16);
            }
            // combine GEMV via bf16 MFMA (independent of a32/pFh): g[j] = h1 . WoutR[j]
            f32x4 gacc[4];
#pragma unroll
            for (int i = 0; i < 4; ++i) {
                const int j0 = (w * 4 + i) * 16;
                f32x4 acc = fz;
#pragma unroll
                for (int kc = 0; kc < 16; ++kc) {
                    const int k0 = kc * 32;
                    s16x8 av = *reinterpret_cast<const s16x8*>(h1b + k0 + kq * 8);
                    s16x8 bv = *reinterpret_cast<const s16x8*>(p.Woutb + (size_t)(j0 + lrow) * 1024 + 512 + k0 + kq * 8);
                    acc = MFMA16(av, bv, acc);
                }
                gacc[i] = acc;
            }
            lbar();   // a32 visible
            // PV via fp8 MFMA over transposed ctxO8T: B = ctxO8T rows (16 h'/tile), A = a fp8 broadcast
            {
                const unsigned char* cob = p.ctxO8T + (size_t)blk * HH * SS;
                const u64* a8q = (const u64*)a32;
#pragma unroll
                for (int i = 0; i < 4; ++i) {
                    const int h0 = (w * 4 + i) * 16;
                    f32x4 acc = fz;
#pragma unroll
                    for (int kc = 0; kc < 8; ++kc) {
                        const int k0 = kc * 32;
                        long long av = (long long)a8q[(k0 >> 3) + kq];
                        long long bv = *reinterpret_cast<const long long*>(cob + (size_t)(h0 + lrow) * SS + k0 + kq * 8);
                        acc = MFMA8(av, bv, acc);
                    }
                    if (l < 16) pFh[h0 + l] = acc[0];
                }
            }
            lbar();   // pFh visible
#pragma unroll
            for (int i = 0; i < 4; ++i) {
                if (l < 16) {
                    const int j = (w * 4 + i) * 16 + l;
                    float tv = tanhf(pFh[j] * inv + gacc[i][0]);
                    __builtin_nontemporal_store(tv, &p.dout[(size_t)t * BH + blk * HH + j]);
                    ast2(&p.outx[pN + blk * HH + j], f2b(tv));
                }
            }
        }
        gbar(p.flags, ++ep);
    }
}

// ---------------- host ----------------

extern "C" void kernel_launch(void* const* d_in, const int* in_sizes, int n_in,
                              void* d_out, int out_size, void* d_ws, size_t ws_size,
                              hipStream_t stream) {
    const int* tokens = (const int*)d_in[0];
    const float* h0in = (const float*)d_in[1];
    const float* c0in = (const float*)d_in[2];
    const float* ctx = (const float*)d_in[3];
    const float* iout = (const float*)d_in[4];
    const float* emb = (const float*)d_in[5];
    const float* Wih0 = (const float*)d_in[6];
    const float* bih0 = (const float*)d_in[7];
    const float* Whh0 = (const float*)d_in[8];
    const float* bhh0 = (const float*)d_in[9];
    const float* Wih1 = (const float*)d_in[10];
    const float* bih1 = (const float*)d_in[11];
    const float* Whh1 = (const float*)d_in[12];
    const float* bhh1 = (const float*)d_in[13];
    const float* Win = (const float*)d_in[14];
    const float* Wout = (const float*)d_in[15];
    float* dout = (float*)d_out;

    char* pw = (char*)d_ws;
    auto take = [&](size_t bytes) { char* r = pw; pw += (bytes + 255) & ~(size_t)255; return r; };
    short* W0cat = (short*)take((size_t)2048 * 1536 * 2);
    short* W1cat = (short*)take((size_t)2048 * 1024 * 2);
    short* Winb  = (short*)take((size_t)512 * 512 * 2);
    short* Woutb = (short*)take((size_t)512 * 1024 * 2);
    float* bias0 = (float*)take(2048 * 4);
    float* bias1 = (float*)take(2048 * 4);
    short* Ebf   = (short*)take((size_t)TT * BB * EE * 2);
    unsigned char* ctxW8 = (unsigned char*)take((size_t)BB * SS * HH);
    unsigned char* ctxO8T = (unsigned char*)take((size_t)BB * SS * HH);
    short* h0x   = (short*)take((size_t)2 * BH * 2);
    short* h1x   = (short*)take((size_t)2 * BH * 2);
    short* outx  = (short*)take((size_t)2 * BH * 2);
    unsigned* flags = (unsigned*)take(NBLK * 4);

    k_pack2<<<2048, 256, 0, stream>>>(Wih0, 1024, Whh0, 512, W0cat, 2048 * 1536);
    k_pack2<<<2048, 256, 0, stream>>>(Wih1, 512, Whh1, 512, W1cat, 2048 * 1024);
    k_pack2<<<1024, 256, 0, stream>>>(Win, 512, Win, 0, Winb, 512 * 512);
    k_pack2<<<1024, 256, 0, stream>>>(Wout, 1024, Wout, 0, Woutb, 512 * 1024);
    k_bias<<<8, 256, 0, stream>>>(bih0, bhh0, bias0, bih1, bhh1, bias1);
    k_emb<<<4096, 256, 0, stream>>>(tokens, emb, Ebf);
    k_state<<<256, 256, 0, stream>>>(h0in, iout, h0x, h1x, outx);
    k_cvt8<<<dim3(8, 256), 512, 0, stream>>>(ctx, Winb, 512, 0, ctxW8);
    k_cvt8<<<dim3(8, 256), 512, 0, stream>>>(ctx, Woutb, 1024, 1, ctxO8T);
    (void)hipMemsetAsync(flags, 0, NBLK * 4, stream);

    const unsigned smem_bytes = (16 * 1536 + 16 * 1024 + 128 * 256) * 2 + 1008 * 4;
    (void)hipFuncSetAttribute((const void*)coop_k, hipFuncAttributeMaxDynamicSharedMemorySize, (int)smem_bytes);

    P prm;
    prm.Ebf = Ebf; prm.c0in = c0in;
    prm.ctxW8 = ctxW8; prm.ctxO8T = ctxO8T; prm.Woutb = Woutb;
    prm.W0cat = W0cat; prm.W1cat = W1cat;
    prm.bias0 = bias0; prm.bias1 = bias1;
    prm.h0x = h0x; prm.h1x = h1x; prm.outx = outx;
    prm.dout = dout; prm.flags = flags;
    void* args[] = {&prm};
    (void)hipLaunchCooperativeKernel((void*)coop_k, dim3(NBLK), dim3(NTHR), args, smem_bytes, stream);
}

// Round 12
// 12925.787 us; speedup vs baseline: 2.9755x; 1.1283x over previous
//
#include <hip/hip_runtime.h>
#include <hip/hip_bf16.h>
#include <math.h>

#define TT 256
#define BB 128
#define SS 256
#define HH 512
#define EE 512
#define NBLK 128
#define NTHR 512
#define BH (BB * HH)

typedef __attribute__((ext_vector_type(4))) float f32x4;
typedef __attribute__((ext_vector_type(8))) short s16x8;
typedef unsigned long long u64;

__device__ __forceinline__ float b2f(short v) {
    union { unsigned u; float f; } c;
    c.u = ((unsigned)(unsigned short)v) << 16;
    return c.f;
}
__device__ __forceinline__ short f2b(float f) {
    union { float f; unsigned u; } c; c.f = f;
    unsigned u = c.u;
    unsigned r = (u + 0x7fffu + ((u >> 16) & 1u)) >> 16;
    return (short)r;
}
__device__ __forceinline__ float sigm(float x) { return 1.f / (1.f + __expf(-x)); }

// agent-scope (LLC-coherent, cache-bypassing) exchange primitives
__device__ __forceinline__ u64 aldq(const void* p) {
    return __hip_atomic_load((const u64*)p, __ATOMIC_RELAXED, __HIP_MEMORY_SCOPE_AGENT);
}
__device__ __forceinline__ void ast2(short* p, short v) {
    __hip_atomic_store(p, v, __ATOMIC_RELAXED, __HIP_MEMORY_SCOPE_AGENT);
}
__device__ __forceinline__ s16x8 ald16(const void* p) {
    s16x8 r;
    asm volatile("global_load_dwordx4 %0, %1, off sc0 sc1" : "=v"(r) : "v"(p) : "memory");
    return r;
}

// LDS-only barrier: does NOT drain vmcnt
__device__ __forceinline__ void lbar() {
    asm volatile("s_waitcnt lgkmcnt(0)" ::: "memory");
    __builtin_amdgcn_s_barrier();
}

// ---------------- prep kernels ----------------

__global__ void k_pack2(const float* __restrict__ Wa, int ka, const float* __restrict__ Wb, int kb,
                        short* __restrict__ dst, int n) {
    const int K = ka + kb;
    for (int i = blockIdx.x * blockDim.x + threadIdx.x; i < n; i += gridDim.x * blockDim.x) {
        int g = i / K, k = i - g * K;
        float v = (k < ka) ? Wa[(size_t)g * ka + k] : Wb[(size_t)g * kb + (k - ka)];
        dst[i] = f2b(v);
    }
}

__global__ void k_bias(const float* __restrict__ a, const float* __restrict__ b, float* __restrict__ o,
                       const float* __restrict__ a2, const float* __restrict__ b2, float* __restrict__ o2) {
    int i = blockIdx.x * blockDim.x + threadIdx.x;
    if (i < 2048) { o[i] = a[i] + b[i]; o2[i] = a2[i] + b2[i]; }
}

__global__ void k_emb(const int* __restrict__ tok, const float* __restrict__ emb, short* __restrict__ Ebf) {
    const int n = TT * BB * EE;
    for (int i = blockIdx.x * blockDim.x + threadIdx.x; i < n; i += gridDim.x * blockDim.x) {
        int tb = i >> 9, k = i & 511;
        int t = tok[tb];
        Ebf[i] = f2b(emb[(size_t)t * EE + k]);
    }
}

// out8 = fp8( ctx[s,b,:] @ Wb[n,:]^T );  transpose=0: [(b,s), n];  transpose=1: [(b,n), s]
__global__ __launch_bounds__(512) void k_cvt8(const float* __restrict__ ctx, const short* __restrict__ Wb,
                                              int wstride, int transpose, unsigned char* __restrict__ out8) {
    const int tid = threadIdx.x, w = tid >> 6, l = tid & 63;
    const int m0 = blockIdx.y * 128, n0 = blockIdx.x * 64;
    const int kc8 = (l >> 4) * 8;
    const int m = m0 + w * 16 + (l & 15);
    const int b = m >> 8, s = m & 255;
    const float* arow = ctx + ((size_t)s * BB + b) * HH + kc8;
    f32x4 acc[4];
    const f32x4 zero = {0.f, 0.f, 0.f, 0.f};
#pragma unroll
    for (int j = 0; j < 4; ++j) acc[j] = zero;
#pragma unroll
    for (int kc = 0; kc < 16; ++kc) {
        const int k0 = kc * 32;
        float4 x0 = *reinterpret_cast<const float4*>(arow + k0);
        float4 x1 = *reinterpret_cast<const float4*>(arow + k0 + 4);
        s16x8 afr;
        afr[0] = f2b(x0.x); afr[1] = f2b(x0.y); afr[2] = f2b(x0.z); afr[3] = f2b(x0.w);
        afr[4] = f2b(x1.x); afr[5] = f2b(x1.y); afr[6] = f2b(x1.z); afr[7] = f2b(x1.w);
#pragma unroll
        for (int j = 0; j < 4; ++j) {
            s16x8 bfr = *reinterpret_cast<const s16x8*>(Wb + (size_t)(n0 + j * 16 + (l & 15)) * wstride + k0 + kc8);
            acc[j] = __builtin_amdgcn_mfma_f32_16x16x32_bf16(afr, bfr, acc[j], 0, 0, 0);
        }
    }
#pragma unroll
    for (int j = 0; j < 4; ++j)
#pragma unroll
        for (int r = 0; r < 4; ++r) {
            const int mm = m0 + w * 16 + (l >> 4) * 4 + r;
            const int nn = n0 + j * 16 + (l & 15);
            unsigned char v8 = (unsigned char)(__builtin_amdgcn_cvt_pk_fp8_f32(acc[j][r], 0.f, 0, false) & 0xff);
            if (transpose) {
                const int bb = mm >> 8, ss = mm & 255;
                out8[((size_t)bb * HH + nn) * SS + ss] = v8;
            } else {
                out8[(size_t)mm * HH + nn] = v8;
            }
        }
}

__global__ void k_state(const float* __restrict__ h0in, const float* __restrict__ iout,
                        short* __restrict__ h0x, short* __restrict__ h1x, short* __restrict__ outx) {
    int i = blockIdx.x * blockDim.x + threadIdx.x;
    if (i < BH) {
        h0x[i] = f2b(h0in[i]);
        h1x[i] = f2b(h0in[BH + i]);
        outx[i] = f2b(iout[i]);
    }
}

// ---------------- persistent cooperative kernel ----------------

struct P {
    const short* Ebf;
    const float* c0in;
    const unsigned char* ctxW8;   // [(b,s), n] fp8: scores source
    const unsigned char* ctxO8T;  // [(b,h'), s] fp8: PV-in-output-space, transposed
    const short* Woutb;           // bf16 [j][1024]
    const short* W0cat;
    const short* W1cat;
    const float* bias0;
    const float* bias1;
    short* h0x;
    short* h1x;
    short* outx;
    float* dout;
    unsigned* flags;              // one flag per 64B line: flags[blk*16]
};

#define MFMA16(a, b, c) __builtin_amdgcn_mfma_f32_16x16x32_bf16((a), (b), (c), 0, 0, 0)
#define MFMA8(a, b, c) __builtin_amdgcn_mfma_f32_16x16x32_fp8_fp8((a), (b), (c), 0, 0, 0)

__device__ __forceinline__ s16x8 ldsfrag(const short* base, int stride, int row, int col8) {
    return *reinterpret_cast<const s16x8*>(base + row * stride + ((col8 ^ (row & 7)) << 3));
}

__device__ __forceinline__ void issue8(const short* __restrict__ src, int tid, int khalf, s16x8* q) {
#pragma unroll
    for (int c = 0; c < 8; ++c) {
        const int chunk = c * 512 + tid;
        const int row = chunk >> 5, col8 = chunk & 31;
        q[c] = ald16(src + row * HH + khalf * 256 + col8 * 8);
    }
}
template <int N>
__device__ __forceinline__ void write8n(short* __restrict__ stg, int tid, const s16x8* q) {
    asm volatile("s_waitcnt vmcnt(%0)" ::"i"(N) : "memory");
#pragma unroll
    for (int c = 0; c < 8; ++c) {
        const int chunk = c * 512 + tid;
        const int row = chunk >> 5, col8 = chunk & 31;
        *reinterpret_cast<s16x8*>(stg + row * 256 + ((col8 ^ (row & 7)) << 3)) = q[c];
    }
}

__device__ __forceinline__ f32x4 seg8(const short* stgp, const short* Ws, int wstride, int wbase,
                                      int mrow, int wrow, int kq, f32x4 acc) {
#pragma unroll
    for (int seg = 0; seg < 8; ++seg)
        acc = MFMA16(ldsfrag(stgp, 256, mrow, seg * 4 + kq),
                     ldsfrag(Ws, wstride, wrow, wbase + seg * 4 + kq), acc);
    return acc;
}

// full grid barrier — CONTENTION-FIXED: one flag per 64B LLC line, each poller
// watches a distinct line, s_sleep backoff. (Previously 128 flags in 2 lines:
// ~400 concurrent accesses serialized at one LLC bank ≈ 15-20us per barrier.)
__device__ __forceinline__ void gbar(unsigned* flags, unsigned target) {
    asm volatile("s_waitcnt vmcnt(0)" ::: "memory");
    __syncthreads();
    if (threadIdx.x == 0)
        __hip_atomic_store(&flags[blockIdx.x * 16], target, __ATOMIC_RELAXED, __HIP_MEMORY_SCOPE_AGENT);
    if (threadIdx.x < NBLK) {
        while (__hip_atomic_load(&flags[threadIdx.x * 16], __ATOMIC_RELAXED, __HIP_MEMORY_SCOPE_AGENT) < target)
            __builtin_amdgcn_s_sleep(8);
    }
    __syncthreads();
}

__global__ void __launch_bounds__(NTHR, 1) coop_k(P p) {
    extern __shared__ __align__(16) char smem[];
    short* W0s = (short*)smem;            // 16 x 1536 sw
    short* W1s = W0s + 16 * 1536;         // 16 x 1024 sw
    short* stg = W1s + 16 * 1024;         // 128 x 256 sw stage / scratch
    float* smallf = (float*)(stg + 128 * 256);
    float* bias0s = smallf;               // 16
    float* bias1s = smallf + 16;          // 16
    float* red = smallf + 32;             // 16
    float* scv = smallf + 48;             // 256
    float* aU = smallf + 304;             // 256
    short* h1b = (short*)(smallf + 560);  // 512 bf16
    unsigned* h18u = (unsigned*)(smallf + 816);  // 512 fp8
    unsigned* a32 = (unsigned*)(smallf + 944);   // 256 fp8

    const int tid = threadIdx.x;
    const int blk = blockIdx.x;
    const int l = tid & 63;
    const int w = tid >> 6;
    const int lrow = l & 15;
    const int mrow = w * 16 + lrow;
    const int kq = l >> 4;
    const size_t OFF_HF = (size_t)TT * BH;
    const size_t OFF_CF = OFF_HF + 2 * (size_t)BH;
    const size_t OFF_AT = OFF_CF + 2 * (size_t)BH;
    const f32x4 fz = {0.f, 0.f, 0.f, 0.f};

    // --- prologue ---
    for (int idx = tid; idx < 16 * 192; idx += NTHR) {
        int row = idx / 192, col8 = idx % 192;
        int g = (row & 3) * 512 + blk * 4 + (row >> 2);
        *reinterpret_cast<s16x8*>(W0s + row * 1536 + ((col8 ^ (row & 7)) << 3)) =
            *reinterpret_cast<const s16x8*>(p.W0cat + (size_t)g * 1536 + col8 * 8);
    }
    for (int idx = tid; idx < 16 * 128; idx += NTHR) {
        int row = idx / 128, col8 = idx % 128;
        int g = (row & 3) * 512 + blk * 4 + (row >> 2);
        *reinterpret_cast<s16x8*>(W1s + row * 1024 + ((col8 ^ (row & 7)) << 3)) =
            *reinterpret_cast<const s16x8*>(p.W1cat + (size_t)g * 1024 + col8 * 8);
    }
    if (tid < 16) {
        int g = (tid & 3) * 512 + blk * 4 + (tid >> 2);
        bias0s[tid] = p.bias0[g];
        bias1s[tid] = p.bias1[g];
    }
    __syncthreads();

    const int bA = tid >> 2;
    const int jA = blk * 4 + (tid & 3);
    float c0reg = p.c0in[bA * HH + jA];
    float c1reg = p.c0in[BH + bA * HH + jA];
    unsigned ep = 0;
    s16x8 qa[8], qb[8], qc[8], qd[8];

    for (int t = 0; t < TT; ++t) {
        const size_t pB = (size_t)(t & 1) * BH;
        const size_t pN = (size_t)((t & 1) ^ 1) * BH;

        // ================= Phase A: layer-0 gates + cell =================
        {
            issue8(p.outx + pB, tid, 0, qa);
            issue8(p.outx + pB, tid, 1, qb);
            f32x4 aE = fz, aO = fz, aH = fz;
            {
                const short* erow = p.Ebf + ((size_t)t * BB + mrow) * EE + kq * 8;
#pragma unroll
                for (int seg = 0; seg < 16; ++seg) {
                    s16x8 afr = *reinterpret_cast<const s16x8*>(erow + seg * 32);
                    aE = MFMA16(afr, ldsfrag(W0s, 1536, lrow, seg * 4 + kq), aE);
                }
            }
            write8n<8>(stg, tid, qa);
            issue8(p.h0x + pB, tid, 0, qc);
            lbar();
            aO = seg8(stg, W0s, 1536, 64, mrow, lrow, kq, aO);
            lbar();
            write8n<8>(stg, tid, qb);
            issue8(p.h0x + pB, tid, 1, qd);
            lbar();
            aO = seg8(stg, W0s, 1536, 96, mrow, lrow, kq, aO);
            lbar();
            write8n<8>(stg, tid, qc);
            lbar();
            aH = seg8(stg, W0s, 1536, 128, mrow, lrow, kq, aH);
            lbar();
            write8n<0>(stg, tid, qd);
            lbar();
            aH = seg8(stg, W0s, 1536, 160, mrow, lrow, kq, aH);

            f32x4 acc = aE + aO + aH;
            lbar();
            float* scr = (float*)stg + w * 272;
#pragma unroll
            for (int r = 0; r < 4; ++r) scr[lrow * 17 + kq * 4 + r] = acc[r];
            const int bloc = l >> 2;
            const int n0 = (l & 3) * 4;
            float gi = scr[(n0 + 0) * 17 + bloc] + bias0s[n0 + 0];
            float gf = scr[(n0 + 1) * 17 + bloc] + bias0s[n0 + 1];
            float gg = scr[(n0 + 2) * 17 + bloc] + bias0s[n0 + 2];
            float go = scr[(n0 + 3) * 17 + bloc] + bias0s[n0 + 3];
            float cn = sigm(gf) * c0reg + sigm(gi) * tanhf(gg);
            float hn = sigm(go) * tanhf(cn);
            c0reg = cn;
            ast2(&p.h0x[pN + bA * HH + jA], f2b(hn));
            if (t == TT - 1) {
                p.dout[OFF_HF + bA * HH + jA] = hn;
                p.dout[OFF_CF + bA * HH + jA] = cn;
            }
        }
        gbar(p.flags, ++ep);

        // ================= Phase B: layer-1 gates + cell =================
        {
            issue8(p.h0x + pN, tid, 0, qa);
            issue8(p.h0x + pN, tid, 1, qb);
            f32x4 b0 = fz, b1 = fz;
            write8n<8>(stg, tid, qa);
            issue8(p.h1x + pB, tid, 0, qc);
            lbar();
            b0 = seg8(stg, W1s, 1024, 0, mrow, lrow, kq, b0);
            lbar();
            write8n<8>(stg, tid, qb);
            issue8(p.h1x + pB, tid, 1, qd);
            lbar();
            b0 = seg8(stg, W1s, 1024, 32, mrow, lrow, kq, b0);
            lbar();
            write8n<8>(stg, tid, qc);
            lbar();
            b1 = seg8(stg, W1s, 1024, 64, mrow, lrow, kq, b1);
            lbar();
            write8n<0>(stg, tid, qd);
            lbar();
            b1 = seg8(stg, W1s, 1024, 96, mrow, lrow, kq, b1);

            f32x4 acc = b0 + b1;
            lbar();
            float* scr = (float*)stg + w * 272;
#pragma unroll
            for (int r = 0; r < 4; ++r) scr[lrow * 17 + kq * 4 + r] = acc[r];
            const int bloc = l >> 2;
            const int n0 = (l & 3) * 4;
            float gi = scr[(n0 + 0) * 17 + bloc] + bias1s[n0 + 0];
            float gf = scr[(n0 + 1) * 17 + bloc] + bias1s[n0 + 1];
            float gg = scr[(n0 + 2) * 17 + bloc] + bias1s[n0 + 2];
            float go = scr[(n0 + 3) * 17 + bloc] + bias1s[n0 + 3];
            float cn = sigm(gf) * c1reg + sigm(gi) * tanhf(gg);
            float hn = sigm(go) * tanhf(cn);
            c1reg = cn;
            ast2(&p.h1x[pN + bA * HH + jA], f2b(hn));
            if (t == TT - 1) {
                p.dout[OFF_HF + BH + bA * HH + jA] = hn;
                p.dout[OFF_CF + BH + bA * HH + jA] = cn;
            }
        }
        gbar(p.flags, ++ep);

        // ===== Phase C: attention + fused output row for batch b = blk (all-MFMA) =====
        {
            float* pFh = (float*)stg;   // 512 floats: PV result in output space
            if (tid < 128) {
                union { u64 v; short s[4]; } c;
                c.v = aldq(p.h1x + pN + blk * HH + tid * 4);
#pragma unroll
                for (int j = 0; j < 4; ++j) h1b[tid * 4 + j] = c.s[j];
                float f0 = b2f(c.s[0]), f1 = b2f(c.s[1]), f2 = b2f(c.s[2]), f3 = b2f(c.s[3]);
                unsigned lo = __builtin_amdgcn_cvt_pk_fp8_f32(f0, f1, 0, false) & 0xffffu;
                unsigned hi = __builtin_amdgcn_cvt_pk_fp8_f32(f2, f3, 0, false) & 0xffffu;
                h18u[tid] = lo | (hi << 16);
            }
            lbar();
            // scores via fp8 MFMA: B = ctxW8 rows (16 s/tile), A = h1 fp8 broadcast
            {
                const unsigned char* cwb = p.ctxW8 + (size_t)blk * SS * HH;
                const u64* h18q = (const u64*)h18u;
#pragma unroll
                for (int i = 0; i < 2; ++i) {
                    const int s0 = (w * 2 + i) * 16;
                    f32x4 acc = fz;
#pragma unroll
                    for (int kc = 0; kc < 16; ++kc) {
                        const int k0 = kc * 32;
                        long long av = (long long)h18q[(k0 >> 3) + kq];
                        long long bv = *reinterpret_cast<const long long*>(cwb + (size_t)(s0 + lrow) * HH + k0 + kq * 8);
                        acc = MFMA8(av, bv, acc);
                    }
                    if (l < 16) scv[s0 + l] = acc[0];
                }
            }
            lbar();
            // softmax over 256 (threads 0..255)
            float sc = -1e30f, e = 0.f;
            if (tid < 256) sc = scv[tid];
            float mx = sc;
#pragma unroll
            for (int off = 32; off; off >>= 1) mx = fmaxf(mx, __shfl_xor(mx, off));
            if (l == 0 && tid < 256) red[w] = mx;
            lbar();
            const float M = fmaxf(fmaxf(red[0], red[1]), fmaxf(red[2], red[3]));
            if (tid < 256) { e = __expf(sc - M); aU[tid] = e; }
            float se = e;
#pragma unroll
            for (int off = 32; off; off >>= 1) se += __shfl_xor(se, off);
            if (l == 0 && tid < 256) red[8 + w] = se;
            lbar();
            const float inv = 1.f / (red[8] + red[9] + red[10] + red[11]);
            if (t == TT - 1 && tid < 256) p.dout[OFF_AT + blk * SS + tid] = aU[tid] * inv;
            // pack softmax weights (unnormalized) to fp8
            if (tid < 64) {
                unsigned lo = __builtin_amdgcn_cvt_pk_fp8_f32(aU[tid * 4], aU[tid * 4 + 1], 0, false) & 0xffffu;
                unsigned hi = __builtin_amdgcn_cvt_pk_fp8_f32(aU[tid * 4 + 2], aU[tid * 4 + 3], 0, false) & 0xffffu;
                a32[tid] = lo | (hi << 16);
            }
            // combine GEMV via bf16 MFMA: g[j] = h1 . WoutR[j]
            f32x4 gacc[4];
#pragma unroll
            for (int i = 0; i < 4; ++i) {
                const int j0 = (w * 4 + i) * 16;
                f32x4 acc = fz;
#pragma unroll
                for (int kc = 0; kc < 16; ++kc) {
                    const int k0 = kc * 32;
                    s16x8 av = *reinterpret_cast<const s16x8*>(h1b + k0 + kq * 8);
                    s16x8 bv = *reinterpret_cast<const s16x8*>(p.Woutb + (size_t)(j0 + lrow) * 1024 + 512 + k0 + kq * 8);
                    acc = MFMA16(av, bv, acc);
                }
                gacc[i] = acc;
            }
            lbar();   // a32 visible
            // PV via fp8 MFMA over transposed ctxO8T
            {
                const unsigned char* cob = p.ctxO8T + (size_t)blk * HH * SS;
                const u64* a8q = (const u64*)a32;
#pragma unroll
                for (int i = 0; i < 4; ++i) {
                    const int h0 = (w * 4 + i) * 16;
                    f32x4 acc = fz;
#pragma unroll
                    for (int kc = 0; kc < 8; ++kc) {
                        const int k0 = kc * 32;
                        long long av = (long long)a8q[(k0 >> 3) + kq];
                        long long bv = *reinterpret_cast<const long long*>(cob + (size_t)(h0 + lrow) * SS + k0 + kq * 8);
                        acc = MFMA8(av, bv, acc);
                    }
                    if (l < 16) pFh[h0 + l] = acc[0];
                }
            }
            lbar();   // pFh visible
#pragma unroll
            for (int i = 0; i < 4; ++i) {
                if (l < 16) {
                    const int j = (w * 4 + i) * 16 + l;
                    float tv = tanhf(pFh[j] * inv + gacc[i][0]);
                    __builtin_nontemporal_store(tv, &p.dout[(size_t)t * BH + blk * HH + j]);
                    ast2(&p.outx[pN + blk * HH + j], f2b(tv));
                }
            }
        }
        gbar(p.flags, ++ep);
    }
}

// ---------------- host ----------------

extern "C" void kernel_launch(void* const* d_in, const int* in_sizes, int n_in,
                              void* d_out, int out_size, void* d_ws, size_t ws_size,
                              hipStream_t stream) {
    const int* tokens = (const int*)d_in[0];
    const float* h0in = (const float*)d_in[1];
    const float* c0in = (const float*)d_in[2];
    const float* ctx = (const float*)d_in[3];
    const float* iout = (const float*)d_in[4];
    const float* emb = (const float*)d_in[5];
    const float* Wih0 = (const float*)d_in[6];
    const float* bih0 = (const float*)d_in[7];
    const float* Whh0 = (const float*)d_in[8];
    const float* bhh0 = (const float*)d_in[9];
    const float* Wih1 = (const float*)d_in[10];
    const float* bih1 = (const float*)d_in[11];
    const float* Whh1 = (const float*)d_in[12];
    const float* bhh1 = (const float*)d_in[13];
    const float* Win = (const float*)d_in[14];
    const float* Wout = (const float*)d_in[15];
    float* dout = (float*)d_out;

    char* pw = (char*)d_ws;
    auto take = [&](size_t bytes) { char* r = pw; pw += (bytes + 255) & ~(size_t)255; return r; };
    short* W0cat = (short*)take((size_t)2048 * 1536 * 2);
    short* W1cat = (short*)take((size_t)2048 * 1024 * 2);
    short* Winb  = (short*)take((size_t)512 * 512 * 2);
    short* Woutb = (short*)take((size_t)512 * 1024 * 2);
    float* bias0 = (float*)take(2048 * 4);
    float* bias1 = (float*)take(2048 * 4);
    short* Ebf   = (short*)take((size_t)TT * BB * EE * 2);
    unsigned char* ctxW8 = (unsigned char*)take((size_t)BB * SS * HH);
    unsigned char* ctxO8T = (unsigned char*)take((size_t)BB * SS * HH);
    short* h0x   = (short*)take((size_t)2 * BH * 2);
    short* h1x   = (short*)take((size_t)2 * BH * 2);
    short* outx  = (short*)take((size_t)2 * BH * 2);
    unsigned* flags = (unsigned*)take(NBLK * 64);   // one 64B line per block

    k_pack2<<<2048, 256, 0, stream>>>(Wih0, 1024, Whh0, 512, W0cat, 2048 * 1536);
    k_pack2<<<2048, 256, 0, stream>>>(Wih1, 512, Whh1, 512, W1cat, 2048 * 1024);
    k_pack2<<<1024, 256, 0, stream>>>(Win, 512, Win, 0, Winb, 512 * 512);
    k_pack2<<<1024, 256, 0, stream>>>(Wout, 1024, Wout, 0, Woutb, 512 * 1024);
    k_bias<<<8, 256, 0, stream>>>(bih0, bhh0, bias0, bih1, bhh1, bias1);
    k_emb<<<4096, 256, 0, stream>>>(tokens, emb, Ebf);
    k_state<<<256, 256, 0, stream>>>(h0in, iout, h0x, h1x, outx);
    k_cvt8<<<dim3(8, 256), 512, 0, stream>>>(ctx, Winb, 512, 0, ctxW8);
    k_cvt8<<<dim3(8, 256), 512, 0, stream>>>(ctx, Woutb, 1024, 1, ctxO8T);
    (void)hipMemsetAsync(flags, 0, NBLK * 64, stream);

    const unsigned smem_bytes = (16 * 1536 + 16 * 1024 + 128 * 256) * 2 + 1008 * 4;
    (void)hipFuncSetAttribute((const void*)coop_k, hipFuncAttributeMaxDynamicSharedMemorySize, (int)smem_bytes);

    P prm;
    prm.Ebf = Ebf; prm.c0in = c0in;
    prm.ctxW8 = ctxW8; prm.ctxO8T = ctxO8T; prm.Woutb = Woutb;
    prm.W0cat = W0cat; prm.W1cat = W1cat;
    prm.bias0 = bias0; prm.bias1 = bias1;
    prm.h0x = h0x; prm.h1x = h1x; prm.outx = outx;
    prm.dout = dout; prm.flags = flags;
    void* args[] = {&prm};
    (void)hipLaunchCooperativeKernel((void*)coop_k, dim3(NBLK), dim3(NTHR), args, smem_bytes, stream);
}